// Round 1
// baseline (721.563 us; speedup 1.0000x reference)
//
#include <hip/hip_runtime.h>
#include <hip/hip_bf16.h>

#define N_NODES_C 20000
#define N_EDGES_C 640000
#define HID_C 64
#define GRAPHS_C 512
#define OUT_C 128
#define PE_DIM_C 10
#define ATOM_FEATS_C 9
#define ATOM_VOCAB_C 119
#define BOND_VOCAB_C 5
#define LAYERS_C 3
#define NCODES_C 125   // 5*5*5 distinct bond-type combinations

// ---------------------------------------------------------------------------
// Node encoder: atom-embedding sum + SignNet(±lap_pe) + RWSE MLP.
// 4 nodes per 256-thread block; lane j owns channel j.
// ---------------------------------------------------------------------------
__global__ __launch_bounds__(256) void node_encode_kernel(
    const int* __restrict__ x_atom, const float* __restrict__ lap_pe,
    const float* __restrict__ rwse, const float* __restrict__ atom_emb,
    const float* __restrict__ sW1, const float* __restrict__ sb1,
    const float* __restrict__ sW2, const float* __restrict__ sb2,
    const float* __restrict__ rW1, const float* __restrict__ rb1,
    const float* __restrict__ rW2, const float* __restrict__ rb2,
    float* __restrict__ x)
{
    __shared__ float hs[4][HID_C];   // relu(pe@W1+b1) + relu(-pe@W1+b1)
    __shared__ float hr[4][HID_C];   // relu(rwse@W1+b1)
    const int local = threadIdx.x >> 6;
    const int j = threadIdx.x & 63;
    const int n = blockIdx.x * 4 + local;   // grid is exactly N/4 blocks

    // atom embedding sum
    float acc = 0.f;
    #pragma unroll
    for (int f = 0; f < ATOM_FEATS_C; ++f) {
        int idx = x_atom[n * ATOM_FEATS_C + f];
        acc += atom_emb[(f * ATOM_VOCAB_C + idx) * HID_C + j];
    }
    // hidden layers of the three 2-layer MLPs
    float h1 = sb1[j], h2 = sb1[j], hv = rb1[j];
    #pragma unroll
    for (int i = 0; i < PE_DIM_C; ++i) {
        float p = lap_pe[n * PE_DIM_C + i];
        float w = sW1[i * HID_C + j];
        h1 += p * w;
        h2 -= p * w;
        hv += rwse[n * PE_DIM_C + i] * rW1[i * HID_C + j];
    }
    hs[local][j] = fmaxf(h1, 0.f) + fmaxf(h2, 0.f);
    hr[local][j] = fmaxf(hv, 0.f);
    __syncthreads();

    float o = acc + 2.f * sb2[j] + rb2[j];
    #pragma unroll 8
    for (int i = 0; i < HID_C; ++i) {
        o += hs[local][i] * sW2[i * HID_C + j];
        o += hr[local][i] * rW2[i * HID_C + j];
    }
    x[n * HID_C + j] = o;
}

// ---------------------------------------------------------------------------
// Bond tables: for each of 125 codes, e_row = sum_f bond_emb[f][cf]; then
// etab[l][c] = e_row @ We[l] + be[l].  One block (64 threads) per code.
// ---------------------------------------------------------------------------
__global__ void bond_etab_kernel(const float* __restrict__ bond_emb,
                                 const float* __restrict__ We,
                                 const float* __restrict__ be,
                                 float* __restrict__ etab)
{
    __shared__ float t[HID_C];
    const int c = blockIdx.x;
    const int j = threadIdx.x;
    const int f0 = c / 25, f1 = (c / 5) % 5, f2 = c % 5;
    float tv = bond_emb[(0 * BOND_VOCAB_C + f0) * HID_C + j]
             + bond_emb[(1 * BOND_VOCAB_C + f1) * HID_C + j]
             + bond_emb[(2 * BOND_VOCAB_C + f2) * HID_C + j];
    t[j] = tv;
    __syncthreads();
    for (int l = 0; l < LAYERS_C; ++l) {
        float o = be[l * HID_C + j];
        #pragma unroll 8
        for (int i = 0; i < HID_C; ++i)
            o += t[i] * We[(l * HID_C + i) * HID_C + j];
        etab[(l * NCODES_C + c) * HID_C + j] = o;
    }
}

// ---------------------------------------------------------------------------
// CSR build: histogram by dst, exclusive scan, scatter packed (src<<7|code).
// ---------------------------------------------------------------------------
__global__ void hist_kernel(const int* __restrict__ dst, int* __restrict__ counts)
{
    int e = blockIdx.x * blockDim.x + threadIdx.x;
    if (e < N_EDGES_C) atomicAdd(&counts[dst[e]], 1);
}

__global__ void scan_kernel(const int* __restrict__ counts,
                            int* __restrict__ row_ptr, int* __restrict__ cursor)
{
    __shared__ int part[1024];
    const int t = threadIdx.x;
    const int CH = 20;                // 1024*20 = 20480 >= 20000
    const int base = t * CH;
    int s = 0;
    for (int i = 0; i < CH; ++i) {
        int idx = base + i;
        if (idx < N_NODES_C) s += counts[idx];
    }
    part[t] = s;
    __syncthreads();
    for (int d = 1; d < 1024; d <<= 1) {
        int val = (t >= d) ? part[t - d] : 0;
        __syncthreads();
        part[t] += val;
        __syncthreads();
    }
    int run = part[t] - s;            // exclusive prefix of this chunk
    for (int i = 0; i < CH; ++i) {
        int idx = base + i;
        if (idx < N_NODES_C) {
            row_ptr[idx] = run;
            cursor[idx]  = run;
            run += counts[idx];
        }
    }
    if (t == 1023) row_ptr[N_NODES_C] = part[1023];
}

__global__ void scatter_kernel(const int* __restrict__ ei, const int* __restrict__ ea,
                               int* __restrict__ cursor, int* __restrict__ packed)
{
    int e = blockIdx.x * blockDim.x + threadIdx.x;
    if (e >= N_EDGES_C) return;
    int src  = ei[e];
    int dst  = ei[N_EDGES_C + e];
    int code = ea[e * 3] * 25 + ea[e * 3 + 1] * 5 + ea[e * 3 + 2];
    int p = atomicAdd(&cursor[dst], 1);
    packed[p] = (src << 7) | code;
}

// ---------------------------------------------------------------------------
// Per-layer node projections: q,k,v,xs = x @ {Wq,Wk,Wv,Ws} + b. 4 nodes/block.
// ---------------------------------------------------------------------------
__global__ __launch_bounds__(256) void qkvs_kernel(
    const float* __restrict__ x,
    const float* __restrict__ Wq, const float* __restrict__ bq,
    const float* __restrict__ Wk, const float* __restrict__ bk,
    const float* __restrict__ Wv, const float* __restrict__ bv,
    const float* __restrict__ Ws, const float* __restrict__ bs,
    float* __restrict__ q, float* __restrict__ k,
    float* __restrict__ v, float* __restrict__ xs)
{
    __shared__ float xr[4][HID_C];
    const int local = threadIdx.x >> 6;
    const int j = threadIdx.x & 63;
    const int n = blockIdx.x * 4 + local;
    xr[local][j] = x[n * HID_C + j];
    __syncthreads();
    float aq = bq[j], ak = bk[j], av = bv[j], ax = bs[j];
    #pragma unroll 8
    for (int i = 0; i < HID_C; ++i) {
        float xi = xr[local][i];
        aq += xi * Wq[i * HID_C + j];
        ak += xi * Wk[i * HID_C + j];
        av += xi * Wv[i * HID_C + j];
        ax += xi * Ws[i * HID_C + j];
    }
    q [n * HID_C + j] = aq;
    k [n * HID_C + j] = ak;
    v [n * HID_C + j] = av;
    xs[n * HID_C + j] = ax;
}

// ---------------------------------------------------------------------------
// Attention aggregation, flash-style: one wave per destination node.
// lane j = channel, head = j>>4; online softmax over the node's in-edges.
// etab for the layer is staged in LDS (125*64 f32 = 32 KB).
// ---------------------------------------------------------------------------
__global__ __launch_bounds__(256) void attn_kernel(
    const float* __restrict__ q, const float* __restrict__ k,
    const float* __restrict__ v, const float* __restrict__ xs,
    const float* __restrict__ etab_l, const int* __restrict__ row_ptr,
    const int* __restrict__ packed, float* __restrict__ x)
{
    __shared__ float et[NCODES_C * HID_C];
    for (int i = threadIdx.x; i < NCODES_C * HID_C; i += 256) et[i] = etab_l[i];
    __syncthreads();

    const int local = threadIdx.x >> 6;
    const int j = threadIdx.x & 63;
    const int n = blockIdx.x * 4 + local;

    const float qj = q[n * HID_C + j];
    const int start = row_ptr[n], end = row_ptr[n + 1];

    float m = -3.4e38f, den = 0.f, acc = 0.f;
    for (int base = start; base < end; base += 64) {
        const int cnt = min(64, end - base);
        int pk_l = (base + j < end) ? packed[base + j] : 0;
        for (int i = 0; i < cnt; ++i) {
            const int pk   = __shfl(pk_l, i, 64);
            const int src  = pk >> 7;
            const int code = pk & 127;
            const float ev = et[code * HID_C + j];
            const float ke = k[src * HID_C + j] + ev;
            const float ve = v[src * HID_C + j] + ev;
            float prod = qj * ke;
            prod += __shfl_xor(prod, 8, 64);   // reduce within 16-lane head group
            prod += __shfl_xor(prod, 4, 64);
            prod += __shfl_xor(prod, 2, 64);
            prod += __shfl_xor(prod, 1, 64);
            const float logit = prod * 0.25f;  // 1/sqrt(16)
            const float mn = fmaxf(m, logit);
            const float sc = __expf(m - mn);
            const float ex = __expf(logit - mn);
            den = den * sc + ex;
            acc = acc * sc + ex * ve;
            m = mn;
        }
    }
    const float agg = acc / (den + 1e-16f);
    x[n * HID_C + j] = fmaxf(agg + xs[n * HID_C + j], 0.f);
}

// ---------------------------------------------------------------------------
// Mean pool (atomic accumulate) + classifier head.
// ---------------------------------------------------------------------------
__global__ void pool_kernel(const float* __restrict__ x, const int* __restrict__ batch,
                            float* __restrict__ psum, float* __restrict__ pcnt)
{
    int idx = blockIdx.x * blockDim.x + threadIdx.x;
    if (idx >= N_NODES_C * HID_C) return;
    int n = idx >> 6, j = idx & 63;
    int g = batch[n];
    atomicAdd(&psum[g * HID_C + j], x[idx]);
    if (j == 0) atomicAdd(&pcnt[g], 1.f);
}

__global__ void head_kernel(const float* __restrict__ psum, const float* __restrict__ pcnt,
                            const float* __restrict__ fc_W, const float* __restrict__ fc_b,
                            float* __restrict__ out)
{
    __shared__ float p[HID_C];
    const int g = blockIdx.x;
    const int o = threadIdx.x;        // 0..127
    if (o < HID_C) p[o] = psum[g * HID_C + o] / fmaxf(pcnt[g], 1.f);
    __syncthreads();
    float acc = fc_b[o];
    #pragma unroll 8
    for (int i = 0; i < HID_C; ++i)
        acc += p[i] * fc_W[i * OUT_C + o];
    out[g * OUT_C + o] = acc;
}

// ---------------------------------------------------------------------------
extern "C" void kernel_launch(void* const* d_in, const int* in_sizes, int n_in,
                              void* d_out, int out_size, void* d_ws, size_t ws_size,
                              hipStream_t stream)
{
    const int*   x_atom     = (const int*)  d_in[0];
    const int*   edge_index = (const int*)  d_in[1];
    const int*   edge_attr  = (const int*)  d_in[2];
    const int*   batch      = (const int*)  d_in[3];
    const float* lap_pe     = (const float*)d_in[4];
    const float* rwse       = (const float*)d_in[5];
    const float* atom_emb   = (const float*)d_in[6];
    const float* bond_emb   = (const float*)d_in[7];
    const float* sign_W1    = (const float*)d_in[8];
    const float* sign_b1    = (const float*)d_in[9];
    const float* sign_W2    = (const float*)d_in[10];
    const float* sign_b2    = (const float*)d_in[11];
    const float* rwse_W1    = (const float*)d_in[12];
    const float* rwse_b1    = (const float*)d_in[13];
    const float* rwse_W2    = (const float*)d_in[14];
    const float* rwse_b2    = (const float*)d_in[15];
    const float* Wq = (const float*)d_in[16];
    const float* bq = (const float*)d_in[17];
    const float* Wk = (const float*)d_in[18];
    const float* bk = (const float*)d_in[19];
    const float* Wv = (const float*)d_in[20];
    const float* bv = (const float*)d_in[21];
    const float* We = (const float*)d_in[22];
    const float* be = (const float*)d_in[23];
    const float* Ws = (const float*)d_in[24];
    const float* bs = (const float*)d_in[25];
    const float* fc_W = (const float*)d_in[26];
    const float* fc_b = (const float*)d_in[27];
    float* out = (float*)d_out;

    // workspace layout (256B-aligned slabs)
    char* ws = (char*)d_ws;
    size_t off = 0;
    auto alloc = [&](size_t bytes) {
        size_t o = off;
        off += (bytes + 255) & ~(size_t)255;
        return o;
    };
    float* x    = (float*)(ws + alloc((size_t)N_NODES_C * HID_C * 4));
    float* q    = (float*)(ws + alloc((size_t)N_NODES_C * HID_C * 4));
    float* k    = (float*)(ws + alloc((size_t)N_NODES_C * HID_C * 4));
    float* v    = (float*)(ws + alloc((size_t)N_NODES_C * HID_C * 4));
    float* xs   = (float*)(ws + alloc((size_t)N_NODES_C * HID_C * 4));
    float* etab = (float*)(ws + alloc((size_t)LAYERS_C * NCODES_C * HID_C * 4));
    int* counts = (int*)  (ws + alloc((size_t)N_NODES_C * 4));
    int* rowp   = (int*)  (ws + alloc((size_t)(N_NODES_C + 1) * 4));
    int* cursor = (int*)  (ws + alloc((size_t)N_NODES_C * 4));
    int* packed = (int*)  (ws + alloc((size_t)N_EDGES_C * 4));
    float* psum = (float*)(ws + alloc((size_t)GRAPHS_C * HID_C * 4));
    float* pcnt = (float*)(ws + alloc((size_t)GRAPHS_C * 4));

    hipMemsetAsync(counts, 0, (size_t)N_NODES_C * 4, stream);
    hipMemsetAsync(psum,   0, (size_t)GRAPHS_C * HID_C * 4, stream);
    hipMemsetAsync(pcnt,   0, (size_t)GRAPHS_C * 4, stream);

    node_encode_kernel<<<N_NODES_C / 4, 256, 0, stream>>>(
        x_atom, lap_pe, rwse, atom_emb,
        sign_W1, sign_b1, sign_W2, sign_b2,
        rwse_W1, rwse_b1, rwse_W2, rwse_b2, x);

    bond_etab_kernel<<<NCODES_C, 64, 0, stream>>>(bond_emb, We, be, etab);

    hist_kernel<<<(N_EDGES_C + 255) / 256, 256, 0, stream>>>(edge_index + N_EDGES_C, counts);
    scan_kernel<<<1, 1024, 0, stream>>>(counts, rowp, cursor);
    scatter_kernel<<<(N_EDGES_C + 255) / 256, 256, 0, stream>>>(edge_index, edge_attr, cursor, packed);

    for (int l = 0; l < LAYERS_C; ++l) {
        qkvs_kernel<<<N_NODES_C / 4, 256, 0, stream>>>(
            x,
            Wq + l * HID_C * HID_C, bq + l * HID_C,
            Wk + l * HID_C * HID_C, bk + l * HID_C,
            Wv + l * HID_C * HID_C, bv + l * HID_C,
            Ws + l * HID_C * HID_C, bs + l * HID_C,
            q, k, v, xs);
        attn_kernel<<<N_NODES_C / 4, 256, 0, stream>>>(
            q, k, v, xs, etab + (size_t)l * NCODES_C * HID_C, rowp, packed, x);
    }

    pool_kernel<<<(N_NODES_C * HID_C) / 256, 256, 0, stream>>>(x, batch, psum, pcnt);
    head_kernel<<<GRAPHS_C, OUT_C, 0, stream>>>(psum, pcnt, fc_W, fc_b, out);
}

// Round 2
// 508.082 us; speedup vs baseline: 1.4202x; 1.4202x over previous
//
#include <hip/hip_runtime.h>
#include <hip/hip_bf16.h>

#define N_NODES_C 20000
#define N_EDGES_C 640000
#define HID_C 64
#define GRAPHS_C 512
#define OUT_C 128
#define PE_DIM_C 10
#define ATOM_FEATS_C 9
#define ATOM_VOCAB_C 119
#define BOND_VOCAB_C 5
#define LAYERS_C 3
#define NCODES_C 125   // 5*5*5 distinct bond-type combinations

// ---------------------------------------------------------------------------
// Node encoder: atom-embedding sum + SignNet(±lap_pe) + RWSE MLP.
// 4 nodes per 256-thread block; lane j owns channel j.
// ---------------------------------------------------------------------------
__global__ __launch_bounds__(256) void node_encode_kernel(
    const int* __restrict__ x_atom, const float* __restrict__ lap_pe,
    const float* __restrict__ rwse, const float* __restrict__ atom_emb,
    const float* __restrict__ sW1, const float* __restrict__ sb1,
    const float* __restrict__ sW2, const float* __restrict__ sb2,
    const float* __restrict__ rW1, const float* __restrict__ rb1,
    const float* __restrict__ rW2, const float* __restrict__ rb2,
    float* __restrict__ x)
{
    __shared__ float hs[4][HID_C];   // relu(pe@W1+b1) + relu(-pe@W1+b1)
    __shared__ float hr[4][HID_C];   // relu(rwse@W1+b1)
    const int local = threadIdx.x >> 6;
    const int j = threadIdx.x & 63;
    const int n = blockIdx.x * 4 + local;   // grid is exactly N/4 blocks

    float acc = 0.f;
    #pragma unroll
    for (int f = 0; f < ATOM_FEATS_C; ++f) {
        int idx = x_atom[n * ATOM_FEATS_C + f];
        acc += atom_emb[(f * ATOM_VOCAB_C + idx) * HID_C + j];
    }
    float h1 = sb1[j], h2 = sb1[j], hv = rb1[j];
    #pragma unroll
    for (int i = 0; i < PE_DIM_C; ++i) {
        float p = lap_pe[n * PE_DIM_C + i];
        float w = sW1[i * HID_C + j];
        h1 += p * w;
        h2 -= p * w;
        hv += rwse[n * PE_DIM_C + i] * rW1[i * HID_C + j];
    }
    hs[local][j] = fmaxf(h1, 0.f) + fmaxf(h2, 0.f);
    hr[local][j] = fmaxf(hv, 0.f);
    __syncthreads();

    float o = acc + 2.f * sb2[j] + rb2[j];
    #pragma unroll 8
    for (int i = 0; i < HID_C; ++i) {
        o += hs[local][i] * sW2[i * HID_C + j];
        o += hr[local][i] * rW2[i * HID_C + j];
    }
    x[n * HID_C + j] = o;
}

// ---------------------------------------------------------------------------
// Bond tables: etab[l][c] = (sum_f bond_emb[f][cf]) @ We[l] + be[l].
// ---------------------------------------------------------------------------
__global__ void bond_etab_kernel(const float* __restrict__ bond_emb,
                                 const float* __restrict__ We,
                                 const float* __restrict__ be,
                                 float* __restrict__ etab)
{
    __shared__ float t[HID_C];
    const int c = blockIdx.x;
    const int j = threadIdx.x;
    const int f0 = c / 25, f1 = (c / 5) % 5, f2 = c % 5;
    float tv = bond_emb[(0 * BOND_VOCAB_C + f0) * HID_C + j]
             + bond_emb[(1 * BOND_VOCAB_C + f1) * HID_C + j]
             + bond_emb[(2 * BOND_VOCAB_C + f2) * HID_C + j];
    t[j] = tv;
    __syncthreads();
    for (int l = 0; l < LAYERS_C; ++l) {
        float o = be[l * HID_C + j];
        #pragma unroll 8
        for (int i = 0; i < HID_C; ++i)
            o += t[i] * We[(l * HID_C + i) * HID_C + j];
        etab[(l * NCODES_C + c) * HID_C + j] = o;
    }
}

// ---------------------------------------------------------------------------
// CSR build: histogram by dst, exclusive scan, scatter packed (src<<7|code).
// ---------------------------------------------------------------------------
__global__ void hist_kernel(const int* __restrict__ dst, int* __restrict__ counts)
{
    int e = blockIdx.x * blockDim.x + threadIdx.x;
    if (e < N_EDGES_C) atomicAdd(&counts[dst[e]], 1);
}

__global__ void scan_kernel(const int* __restrict__ counts,
                            int* __restrict__ row_ptr, int* __restrict__ cursor)
{
    __shared__ int part[1024];
    const int t = threadIdx.x;
    const int CH = 20;                // 1024*20 = 20480 >= 20000
    const int base = t * CH;
    int s = 0;
    for (int i = 0; i < CH; ++i) {
        int idx = base + i;
        if (idx < N_NODES_C) s += counts[idx];
    }
    part[t] = s;
    __syncthreads();
    for (int d = 1; d < 1024; d <<= 1) {
        int val = (t >= d) ? part[t - d] : 0;
        __syncthreads();
        part[t] += val;
        __syncthreads();
    }
    int run = part[t] - s;            // exclusive prefix of this chunk
    for (int i = 0; i < CH; ++i) {
        int idx = base + i;
        if (idx < N_NODES_C) {
            row_ptr[idx] = run;
            cursor[idx]  = run;
            run += counts[idx];
        }
    }
    if (t == 1023) row_ptr[N_NODES_C] = part[1023];
}

__global__ void scatter_kernel(const int* __restrict__ ei, const int* __restrict__ ea,
                               int* __restrict__ cursor, int* __restrict__ packed)
{
    int e = blockIdx.x * blockDim.x + threadIdx.x;
    if (e >= N_EDGES_C) return;
    int src  = ei[e];
    int dst  = ei[N_EDGES_C + e];
    int code = ea[e * 3] * 25 + ea[e * 3 + 1] * 5 + ea[e * 3 + 2];
    int p = atomicAdd(&cursor[dst], 1);
    packed[p] = (src << 7) | code;
}

// ---------------------------------------------------------------------------
// Per-layer node projections. 256 threads = 4 groups of 64; group g owns
// matrix g and holds its weight column W[:,j] in 64 VGPRs. 32 nodes/block
// staged in LDS, read back as wave-broadcast float4 (4 FMA / ds_read_b128).
// ---------------------------------------------------------------------------
#define QKVS_NPB 32
__global__ __launch_bounds__(256) void qkvs_kernel(
    const float* __restrict__ x,
    const float* __restrict__ Wq, const float* __restrict__ bq,
    const float* __restrict__ Wk, const float* __restrict__ bk,
    const float* __restrict__ Wv, const float* __restrict__ bv,
    const float* __restrict__ Ws, const float* __restrict__ bs,
    float* __restrict__ q, float* __restrict__ k,
    float* __restrict__ v, float* __restrict__ xs)
{
    __shared__ float4 xr[QKVS_NPB * 16];
    const int g = threadIdx.x >> 6;       // matrix index (wave-uniform)
    const int j = threadIdx.x & 63;       // output channel

    const float* Wg; const float* bgp; float* og;
    if      (g == 0) { Wg = Wq; bgp = bq; og = q;  }
    else if (g == 1) { Wg = Wk; bgp = bk; og = k;  }
    else if (g == 2) { Wg = Wv; bgp = bv; og = v;  }
    else             { Wg = Ws; bgp = bs; og = xs; }

    float w[64];
    #pragma unroll
    for (int i = 0; i < 64; ++i) w[i] = Wg[i * 64 + j];
    const float bias = bgp[j];

    const float4* xg = (const float4*)(x + (size_t)blockIdx.x * QKVS_NPB * 64);
    for (int idx = threadIdx.x; idx < QKVS_NPB * 16; idx += 256) xr[idx] = xg[idx];
    __syncthreads();

    const int n0 = blockIdx.x * QKVS_NPB;
    for (int n = 0; n < QKVS_NPB; ++n) {
        float acc = bias;
        #pragma unroll
        for (int i = 0; i < 16; ++i) {
            float4 xi = xr[n * 16 + i];
            acc = fmaf(xi.x, w[4 * i + 0], acc);
            acc = fmaf(xi.y, w[4 * i + 1], acc);
            acc = fmaf(xi.z, w[4 * i + 2], acc);
            acc = fmaf(xi.w, w[4 * i + 3], acc);
        }
        og[(size_t)(n0 + n) * 64 + j] = acc;
    }
}

// ---------------------------------------------------------------------------
// Attention: one wave per node, 4 edges in flight per iteration.
// slot s = lane>>4 owns one edge; lane owns channels 4r..4r+3 (head r>>2).
// Per-head dot reduces with shfl_xor 1,2; per-slot online-softmax states
// merge at the end with shfl_xor 16,32. Next iteration's k/v/e gathers are
// prefetched before the current softmax math to hide L2 latency.
// ---------------------------------------------------------------------------
__global__ __launch_bounds__(256) void attn_kernel(
    const float* __restrict__ q, const float* __restrict__ k,
    const float* __restrict__ v, const float* __restrict__ xs,
    const float* __restrict__ etab_l, const int* __restrict__ row_ptr,
    const int* __restrict__ packed, float* __restrict__ x)
{
    __shared__ float et[NCODES_C * HID_C];
    {
        const float4* s4 = (const float4*)etab_l;
        float4* d4 = (float4*)et;
        for (int i = threadIdx.x; i < NCODES_C * HID_C / 4; i += 256) d4[i] = s4[i];
    }
    __syncthreads();

    const int wv   = threadIdx.x >> 6;
    const int lane = threadIdx.x & 63;
    const int s    = lane >> 4;          // edge slot 0..3
    const int r    = lane & 15;          // channel-group index
    const int c0   = r * 4;              // channels c0..c0+3 (head r>>2)

    for (int nn = 0; nn < 2; ++nn) {
        const int n = blockIdx.x * 8 + wv * 2 + nn;
        const float4 q4 = *(const float4*)(q + (size_t)n * 64 + c0);
        const int start = row_ptr[n], end = row_ptr[n + 1];

        float m = -3.4e38f, den = 0.f;
        float4 acc = {0.f, 0.f, 0.f, 0.f};

        for (int base = start; base < end; base += 64) {
            const int cnt = min(64, end - base);
            int pk_l = (base + lane < end) ? packed[base + lane] : 0;
            const int nit = (cnt + 3) >> 2;

            // prologue: loads for t = 0
            int idx = s;
            bool vcur = idx < cnt;
            int pk = __shfl(pk_l, idx, 64);
            int src = pk >> 7, code = pk & 127;
            float4 k4 = *(const float4*)(k + (size_t)src * 64 + c0);
            float4 v4 = *(const float4*)(v + (size_t)src * 64 + c0);
            float4 e4 = *(const float4*)(et + code * 64 + c0);

            for (int t = 0; t < nit; ++t) {
                float4 k4n, v4n, e4n; bool vnext = false;
                if (t + 1 < nit) {
                    int idx2 = (t + 1) * 4 + s;          // <= 63 always
                    vnext = idx2 < cnt;
                    int pkn = __shfl(pk_l, idx2, 64);
                    int srcn = pkn >> 7, coden = pkn & 127;
                    k4n = *(const float4*)(k + (size_t)srcn * 64 + c0);
                    v4n = *(const float4*)(v + (size_t)srcn * 64 + c0);
                    e4n = *(const float4*)(et + coden * 64 + c0);
                }
                // current edge
                float p = q4.x * (k4.x + e4.x) + q4.y * (k4.y + e4.y)
                        + q4.z * (k4.z + e4.z) + q4.w * (k4.w + e4.w);
                p += __shfl_xor(p, 1, 64);
                p += __shfl_xor(p, 2, 64);
                const float logit = p * 0.25f;           // 1/sqrt(16)
                const float mn = fmaxf(m, logit);
                const float sc = __expf(m - mn);
                const float ex = vcur ? __expf(logit - mn) : 0.f;
                den = den * sc + ex;
                acc.x = acc.x * sc + ex * (v4.x + e4.x);
                acc.y = acc.y * sc + ex * (v4.y + e4.y);
                acc.z = acc.z * sc + ex * (v4.z + e4.z);
                acc.w = acc.w * sc + ex * (v4.w + e4.w);
                m = mn;
                k4 = k4n; v4 = v4n; e4 = e4n; vcur = vnext;
            }
        }

        // merge the 4 slots' online-softmax states
        #pragma unroll
        for (int off = 16; off <= 32; off <<= 1) {
            float m2 = __shfl_xor(m, off, 64);
            float d2 = __shfl_xor(den, off, 64);
            float ax = __shfl_xor(acc.x, off, 64);
            float ay = __shfl_xor(acc.y, off, 64);
            float az = __shfl_xor(acc.z, off, 64);
            float aw = __shfl_xor(acc.w, off, 64);
            float mn = fmaxf(m, m2);
            float s1 = __expf(m - mn), s2 = __expf(m2 - mn);
            den  = den  * s1 + d2 * s2;
            acc.x = acc.x * s1 + ax * s2;
            acc.y = acc.y * s1 + ay * s2;
            acc.z = acc.z * s1 + az * s2;
            acc.w = acc.w * s1 + aw * s2;
            m = mn;
        }

        if (s == 0) {
            const float inv = 1.f / (den + 1e-16f);
            float4 xs4 = *(const float4*)(xs + (size_t)n * 64 + c0);
            float4 o;
            o.x = fmaxf(acc.x * inv + xs4.x, 0.f);
            o.y = fmaxf(acc.y * inv + xs4.y, 0.f);
            o.z = fmaxf(acc.z * inv + xs4.z, 0.f);
            o.w = fmaxf(acc.w * inv + xs4.w, 0.f);
            *(float4*)(x + (size_t)n * 64 + c0) = o;
        }
    }
}

// ---------------------------------------------------------------------------
// Mean pool: batch is sorted, so accumulate runs in registers and flush one
// atomic per (graph-boundary, channel). Wave handles 128 consecutive nodes.
// ---------------------------------------------------------------------------
__global__ __launch_bounds__(256) void pool_kernel(
    const float* __restrict__ x, const int* __restrict__ batch,
    float* __restrict__ psum, float* __restrict__ pcnt)
{
    const int wave = (blockIdx.x * blockDim.x + threadIdx.x) >> 6;
    const int j = threadIdx.x & 63;
    int n0 = wave * 128;
    if (n0 >= N_NODES_C) return;
    int n1 = min(n0 + 128, N_NODES_C);

    int g = batch[n0];
    float acc = 0.f;
    int run = 0;
    for (int n = n0; n < n1; ++n) {
        int gn = batch[n];
        if (gn != g) {
            atomicAdd(&psum[g * HID_C + j], acc);
            if (j == 0) atomicAdd(&pcnt[g], (float)run);
            acc = 0.f; run = 0; g = gn;
        }
        acc += x[(size_t)n * 64 + j];
        ++run;
    }
    atomicAdd(&psum[g * HID_C + j], acc);
    if (j == 0) atomicAdd(&pcnt[g], (float)run);
}

__global__ void head_kernel(const float* __restrict__ psum, const float* __restrict__ pcnt,
                            const float* __restrict__ fc_W, const float* __restrict__ fc_b,
                            float* __restrict__ out)
{
    __shared__ float p[HID_C];
    const int g = blockIdx.x;
    const int o = threadIdx.x;        // 0..127
    if (o < HID_C) p[o] = psum[g * HID_C + o] / fmaxf(pcnt[g], 1.f);
    __syncthreads();
    float acc = fc_b[o];
    #pragma unroll 8
    for (int i = 0; i < HID_C; ++i)
        acc += p[i] * fc_W[i * OUT_C + o];
    out[g * OUT_C + o] = acc;
}

// ---------------------------------------------------------------------------
extern "C" void kernel_launch(void* const* d_in, const int* in_sizes, int n_in,
                              void* d_out, int out_size, void* d_ws, size_t ws_size,
                              hipStream_t stream)
{
    const int*   x_atom     = (const int*)  d_in[0];
    const int*   edge_index = (const int*)  d_in[1];
    const int*   edge_attr  = (const int*)  d_in[2];
    const int*   batch      = (const int*)  d_in[3];
    const float* lap_pe     = (const float*)d_in[4];
    const float* rwse       = (const float*)d_in[5];
    const float* atom_emb   = (const float*)d_in[6];
    const float* bond_emb   = (const float*)d_in[7];
    const float* sign_W1    = (const float*)d_in[8];
    const float* sign_b1    = (const float*)d_in[9];
    const float* sign_W2    = (const float*)d_in[10];
    const float* sign_b2    = (const float*)d_in[11];
    const float* rwse_W1    = (const float*)d_in[12];
    const float* rwse_b1    = (const float*)d_in[13];
    const float* rwse_W2    = (const float*)d_in[14];
    const float* rwse_b2    = (const float*)d_in[15];
    const float* Wq = (const float*)d_in[16];
    const float* bq = (const float*)d_in[17];
    const float* Wk = (const float*)d_in[18];
    const float* bk = (const float*)d_in[19];
    const float* Wv = (const float*)d_in[20];
    const float* bv = (const float*)d_in[21];
    const float* We = (const float*)d_in[22];
    const float* be = (const float*)d_in[23];
    const float* Ws = (const float*)d_in[24];
    const float* bs = (const float*)d_in[25];
    const float* fc_W = (const float*)d_in[26];
    const float* fc_b = (const float*)d_in[27];
    float* out = (float*)d_out;

    char* ws = (char*)d_ws;
    size_t off = 0;
    auto alloc = [&](size_t bytes) {
        size_t o = off;
        off += (bytes + 255) & ~(size_t)255;
        return o;
    };
    float* x    = (float*)(ws + alloc((size_t)N_NODES_C * HID_C * 4));
    float* q    = (float*)(ws + alloc((size_t)N_NODES_C * HID_C * 4));
    float* k    = (float*)(ws + alloc((size_t)N_NODES_C * HID_C * 4));
    float* v    = (float*)(ws + alloc((size_t)N_NODES_C * HID_C * 4));
    float* xs   = (float*)(ws + alloc((size_t)N_NODES_C * HID_C * 4));
    float* etab = (float*)(ws + alloc((size_t)LAYERS_C * NCODES_C * HID_C * 4));
    int* counts = (int*)  (ws + alloc((size_t)N_NODES_C * 4));
    int* rowp   = (int*)  (ws + alloc((size_t)(N_NODES_C + 1) * 4));
    int* cursor = (int*)  (ws + alloc((size_t)N_NODES_C * 4));
    int* packed = (int*)  (ws + alloc((size_t)N_EDGES_C * 4));
    float* psum = (float*)(ws + alloc((size_t)GRAPHS_C * HID_C * 4));
    float* pcnt = (float*)(ws + alloc((size_t)GRAPHS_C * 4));

    hipMemsetAsync(counts, 0, (size_t)N_NODES_C * 4, stream);
    hipMemsetAsync(psum,   0, (size_t)GRAPHS_C * HID_C * 4, stream);
    hipMemsetAsync(pcnt,   0, (size_t)GRAPHS_C * 4, stream);

    node_encode_kernel<<<N_NODES_C / 4, 256, 0, stream>>>(
        x_atom, lap_pe, rwse, atom_emb,
        sign_W1, sign_b1, sign_W2, sign_b2,
        rwse_W1, rwse_b1, rwse_W2, rwse_b2, x);

    bond_etab_kernel<<<NCODES_C, 64, 0, stream>>>(bond_emb, We, be, etab);

    hist_kernel<<<(N_EDGES_C + 255) / 256, 256, 0, stream>>>(edge_index + N_EDGES_C, counts);
    scan_kernel<<<1, 1024, 0, stream>>>(counts, rowp, cursor);
    scatter_kernel<<<(N_EDGES_C + 255) / 256, 256, 0, stream>>>(edge_index, edge_attr, cursor, packed);

    for (int l = 0; l < LAYERS_C; ++l) {
        qkvs_kernel<<<N_NODES_C / QKVS_NPB, 256, 0, stream>>>(
            x,
            Wq + l * HID_C * HID_C, bq + l * HID_C,
            Wk + l * HID_C * HID_C, bk + l * HID_C,
            Wv + l * HID_C * HID_C, bv + l * HID_C,
            Ws + l * HID_C * HID_C, bs + l * HID_C,
            q, k, v, xs);
        attn_kernel<<<N_NODES_C / 8, 256, 0, stream>>>(
            q, k, v, xs, etab + (size_t)l * NCODES_C * HID_C, rowp, packed, x);
    }

    pool_kernel<<<(N_NODES_C + 511) / 512, 256, 0, stream>>>(x, batch, psum, pcnt);
    head_kernel<<<GRAPHS_C, OUT_C, 0, stream>>>(psum, pcnt, fc_W, fc_b, out);
}

// Round 3
// 454.947 us; speedup vs baseline: 1.5860x; 1.1168x over previous
//
#include <hip/hip_runtime.h>
#include <hip/hip_bf16.h>

#define N_NODES_C 20000
#define N_EDGES_C 640000
#define HID_C 64
#define GRAPHS_C 512
#define OUT_C 128
#define PE_DIM_C 10
#define ATOM_FEATS_C 9
#define ATOM_VOCAB_C 119
#define BOND_VOCAB_C 5
#define LAYERS_C 3
#define NCODES_C 125   // 5*5*5 distinct bond-type combinations

// ---------------------------------------------------------------------------
// Node encoder: 32 nodes/block, 4 waves; wave handles 8 nodes, lane j = chan.
// sW2/rW2 columns preloaded into registers; hidden activations in LDS.
// ---------------------------------------------------------------------------
#define NE_NPB 32
__global__ __launch_bounds__(256) void node_encode_kernel(
    const int* __restrict__ x_atom, const float* __restrict__ lap_pe,
    const float* __restrict__ rwse, const float* __restrict__ atom_emb,
    const float* __restrict__ sW1, const float* __restrict__ sb1,
    const float* __restrict__ sW2, const float* __restrict__ sb2,
    const float* __restrict__ rW1, const float* __restrict__ rb1,
    const float* __restrict__ rW2, const float* __restrict__ rb2,
    float* __restrict__ x)
{
    __shared__ float hs[NE_NPB][HID_C];
    __shared__ float hr[NE_NPB][HID_C];
    const int w = threadIdx.x >> 6;
    const int j = threadIdx.x & 63;
    const int nbase = blockIdx.x * NE_NPB + w * 8;

    float sw2[64], rw2[64];
    #pragma unroll
    for (int i = 0; i < 64; ++i) {
        sw2[i] = sW2[i * 64 + j];
        rw2[i] = rW2[i * 64 + j];
    }
    float sw1[PE_DIM_C], rw1[PE_DIM_C];
    #pragma unroll
    for (int i = 0; i < PE_DIM_C; ++i) {
        sw1[i] = sW1[i * 64 + j];
        rw1[i] = rW1[i * 64 + j];
    }
    const float sb1j = sb1[j], rb1j = rb1[j];
    const float cb = 2.f * sb2[j] + rb2[j];

    float o[8];
    #pragma unroll
    for (int nn = 0; nn < 8; ++nn) {
        const int n = nbase + nn;
        float acc = 0.f;
        #pragma unroll
        for (int f = 0; f < ATOM_FEATS_C; ++f)
            acc += atom_emb[(f * ATOM_VOCAB_C + x_atom[n * ATOM_FEATS_C + f]) * 64 + j];
        float h1 = sb1j, h2 = sb1j, hv = rb1j;
        #pragma unroll
        for (int i = 0; i < PE_DIM_C; ++i) {
            float pv = lap_pe[n * PE_DIM_C + i];
            h1 += pv * sw1[i];
            h2 -= pv * sw1[i];
            hv += rwse[n * PE_DIM_C + i] * rw1[i];
        }
        hs[w * 8 + nn][j] = fmaxf(h1, 0.f) + fmaxf(h2, 0.f);
        hr[w * 8 + nn][j] = fmaxf(hv, 0.f);
        o[nn] = acc + cb;
    }
    __syncthreads();
    #pragma unroll
    for (int nn = 0; nn < 8; ++nn) {
        const float* hsp = hs[w * 8 + nn];
        const float* hrp = hr[w * 8 + nn];
        float a = o[nn];
        #pragma unroll
        for (int i = 0; i < 64; ++i)
            a += hsp[i] * sw2[i] + hrp[i] * rw2[i];
        x[(size_t)(nbase + nn) * 64 + j] = a;
    }
}

// ---------------------------------------------------------------------------
// Bond tables: etab[l][c] = (sum_f bond_emb[f][cf]) @ We[l] + be[l].
// ---------------------------------------------------------------------------
__global__ void bond_etab_kernel(const float* __restrict__ bond_emb,
                                 const float* __restrict__ We,
                                 const float* __restrict__ be,
                                 float* __restrict__ etab)
{
    __shared__ float t[HID_C];
    const int c = blockIdx.x;
    const int j = threadIdx.x;
    const int f0 = c / 25, f1 = (c / 5) % 5, f2 = c % 5;
    float tv = bond_emb[(0 * BOND_VOCAB_C + f0) * HID_C + j]
             + bond_emb[(1 * BOND_VOCAB_C + f1) * HID_C + j]
             + bond_emb[(2 * BOND_VOCAB_C + f2) * HID_C + j];
    t[j] = tv;
    __syncthreads();
    for (int l = 0; l < LAYERS_C; ++l) {
        float o = be[l * HID_C + j];
        #pragma unroll 8
        for (int i = 0; i < HID_C; ++i)
            o += t[i] * We[(l * HID_C + i) * HID_C + j];
        etab[(l * NCODES_C + c) * HID_C + j] = o;
    }
}

// ---------------------------------------------------------------------------
// CSR build: histogram by dst, exclusive scan, scatter packed (src<<7|code).
// ---------------------------------------------------------------------------
__global__ void hist_kernel(const int* __restrict__ dst, int* __restrict__ counts)
{
    int e = blockIdx.x * blockDim.x + threadIdx.x;
    if (e < N_EDGES_C) atomicAdd(&counts[dst[e]], 1);
}

__global__ void scan_kernel(const int* __restrict__ counts,
                            int* __restrict__ row_ptr, int* __restrict__ cursor)
{
    __shared__ int part[1024];
    const int t = threadIdx.x;
    const int CH = 20;                // 1024*20 = 20480 >= 20000
    const int base = t * CH;
    int s = 0;
    for (int i = 0; i < CH; ++i) {
        int idx = base + i;
        if (idx < N_NODES_C) s += counts[idx];
    }
    part[t] = s;
    __syncthreads();
    for (int d = 1; d < 1024; d <<= 1) {
        int val = (t >= d) ? part[t - d] : 0;
        __syncthreads();
        part[t] += val;
        __syncthreads();
    }
    int run = part[t] - s;            // exclusive prefix of this chunk
    for (int i = 0; i < CH; ++i) {
        int idx = base + i;
        if (idx < N_NODES_C) {
            row_ptr[idx] = run;
            cursor[idx]  = run;
            run += counts[idx];
        }
    }
    if (t == 1023) row_ptr[N_NODES_C] = part[1023];
}

__global__ void scatter_kernel(const int* __restrict__ ei, const int* __restrict__ ea,
                               int* __restrict__ cursor, int* __restrict__ packed)
{
    int e = blockIdx.x * blockDim.x + threadIdx.x;
    if (e >= N_EDGES_C) return;
    int src  = ei[e];
    int dst  = ei[N_EDGES_C + e];
    int code = ea[e * 3] * 25 + ea[e * 3 + 1] * 5 + ea[e * 3 + 2];
    int p = atomicAdd(&cursor[dst], 1);
    packed[p] = (src << 7) | code;
}

// ---------------------------------------------------------------------------
// Per-layer node projections. Group g owns matrix g, thread holds W[:,j] in
// 64 VGPRs; 32 nodes staged in LDS read as broadcast float4.
// k and v are written interleaved into kv[n][128] (k: 0..63, v: 64..127).
// ---------------------------------------------------------------------------
#define QKVS_NPB 32
__global__ __launch_bounds__(256) void qkvs_kernel(
    const float* __restrict__ x,
    const float* __restrict__ Wq, const float* __restrict__ bq,
    const float* __restrict__ Wk, const float* __restrict__ bk,
    const float* __restrict__ Wv, const float* __restrict__ bv,
    const float* __restrict__ Ws, const float* __restrict__ bs,
    float* __restrict__ q, float* __restrict__ kv, float* __restrict__ xs)
{
    __shared__ float4 xr[QKVS_NPB * 16];
    const int g = threadIdx.x >> 6;       // matrix index (wave-uniform)
    const int j = threadIdx.x & 63;       // output channel

    const float* Wg; const float* bgp; float* og; int stride, offs;
    if      (g == 0) { Wg = Wq; bgp = bq; og = q;  stride = 64;  offs = 0;  }
    else if (g == 1) { Wg = Wk; bgp = bk; og = kv; stride = 128; offs = 0;  }
    else if (g == 2) { Wg = Wv; bgp = bv; og = kv; stride = 128; offs = 64; }
    else             { Wg = Ws; bgp = bs; og = xs; stride = 64;  offs = 0;  }

    float w[64];
    #pragma unroll
    for (int i = 0; i < 64; ++i) w[i] = Wg[i * 64 + j];
    const float bias = bgp[j];

    const float4* xg = (const float4*)(x + (size_t)blockIdx.x * QKVS_NPB * 64);
    for (int idx = threadIdx.x; idx < QKVS_NPB * 16; idx += 256) xr[idx] = xg[idx];
    __syncthreads();

    const int n0 = blockIdx.x * QKVS_NPB;
    for (int n = 0; n < QKVS_NPB; ++n) {
        float acc = bias;
        #pragma unroll
        for (int i = 0; i < 16; ++i) {
            float4 xi = xr[n * 16 + i];
            acc = fmaf(xi.x, w[4 * i + 0], acc);
            acc = fmaf(xi.y, w[4 * i + 1], acc);
            acc = fmaf(xi.z, w[4 * i + 2], acc);
            acc = fmaf(xi.w, w[4 * i + 3], acc);
        }
        og[(size_t)(n0 + n) * stride + offs + j] = acc;
    }
}

// ---------------------------------------------------------------------------
// Attention: one wave per node, 4 edge slots; slot s = lane>>4 owns an edge,
// lane owns channels 4r..4r+3 (head r>>2). No max-shift: softmax is
// shift-invariant and logits here are O(1), so ex = exp(min(logit,80))
// directly -> no serial rescale chain; den/acc sums are independent.
// et table (32 KB) read straight from L1-resident global memory.
// ---------------------------------------------------------------------------
__global__ __launch_bounds__(256) void attn_kernel(
    const float* __restrict__ q, const float* __restrict__ kv,
    const float* __restrict__ xs, const float* __restrict__ etab_l,
    const int* __restrict__ row_ptr, const int* __restrict__ packed,
    float* __restrict__ x)
{
    const int wv   = threadIdx.x >> 6;
    const int lane = threadIdx.x & 63;
    const int s    = lane >> 4;          // edge slot 0..3
    const int r    = lane & 15;          // channel-group index
    const int c0   = r * 4;              // channels c0..c0+3 (head r>>2)

    for (int nn = 0; nn < 2; ++nn) {
        const int n = blockIdx.x * 8 + wv * 2 + nn;
        const float4 q4 = *(const float4*)(q + (size_t)n * 64 + c0);
        const int start = row_ptr[n], end = row_ptr[n + 1];

        float den = 0.f;
        float4 acc = {0.f, 0.f, 0.f, 0.f};

        for (int base = start; base < end; base += 64) {
            const int cnt = min(64, end - base);
            int pk_l = (base + lane < end) ? packed[base + lane] : 0;
            const int nit = (cnt + 3) >> 2;

            // prologue: loads for t = 0
            bool vcur = s < cnt;
            int pk = __shfl(pk_l, s, 64);
            int src = pk >> 7, code = pk & 127;
            const float* kvp = kv + (size_t)src * 128;
            float4 k4 = *(const float4*)(kvp + c0);
            float4 v4 = *(const float4*)(kvp + 64 + c0);
            float4 e4 = *(const float4*)(etab_l + code * 64 + c0);

            for (int t = 0; t < nit; ++t) {
                float4 k4n, v4n, e4n; bool vnext = false;
                if (t + 1 < nit) {
                    int idx2 = (t + 1) * 4 + s;          // <= 63 always
                    vnext = idx2 < cnt;
                    int pkn = __shfl(pk_l, idx2, 64);
                    int srcn = pkn >> 7, coden = pkn & 127;
                    const float* kvn = kv + (size_t)srcn * 128;
                    k4n = *(const float4*)(kvn + c0);
                    v4n = *(const float4*)(kvn + 64 + c0);
                    e4n = *(const float4*)(etab_l + coden * 64 + c0);
                }
                float p = q4.x * (k4.x + e4.x) + q4.y * (k4.y + e4.y)
                        + q4.z * (k4.z + e4.z) + q4.w * (k4.w + e4.w);
                p += __shfl_xor(p, 1, 64);
                p += __shfl_xor(p, 2, 64);
                const float logit = fminf(p * 0.25f, 80.f);  // 1/sqrt(16), overflow guard
                const float ex = vcur ? __expf(logit) : 0.f;
                den += ex;
                acc.x = fmaf(ex, v4.x + e4.x, acc.x);
                acc.y = fmaf(ex, v4.y + e4.y, acc.y);
                acc.z = fmaf(ex, v4.z + e4.z, acc.z);
                acc.w = fmaf(ex, v4.w + e4.w, acc.w);
                k4 = k4n; v4 = v4n; e4 = e4n; vcur = vnext;
            }
        }

        // sum the 4 slots' partials
        #pragma unroll
        for (int off = 16; off <= 32; off <<= 1) {
            den   += __shfl_xor(den,   off, 64);
            acc.x += __shfl_xor(acc.x, off, 64);
            acc.y += __shfl_xor(acc.y, off, 64);
            acc.z += __shfl_xor(acc.z, off, 64);
            acc.w += __shfl_xor(acc.w, off, 64);
        }

        if (s == 0) {
            const float inv = 1.f / (den + 1e-16f);
            float4 xs4 = *(const float4*)(xs + (size_t)n * 64 + c0);
            float4 o;
            o.x = fmaxf(acc.x * inv + xs4.x, 0.f);
            o.y = fmaxf(acc.y * inv + xs4.y, 0.f);
            o.z = fmaxf(acc.z * inv + xs4.z, 0.f);
            o.w = fmaxf(acc.w * inv + xs4.w, 0.f);
            *(float4*)(x + (size_t)n * 64 + c0) = o;
        }
    }
}

// ---------------------------------------------------------------------------
// Graph boundaries: gstart[g] = lower_bound(batch, g), g in [0,512].
// ---------------------------------------------------------------------------
__global__ void gbounds_kernel(const int* __restrict__ batch, int* __restrict__ gstart)
{
    int g = blockIdx.x * blockDim.x + threadIdx.x;
    if (g > GRAPHS_C) return;
    int lo = 0, hi = N_NODES_C;
    while (lo < hi) {
        int mid = (lo + hi) >> 1;
        if (batch[mid] < g) lo = mid + 1; else hi = mid;
    }
    gstart[g] = lo;
}

// ---------------------------------------------------------------------------
// Fused mean-pool + classifier head: one 128-thread block per graph.
// ---------------------------------------------------------------------------
__global__ __launch_bounds__(128) void pool_head_kernel(
    const float* __restrict__ x, const int* __restrict__ gstart,
    const float* __restrict__ fc_W, const float* __restrict__ fc_b,
    float* __restrict__ out)
{
    __shared__ float tmp[128];
    __shared__ float p[HID_C];
    const int g = blockIdx.x;
    const int s0 = gstart[g], s1 = gstart[g + 1];
    const int ch = threadIdx.x & 63;
    const int half = threadIdx.x >> 6;

    float acc = 0.f;
    for (int n = s0 + half; n < s1; n += 2)
        acc += x[(size_t)n * 64 + ch];
    tmp[threadIdx.x] = acc;
    __syncthreads();
    if (half == 0)
        p[ch] = (tmp[ch] + tmp[64 + ch]) / fmaxf((float)(s1 - s0), 1.f);
    __syncthreads();

    const int o = threadIdx.x;            // 0..127
    float r = fc_b[o];
    #pragma unroll 8
    for (int i = 0; i < HID_C; ++i)
        r = fmaf(p[i], fc_W[i * OUT_C + o], r);
    out[(size_t)g * OUT_C + o] = r;
}

// ---------------------------------------------------------------------------
extern "C" void kernel_launch(void* const* d_in, const int* in_sizes, int n_in,
                              void* d_out, int out_size, void* d_ws, size_t ws_size,
                              hipStream_t stream)
{
    const int*   x_atom     = (const int*)  d_in[0];
    const int*   edge_index = (const int*)  d_in[1];
    const int*   edge_attr  = (const int*)  d_in[2];
    const int*   batch      = (const int*)  d_in[3];
    const float* lap_pe     = (const float*)d_in[4];
    const float* rwse       = (const float*)d_in[5];
    const float* atom_emb   = (const float*)d_in[6];
    const float* bond_emb   = (const float*)d_in[7];
    const float* sign_W1    = (const float*)d_in[8];
    const float* sign_b1    = (const float*)d_in[9];
    const float* sign_W2    = (const float*)d_in[10];
    const float* sign_b2    = (const float*)d_in[11];
    const float* rwse_W1    = (const float*)d_in[12];
    const float* rwse_b1    = (const float*)d_in[13];
    const float* rwse_W2    = (const float*)d_in[14];
    const float* rwse_b2    = (const float*)d_in[15];
    const float* Wq = (const float*)d_in[16];
    const float* bq = (const float*)d_in[17];
    const float* Wk = (const float*)d_in[18];
    const float* bk = (const float*)d_in[19];
    const float* Wv = (const float*)d_in[20];
    const float* bv = (const float*)d_in[21];
    const float* We = (const float*)d_in[22];
    const float* be = (const float*)d_in[23];
    const float* Ws = (const float*)d_in[24];
    const float* bs = (const float*)d_in[25];
    const float* fc_W = (const float*)d_in[26];
    const float* fc_b = (const float*)d_in[27];
    float* out = (float*)d_out;

    char* ws = (char*)d_ws;
    size_t off = 0;
    auto alloc = [&](size_t bytes) {
        size_t o = off;
        off += (bytes + 255) & ~(size_t)255;
        return o;
    };
    float* x    = (float*)(ws + alloc((size_t)N_NODES_C * HID_C * 4));
    float* q    = (float*)(ws + alloc((size_t)N_NODES_C * HID_C * 4));
    float* kv   = (float*)(ws + alloc((size_t)N_NODES_C * HID_C * 2 * 4));
    float* xs   = (float*)(ws + alloc((size_t)N_NODES_C * HID_C * 4));
    float* etab = (float*)(ws + alloc((size_t)LAYERS_C * NCODES_C * HID_C * 4));
    int* counts = (int*)  (ws + alloc((size_t)N_NODES_C * 4));
    int* rowp   = (int*)  (ws + alloc((size_t)(N_NODES_C + 1) * 4));
    int* cursor = (int*)  (ws + alloc((size_t)N_NODES_C * 4));
    int* packed = (int*)  (ws + alloc((size_t)N_EDGES_C * 4));
    int* gstart = (int*)  (ws + alloc((size_t)(GRAPHS_C + 1) * 4));

    hipMemsetAsync(counts, 0, (size_t)N_NODES_C * 4, stream);

    node_encode_kernel<<<N_NODES_C / NE_NPB, 256, 0, stream>>>(
        x_atom, lap_pe, rwse, atom_emb,
        sign_W1, sign_b1, sign_W2, sign_b2,
        rwse_W1, rwse_b1, rwse_W2, rwse_b2, x);

    bond_etab_kernel<<<NCODES_C, 64, 0, stream>>>(bond_emb, We, be, etab);

    hist_kernel<<<(N_EDGES_C + 255) / 256, 256, 0, stream>>>(edge_index + N_EDGES_C, counts);
    scan_kernel<<<1, 1024, 0, stream>>>(counts, rowp, cursor);
    scatter_kernel<<<(N_EDGES_C + 255) / 256, 256, 0, stream>>>(edge_index, edge_attr, cursor, packed);
    gbounds_kernel<<<1, 1024, 0, stream>>>(batch, gstart);

    for (int l = 0; l < LAYERS_C; ++l) {
        qkvs_kernel<<<N_NODES_C / QKVS_NPB, 256, 0, stream>>>(
            x,
            Wq + l * HID_C * HID_C, bq + l * HID_C,
            Wk + l * HID_C * HID_C, bk + l * HID_C,
            Wv + l * HID_C * HID_C, bv + l * HID_C,
            Ws + l * HID_C * HID_C, bs + l * HID_C,
            q, kv, xs);
        attn_kernel<<<N_NODES_C / 8, 256, 0, stream>>>(
            q, kv, xs, etab + (size_t)l * NCODES_C * HID_C, rowp, packed, x);
    }

    pool_head_kernel<<<GRAPHS_C, 128, 0, stream>>>(x, gstart, fc_W, fc_b, out);
}

// Round 6
// 414.031 us; speedup vs baseline: 1.7428x; 1.0988x over previous
//
#include <hip/hip_runtime.h>
#include <hip/hip_bf16.h>

#define N_NODES_C 20000
#define N_NODES_PAD 20032
#define N_EDGES_C 640000
#define HID_C 64
#define GRAPHS_C 512
#define OUT_C 128
#define PE_DIM_C 10
#define ATOM_FEATS_C 9
#define ATOM_VOCAB_C 119
#define BOND_VOCAB_C 5
#define LAYERS_C 3
#define NCODES_C 125   // 5*5*5 distinct bond-type combinations

typedef __attribute__((ext_vector_type(8))) short bf16x8;
typedef __attribute__((ext_vector_type(4))) float f32x4;

static __device__ __forceinline__ void split_bf(float f, unsigned short& hi, unsigned short& lo)
{
    __hip_bfloat16 h = __float2bfloat16(f);
    float fh = __bfloat162float(h);
    __hip_bfloat16 l = __float2bfloat16(f - fh);
    hi = *reinterpret_cast<unsigned short*>(&h);
    lo = *reinterpret_cast<unsigned short*>(&l);
}

// ---------------------------------------------------------------------------
// Node encoder: atom-emb sum + SignNet(±lap_pe) + RWSE MLP. Also emits the
// split-bf16 copy of x used by the MFMA projection kernel.
// ---------------------------------------------------------------------------
#define NE_NPB 32
__global__ __launch_bounds__(256) void node_encode_kernel(
    const int* __restrict__ x_atom, const float* __restrict__ lap_pe,
    const float* __restrict__ rwse, const float* __restrict__ atom_emb,
    const float* __restrict__ sW1, const float* __restrict__ sb1,
    const float* __restrict__ sW2, const float* __restrict__ sb2,
    const float* __restrict__ rW1, const float* __restrict__ rb1,
    const float* __restrict__ rW2, const float* __restrict__ rb2,
    float* __restrict__ x, unsigned short* __restrict__ xhi,
    unsigned short* __restrict__ xlo)
{
    __shared__ float hs[NE_NPB][HID_C];
    __shared__ float hr[NE_NPB][HID_C];
    const int w = threadIdx.x >> 6;
    const int j = threadIdx.x & 63;
    const int nbase = blockIdx.x * NE_NPB + w * 8;

    float sw2[64], rw2[64];
    #pragma unroll
    for (int i = 0; i < 64; ++i) {
        sw2[i] = sW2[i * 64 + j];
        rw2[i] = rW2[i * 64 + j];
    }
    float sw1[PE_DIM_C], rw1[PE_DIM_C];
    #pragma unroll
    for (int i = 0; i < PE_DIM_C; ++i) {
        sw1[i] = sW1[i * 64 + j];
        rw1[i] = rW1[i * 64 + j];
    }
    const float sb1j = sb1[j], rb1j = rb1[j];
    const float cb = 2.f * sb2[j] + rb2[j];

    float o[8];
    #pragma unroll
    for (int nn = 0; nn < 8; ++nn) {
        const int n = nbase + nn;
        float acc = 0.f;
        #pragma unroll
        for (int f = 0; f < ATOM_FEATS_C; ++f)
            acc += atom_emb[(f * ATOM_VOCAB_C + x_atom[n * ATOM_FEATS_C + f]) * 64 + j];
        float h1 = sb1j, h2 = sb1j, hv = rb1j;
        #pragma unroll
        for (int i = 0; i < PE_DIM_C; ++i) {
            float pv = lap_pe[n * PE_DIM_C + i];
            h1 += pv * sw1[i];
            h2 -= pv * sw1[i];
            hv += rwse[n * PE_DIM_C + i] * rw1[i];
        }
        hs[w * 8 + nn][j] = fmaxf(h1, 0.f) + fmaxf(h2, 0.f);
        hr[w * 8 + nn][j] = fmaxf(hv, 0.f);
        o[nn] = acc + cb;
    }
    __syncthreads();
    #pragma unroll
    for (int nn = 0; nn < 8; ++nn) {
        const float* hsp = hs[w * 8 + nn];
        const float* hrp = hr[w * 8 + nn];
        float a = o[nn];
        #pragma unroll
        for (int i = 0; i < 64; ++i)
            a += hsp[i] * sw2[i] + hrp[i] * rw2[i];
        const size_t idx = (size_t)(nbase + nn) * 64 + j;
        x[idx] = a;
        unsigned short hi, lo;
        split_bf(a, hi, lo);
        xhi[idx] = hi;
        xlo[idx] = lo;
    }
}

// ---------------------------------------------------------------------------
// Bond tables: etab[l][c] = (sum_f bond_emb[f][cf]) @ We[l] + be[l].
// ---------------------------------------------------------------------------
__global__ void bond_etab_kernel(const float* __restrict__ bond_emb,
                                 const float* __restrict__ We,
                                 const float* __restrict__ be,
                                 float* __restrict__ etab)
{
    __shared__ float t[HID_C];
    const int c = blockIdx.x;
    const int j = threadIdx.x;
    const int f0 = c / 25, f1 = (c / 5) % 5, f2 = c % 5;
    float tv = bond_emb[(0 * BOND_VOCAB_C + f0) * HID_C + j]
             + bond_emb[(1 * BOND_VOCAB_C + f1) * HID_C + j]
             + bond_emb[(2 * BOND_VOCAB_C + f2) * HID_C + j];
    t[j] = tv;
    __syncthreads();
    for (int l = 0; l < LAYERS_C; ++l) {
        float o = be[l * HID_C + j];
        #pragma unroll 8
        for (int i = 0; i < HID_C; ++i)
            o += t[i] * We[(l * HID_C + i) * HID_C + j];
        etab[(l * NCODES_C + c) * HID_C + j] = o;
    }
}

// ---------------------------------------------------------------------------
// Weight prep: split Wq/Wk/Wv/Ws into bf16 hi/lo, transposed to [n][k] so
// MFMA B-fragments are contiguous 16B loads. bt[l][mat*64+j][k].
// ---------------------------------------------------------------------------
__global__ void prep_w_kernel(const float* __restrict__ Wq, const float* __restrict__ Wk,
                              const float* __restrict__ Wv, const float* __restrict__ Ws,
                              unsigned short* __restrict__ bt_hi, unsigned short* __restrict__ bt_lo)
{
    const int idx = blockIdx.x * 256 + threadIdx.x;   // 3*4*64*64 = 49152
    const int j = idx & 63;
    const int k = (idx >> 6) & 63;
    const int mat = (idx >> 12) & 3;                  // uniform within a block
    const int l = idx >> 14;
    const float* W;
    if      (mat == 0) W = Wq;
    else if (mat == 1) W = Wk;
    else if (mat == 2) W = Wv;
    else               W = Ws;
    const float wv = W[(size_t)l * 4096 + k * 64 + j];
    unsigned short hi, lo;
    split_bf(wv, hi, lo);
    const size_t o = ((size_t)l * 256 + mat * 64 + j) * 64 + k;
    bt_hi[o] = hi;
    bt_lo[o] = lo;
}

// ---------------------------------------------------------------------------
// CSR build: histogram by dst, exclusive scan, scatter packed (src<<7|code).
// ---------------------------------------------------------------------------
__global__ void hist_kernel(const int* __restrict__ dst, int* __restrict__ counts)
{
    int e = blockIdx.x * blockDim.x + threadIdx.x;
    if (e < N_EDGES_C) atomicAdd(&counts[dst[e]], 1);
}

__global__ void scan_kernel(const int* __restrict__ counts,
                            int* __restrict__ row_ptr, int* __restrict__ cursor)
{
    __shared__ int part[1024];
    const int t = threadIdx.x;
    const int CH = 20;                // 1024*20 = 20480 >= 20000
    const int base = t * CH;
    int s = 0;
    for (int i = 0; i < CH; ++i) {
        int idx = base + i;
        if (idx < N_NODES_C) s += counts[idx];
    }
    part[t] = s;
    __syncthreads();
    for (int d = 1; d < 1024; d <<= 1) {
        int val = (t >= d) ? part[t - d] : 0;
        __syncthreads();
        part[t] += val;
        __syncthreads();
    }
    int run = part[t] - s;            // exclusive prefix of this chunk
    for (int i = 0; i < CH; ++i) {
        int idx = base + i;
        if (idx < N_NODES_C) {
            row_ptr[idx] = run;
            cursor[idx]  = run;
            run += counts[idx];
        }
    }
    if (t == 1023) row_ptr[N_NODES_C] = part[1023];
}

__global__ void scatter_kernel(const int* __restrict__ ei, const int* __restrict__ ea,
                               int* __restrict__ cursor, int* __restrict__ packed)
{
    int e = blockIdx.x * blockDim.x + threadIdx.x;
    if (e >= N_EDGES_C) return;
    int src  = ei[e];
    int dst  = ei[N_EDGES_C + e];
    int code = ea[e * 3] * 25 + ea[e * 3 + 1] * 5 + ea[e * 3 + 2];
    int p = atomicAdd(&cursor[dst], 1);
    packed[p] = (src << 7) | code;
}

// ---------------------------------------------------------------------------
// Projections via split-bf16 MFMA: [20000x64] @ [64x256] (q|k|v|xs).
// Block = 4 waves; wave w owns matrix w, 64 rows x 64 cols, K=64.
// acc += Ahi*Bhi + Ahi*Blo + Alo*Bhi  (f32 accum; lo*lo dropped ~2^-18).
// ---------------------------------------------------------------------------
template<int L>
__global__ __launch_bounds__(256) void qkvs_mfma_kernel(
    const unsigned short* __restrict__ xhi, const unsigned short* __restrict__ xlo,
    const unsigned short* __restrict__ bt_hi, const unsigned short* __restrict__ bt_lo,
    const float* __restrict__ bq, const float* __restrict__ bk,
    const float* __restrict__ bv, const float* __restrict__ bs,
    float* __restrict__ q, float* __restrict__ kv, float* __restrict__ xs)
{
    const int w    = threadIdx.x >> 6;   // matrix 0..3
    const int lane = threadIdx.x & 63;
    const int lr   = lane & 15;
    const int lg   = lane >> 4;
    const int m0   = blockIdx.x * 64;

    f32x4 acc[4][4];
    #pragma unroll
    for (int m = 0; m < 4; ++m)
        #pragma unroll
        for (int n = 0; n < 4; ++n)
            acc[m][n] = (f32x4){0.f, 0.f, 0.f, 0.f};

    const unsigned short* bth = bt_hi + (size_t)(w * 64) * 64;
    const unsigned short* btl = bt_lo + (size_t)(w * 64) * 64;

    #pragma unroll
    for (int pass = 0; pass < 3; ++pass) {
        const unsigned short* Ap = (pass == 2) ? xlo : xhi;
        const unsigned short* Bp = (pass == 1) ? btl : bth;
        #pragma unroll
        for (int kk = 0; kk < 2; ++kk) {
            const int kb = kk * 32 + lg * 8;
            bf16x8 a[4], b[4];
            #pragma unroll
            for (int m = 0; m < 4; ++m)
                a[m] = *(const bf16x8*)(Ap + (size_t)(m0 + m * 16 + lr) * 64 + kb);
            #pragma unroll
            for (int n = 0; n < 4; ++n)
                b[n] = *(const bf16x8*)(Bp + (size_t)(n * 16 + lr) * 64 + kb);
            #pragma unroll
            for (int m = 0; m < 4; ++m)
                #pragma unroll
                for (int n = 0; n < 4; ++n)
                    acc[m][n] = __builtin_amdgcn_mfma_f32_16x16x32_bf16(a[m], b[n], acc[m][n], 0, 0, 0);
        }
    }

    const float* bias = (w == 0) ? bq : (w == 1) ? bk : (w == 2) ? bv : bs;
    float bv4[4];
    #pragma unroll
    for (int n = 0; n < 4; ++n) bv4[n] = bias[n * 16 + lr];

    float* outp; int stride, offs;
    if      (w == 0) { outp = q;  stride = 64;  offs = 0;  }
    else if (w == 1) { outp = kv; stride = 128; offs = 0;  }
    else if (w == 2) { outp = kv; stride = 128; offs = 64; }
    else             { outp = xs; stride = 64;  offs = 0;  }

    #pragma unroll
    for (int m = 0; m < 4; ++m) {
        #pragma unroll
        for (int rr = 0; rr < 4; ++rr) {
            const int row = m0 + m * 16 + lg * 4 + rr;
            if (row < N_NODES_C) {
                #pragma unroll
                for (int n = 0; n < 4; ++n)
                    outp[(size_t)row * stride + offs + n * 16 + lr] = acc[m][n][rr] + bv4[n];
            }
        }
    }
}

// ---------------------------------------------------------------------------
// Attention: one wave per node; slot s = lane>>4 owns an edge, lane owns
// channels 4r..4r+3 (head r>>2). Depth-2 software pipeline (3 reg buffers):
// each stage's k/v/e gathers issue two iterations before consumption.
// No max-shift (softmax shift-invariant; logits O(1), clamped at 80).
// ---------------------------------------------------------------------------
template<int L>
__global__ __launch_bounds__(256) void attn_kernel(
    const float* __restrict__ q, const float* __restrict__ kv,
    const float* __restrict__ xs, const float* __restrict__ etab_l,
    const int* __restrict__ row_ptr, const int* __restrict__ packed,
    float* __restrict__ x, unsigned short* __restrict__ xhi,
    unsigned short* __restrict__ xlo)
{
    const int lane = threadIdx.x & 63;
    const int s    = lane >> 4;
    const int r    = lane & 15;
    const int c0   = r * 4;
    const int n    = blockIdx.x * 4 + (threadIdx.x >> 6);

    const float4 q4 = *(const float4*)(q + (size_t)n * 64 + c0);
    const int start = row_ptr[n], end = row_ptr[n + 1];

    float den = 0.f;
    float4 acc = {0.f, 0.f, 0.f, 0.f};

    for (int base = start; base < end; base += 64) {
        const int cnt = min(64, end - base);
        int pk_l = (base + lane < end) ? packed[base + lane] : 0;
        const int nit = (cnt + 3) >> 2;

        float4 kA, vA, eA, kB, vB, eB, kC, vC, eC;

        auto LD = [&](int t, float4& kf, float4& vf, float4& ef) {
            int idx = min(t * 4 + s, 63);
            int pk = __shfl(pk_l, idx, 64);
            const float* kvp = kv + (size_t)(pk >> 7) * 128;
            kf = *(const float4*)(kvp + c0);
            vf = *(const float4*)(kvp + 64 + c0);
            ef = *(const float4*)(etab_l + (pk & 127) * 64 + c0);
        };
        auto PROC = [&](int t, const float4& kf, const float4& vf, const float4& ef) {
            float p = q4.x * (kf.x + ef.x) + q4.y * (kf.y + ef.y)
                    + q4.z * (kf.z + ef.z) + q4.w * (kf.w + ef.w);
            p += __shfl_xor(p, 1, 64);
            p += __shfl_xor(p, 2, 64);
            const float ex = (t * 4 + s < cnt) ? __expf(fminf(p * 0.25f, 80.f)) : 0.f;
            den += ex;
            acc.x = fmaf(ex, vf.x + ef.x, acc.x);
            acc.y = fmaf(ex, vf.y + ef.y, acc.y);
            acc.z = fmaf(ex, vf.z + ef.z, acc.z);
            acc.w = fmaf(ex, vf.w + ef.w, acc.w);
        };

        LD(0, kA, vA, eA);
        LD(1, kB, vB, eB);
        int t = 0;
        for (; t + 3 <= nit; t += 3) {
            LD(t + 2, kC, vC, eC); PROC(t,     kA, vA, eA);
            LD(t + 3, kA, vA, eA); PROC(t + 1, kB, vB, eB);
            LD(t + 4, kB, vB, eB); PROC(t + 2, kC, vC, eC);
        }
        if (t     < nit) PROC(t,     kA, vA, eA);
        if (t + 1 < nit) PROC(t + 1, kB, vB, eB);
    }

    // sum the 4 slots' partials
    #pragma unroll
    for (int off = 16; off <= 32; off <<= 1) {
        den   += __shfl_xor(den,   off, 64);
        acc.x += __shfl_xor(acc.x, off, 64);
        acc.y += __shfl_xor(acc.y, off, 64);
        acc.z += __shfl_xor(acc.z, off, 64);
        acc.w += __shfl_xor(acc.w, off, 64);
    }

    if (s == 0) {
        const float inv = 1.f / (den + 1e-16f);
        float4 xs4 = *(const float4*)(xs + (size_t)n * 64 + c0);
        float4 o;
        o.x = fmaxf(acc.x * inv + xs4.x, 0.f);
        o.y = fmaxf(acc.y * inv + xs4.y, 0.f);
        o.z = fmaxf(acc.z * inv + xs4.z, 0.f);
        o.w = fmaxf(acc.w * inv + xs4.w, 0.f);
        *(float4*)(x + (size_t)n * 64 + c0) = o;

        ushort4 hh, ll;
        split_bf(o.x, hh.x, ll.x);
        split_bf(o.y, hh.y, ll.y);
        split_bf(o.z, hh.z, ll.z);
        split_bf(o.w, hh.w, ll.w);
        *(ushort4*)(xhi + (size_t)n * 64 + c0) = hh;
        *(ushort4*)(xlo + (size_t)n * 64 + c0) = ll;
    }
}

// ---------------------------------------------------------------------------
// Graph boundaries: gstart[g] = lower_bound(batch, g), g in [0,512].
// ---------------------------------------------------------------------------
__global__ void gbounds_kernel(const int* __restrict__ batch, int* __restrict__ gstart)
{
    int g = blockIdx.x * blockDim.x + threadIdx.x;
    if (g > GRAPHS_C) return;
    int lo = 0, hi = N_NODES_C;
    while (lo < hi) {
        int mid = (lo + hi) >> 1;
        if (batch[mid] < g) lo = mid + 1; else hi = mid;
    }
    gstart[g] = lo;
}

// ---------------------------------------------------------------------------
// Fused mean-pool + classifier head: one 128-thread block per graph.
// ---------------------------------------------------------------------------
__global__ __launch_bounds__(128) void pool_head_kernel(
    const float* __restrict__ x, const int* __restrict__ gstart,
    const float* __restrict__ fc_W, const float* __restrict__ fc_b,
    float* __restrict__ out)
{
    __shared__ float tmp[128];
    __shared__ float p[HID_C];
    const int g = blockIdx.x;
    const int s0 = gstart[g], s1 = gstart[g + 1];
    const int ch = threadIdx.x & 63;
    const int half = threadIdx.x >> 6;

    float acc = 0.f;
    for (int n = s0 + half; n < s1; n += 2)
        acc += x[(size_t)n * 64 + ch];
    tmp[threadIdx.x] = acc;
    __syncthreads();
    if (half == 0)
        p[ch] = (tmp[ch] + tmp[64 + ch]) / fmaxf((float)(s1 - s0), 1.f);
    __syncthreads();

    const int o = threadIdx.x;            // 0..127
    float rr = fc_b[o];
    #pragma unroll 8
    for (int i = 0; i < HID_C; ++i)
        rr = fmaf(p[i], fc_W[i * OUT_C + o], rr);
    out[(size_t)g * OUT_C + o] = rr;
}

// ---------------------------------------------------------------------------
extern "C" void kernel_launch(void* const* d_in, const int* in_sizes, int n_in,
                              void* d_out, int out_size, void* d_ws, size_t ws_size,
                              hipStream_t stream)
{
    const int*   x_atom     = (const int*)  d_in[0];
    const int*   edge_index = (const int*)  d_in[1];
    const int*   edge_attr  = (const int*)  d_in[2];
    const int*   batch      = (const int*)  d_in[3];
    const float* lap_pe     = (const float*)d_in[4];
    const float* rwse       = (const float*)d_in[5];
    const float* atom_emb   = (const float*)d_in[6];
    const float* bond_emb   = (const float*)d_in[7];
    const float* sign_W1    = (const float*)d_in[8];
    const float* sign_b1    = (const float*)d_in[9];
    const float* sign_W2    = (const float*)d_in[10];
    const float* sign_b2    = (const float*)d_in[11];
    const float* rwse_W1    = (const float*)d_in[12];
    const float* rwse_b1    = (const float*)d_in[13];
    const float* rwse_W2    = (const float*)d_in[14];
    const float* rwse_b2    = (const float*)d_in[15];
    const float* Wq = (const float*)d_in[16];
    const float* bq = (const float*)d_in[17];
    const float* Wk = (const float*)d_in[18];
    const float* bk = (const float*)d_in[19];
    const float* Wv = (const float*)d_in[20];
    const float* bv = (const float*)d_in[21];
    const float* We = (const float*)d_in[22];
    const float* be = (const float*)d_in[23];
    const float* Ws = (const float*)d_in[24];
    const float* bs = (const float*)d_in[25];
    const float* fc_W = (const float*)d_in[26];
    const float* fc_b = (const float*)d_in[27];
    float* out = (float*)d_out;

    char* ws = (char*)d_ws;
    size_t off = 0;
    auto alloc = [&](size_t bytes) {
        size_t o = off;
        off += (bytes + 255) & ~(size_t)255;
        return o;
    };
    float* x    = (float*)(ws + alloc((size_t)N_NODES_C * HID_C * 4));
    float* q    = (float*)(ws + alloc((size_t)N_NODES_C * HID_C * 4));
    float* kv   = (float*)(ws + alloc((size_t)N_NODES_C * HID_C * 2 * 4));
    float* xs   = (float*)(ws + alloc((size_t)N_NODES_C * HID_C * 4));
    unsigned short* xhi = (unsigned short*)(ws + alloc((size_t)N_NODES_PAD * HID_C * 2));
    unsigned short* xlo = (unsigned short*)(ws + alloc((size_t)N_NODES_PAD * HID_C * 2));
    unsigned short* bt_hi = (unsigned short*)(ws + alloc((size_t)LAYERS_C * 256 * 64 * 2));
    unsigned short* bt_lo = (unsigned short*)(ws + alloc((size_t)LAYERS_C * 256 * 64 * 2));
    float* etab = (float*)(ws + alloc((size_t)LAYERS_C * NCODES_C * HID_C * 4));
    int* counts = (int*)  (ws + alloc((size_t)N_NODES_C * 4));
    int* rowp   = (int*)  (ws + alloc((size_t)(N_NODES_C + 1) * 4));
    int* cursor = (int*)  (ws + alloc((size_t)N_NODES_C * 4));
    int* packed = (int*)  (ws + alloc((size_t)N_EDGES_C * 4));
    int* gstart = (int*)  (ws + alloc((size_t)(GRAPHS_C + 1) * 4));

    hipMemsetAsync(counts, 0, (size_t)N_NODES_C * 4, stream);

    node_encode_kernel<<<N_NODES_C / NE_NPB, 256, 0, stream>>>(
        x_atom, lap_pe, rwse, atom_emb,
        sign_W1, sign_b1, sign_W2, sign_b2,
        rwse_W1, rwse_b1, rwse_W2, rwse_b2, x, xhi, xlo);

    bond_etab_kernel<<<NCODES_C, 64, 0, stream>>>(bond_emb, We, be, etab);
    prep_w_kernel<<<(LAYERS_C * 4 * 64 * 64) / 256, 256, 0, stream>>>(Wq, Wk, Wv, Ws, bt_hi, bt_lo);

    hist_kernel<<<(N_EDGES_C + 255) / 256, 256, 0, stream>>>(edge_index + N_EDGES_C, counts);
    scan_kernel<<<1, 1024, 0, stream>>>(counts, rowp, cursor);
    scatter_kernel<<<(N_EDGES_C + 255) / 256, 256, 0, stream>>>(edge_index, edge_attr, cursor, packed);
    gbounds_kernel<<<1, 1024, 0, stream>>>(batch, gstart);

    const int qkvs_grid = (N_NODES_C + 63) / 64;
    const int attn_grid = N_NODES_C / 4;
    for (int l = 0; l < LAYERS_C; ++l) {
        const unsigned short* bh = bt_hi + (size_t)l * 256 * 64;
        const unsigned short* bl = bt_lo + (size_t)l * 256 * 64;
        const float* el = etab + (size_t)l * NCODES_C * HID_C;
        switch (l) {
        case 0:
            qkvs_mfma_kernel<0><<<qkvs_grid, 256, 0, stream>>>(xhi, xlo, bh, bl,
                bq + l * 64, bk + l * 64, bv + l * 64, bs + l * 64, q, kv, xs);
            attn_kernel<0><<<attn_grid, 256, 0, stream>>>(q, kv, xs, el, rowp, packed, x, xhi, xlo);
            break;
        case 1:
            qkvs_mfma_kernel<1><<<qkvs_grid, 256, 0, stream>>>(xhi, xlo, bh, bl,
                bq + l * 64, bk + l * 64, bv + l * 64, bs + l * 64, q, kv, xs);
            attn_kernel<1><<<attn_grid, 256, 0, stream>>>(q, kv, xs, el, rowp, packed, x, xhi, xlo);
            break;
        default:
            qkvs_mfma_kernel<2><<<qkvs_grid, 256, 0, stream>>>(xhi, xlo, bh, bl,
                bq + l * 64, bk + l * 64, bv + l * 64, bs + l * 64, q, kv, xs);
            attn_kernel<2><<<attn_grid, 256, 0, stream>>>(q, kv, xs, el, rowp, packed, x, xhi, xlo);
            break;
        }
    }

    pool_head_kernel<<<GRAPHS_C, 128, 0, stream>>>(x, gstart, fc_W, fc_b, out);
}

// Round 7
// 410.331 us; speedup vs baseline: 1.7585x; 1.0090x over previous
//
#include <hip/hip_runtime.h>
#include <hip/hip_bf16.h>

#define N_NODES_C 20000
#define N_NODES_PAD 20032
#define N_EDGES_C 640000
#define HID_C 64
#define GRAPHS_C 512
#define OUT_C 128
#define PE_DIM_C 10
#define ATOM_FEATS_C 9
#define ATOM_VOCAB_C 119
#define BOND_VOCAB_C 5
#define LAYERS_C 3
#define NCODES_C 125   // 5*5*5 distinct bond-type combinations

typedef __attribute__((ext_vector_type(8))) short bf16x8;
typedef __attribute__((ext_vector_type(4))) float f32x4;

static __device__ __forceinline__ void split_bf(float f, unsigned short& hi, unsigned short& lo)
{
    __hip_bfloat16 h = __float2bfloat16(f);
    float fh = __bfloat162float(h);
    __hip_bfloat16 l = __float2bfloat16(f - fh);
    hi = *reinterpret_cast<unsigned short*>(&h);
    lo = *reinterpret_cast<unsigned short*>(&l);
}

static __device__ __forceinline__ unsigned short f2bf(float f)
{
    __hip_bfloat16 h = __float2bfloat16(f);
    return *reinterpret_cast<unsigned short*>(&h);
}

// unpack a u32 holding two bf16 (lo half = even channel) to two floats
static __device__ __forceinline__ void bf2x(unsigned u, float& a, float& b)
{
    a = __uint_as_float(u << 16);
    b = __uint_as_float(u & 0xffff0000u);
}

// ---------------------------------------------------------------------------
// Node encoder: atom-emb sum + SignNet(±lap_pe) + RWSE MLP. Emits f32 x and
// the split-bf16 copy (xhi/xlo) for the MFMA projection kernel.
// ---------------------------------------------------------------------------
#define NE_NPB 32
__global__ __launch_bounds__(256) void node_encode_kernel(
    const int* __restrict__ x_atom, const float* __restrict__ lap_pe,
    const float* __restrict__ rwse, const float* __restrict__ atom_emb,
    const float* __restrict__ sW1, const float* __restrict__ sb1,
    const float* __restrict__ sW2, const float* __restrict__ sb2,
    const float* __restrict__ rW1, const float* __restrict__ rb1,
    const float* __restrict__ rW2, const float* __restrict__ rb2,
    float* __restrict__ x, unsigned short* __restrict__ xhi,
    unsigned short* __restrict__ xlo)
{
    __shared__ float hs[NE_NPB][HID_C];
    __shared__ float hr[NE_NPB][HID_C];
    const int w = threadIdx.x >> 6;
    const int j = threadIdx.x & 63;
    const int nbase = blockIdx.x * NE_NPB + w * 8;

    float sw2[64], rw2[64];
    #pragma unroll
    for (int i = 0; i < 64; ++i) {
        sw2[i] = sW2[i * 64 + j];
        rw2[i] = rW2[i * 64 + j];
    }
    float sw1[PE_DIM_C], rw1[PE_DIM_C];
    #pragma unroll
    for (int i = 0; i < PE_DIM_C; ++i) {
        sw1[i] = sW1[i * 64 + j];
        rw1[i] = rW1[i * 64 + j];
    }
    const float sb1j = sb1[j], rb1j = rb1[j];
    const float cb = 2.f * sb2[j] + rb2[j];

    float o[8];
    #pragma unroll
    for (int nn = 0; nn < 8; ++nn) {
        const int n = nbase + nn;
        float acc = 0.f;
        #pragma unroll
        for (int f = 0; f < ATOM_FEATS_C; ++f)
            acc += atom_emb[(f * ATOM_VOCAB_C + x_atom[n * ATOM_FEATS_C + f]) * 64 + j];
        float h1 = sb1j, h2 = sb1j, hv = rb1j;
        #pragma unroll
        for (int i = 0; i < PE_DIM_C; ++i) {
            float pv = lap_pe[n * PE_DIM_C + i];
            h1 += pv * sw1[i];
            h2 -= pv * sw1[i];
            hv += rwse[n * PE_DIM_C + i] * rw1[i];
        }
        hs[w * 8 + nn][j] = fmaxf(h1, 0.f) + fmaxf(h2, 0.f);
        hr[w * 8 + nn][j] = fmaxf(hv, 0.f);
        o[nn] = acc + cb;
    }
    __syncthreads();
    #pragma unroll
    for (int nn = 0; nn < 8; ++nn) {
        const float* hsp = hs[w * 8 + nn];
        const float* hrp = hr[w * 8 + nn];
        float a = o[nn];
        #pragma unroll
        for (int i = 0; i < 64; ++i)
            a += hsp[i] * sw2[i] + hrp[i] * rw2[i];
        const size_t idx = (size_t)(nbase + nn) * 64 + j;
        x[idx] = a;
        unsigned short hi, lo;
        split_bf(a, hi, lo);
        xhi[idx] = hi;
        xlo[idx] = lo;
    }
}

// ---------------------------------------------------------------------------
// Bond tables (bf16): etb[l][c] = bf16( (sum_f bond_emb[f][cf]) @ We[l] + be[l] ).
// ---------------------------------------------------------------------------
__global__ void bond_etab_kernel(const float* __restrict__ bond_emb,
                                 const float* __restrict__ We,
                                 const float* __restrict__ be,
                                 unsigned short* __restrict__ etb)
{
    __shared__ float t[HID_C];
    const int c = blockIdx.x;
    const int j = threadIdx.x;
    const int f0 = c / 25, f1 = (c / 5) % 5, f2 = c % 5;
    float tv = bond_emb[(0 * BOND_VOCAB_C + f0) * HID_C + j]
             + bond_emb[(1 * BOND_VOCAB_C + f1) * HID_C + j]
             + bond_emb[(2 * BOND_VOCAB_C + f2) * HID_C + j];
    t[j] = tv;
    __syncthreads();
    for (int l = 0; l < LAYERS_C; ++l) {
        float o = be[l * HID_C + j];
        #pragma unroll 8
        for (int i = 0; i < HID_C; ++i)
            o += t[i] * We[(l * HID_C + i) * HID_C + j];
        etb[(l * NCODES_C + c) * HID_C + j] = f2bf(o);
    }
}

// ---------------------------------------------------------------------------
// Weight prep: split Wq/Wk/Wv/Ws into bf16 hi/lo, transposed to [n][k] so
// MFMA B-fragments are contiguous 16B loads. bt[l][mat*64+j][k].
// ---------------------------------------------------------------------------
__global__ void prep_w_kernel(const float* __restrict__ Wq, const float* __restrict__ Wk,
                              const float* __restrict__ Wv, const float* __restrict__ Ws,
                              unsigned short* __restrict__ bt_hi, unsigned short* __restrict__ bt_lo)
{
    const int idx = blockIdx.x * 256 + threadIdx.x;   // 3*4*64*64 = 49152
    const int j = idx & 63;
    const int k = (idx >> 6) & 63;
    const int mat = (idx >> 12) & 3;                  // uniform within a block
    const int l = idx >> 14;
    const float* W;
    if      (mat == 0) W = Wq;
    else if (mat == 1) W = Wk;
    else if (mat == 2) W = Wv;
    else               W = Ws;
    const float wv = W[(size_t)l * 4096 + k * 64 + j];
    unsigned short hi, lo;
    split_bf(wv, hi, lo);
    const size_t o = ((size_t)l * 256 + mat * 64 + j) * 64 + k;
    bt_hi[o] = hi;
    bt_lo[o] = lo;
}

// ---------------------------------------------------------------------------
// CSR build: histogram by dst, exclusive scan, scatter packed (src<<7|code).
// ---------------------------------------------------------------------------
__global__ void hist_kernel(const int* __restrict__ dst, int* __restrict__ counts)
{
    int e = blockIdx.x * blockDim.x + threadIdx.x;
    if (e < N_EDGES_C) atomicAdd(&counts[dst[e]], 1);
}

__global__ void scan_kernel(const int* __restrict__ counts,
                            int* __restrict__ row_ptr, int* __restrict__ cursor)
{
    __shared__ int part[1024];
    const int t = threadIdx.x;
    const int CH = 20;                // 1024*20 = 20480 >= 20000
    const int base = t * CH;
    int s = 0;
    for (int i = 0; i < CH; ++i) {
        int idx = base + i;
        if (idx < N_NODES_C) s += counts[idx];
    }
    part[t] = s;
    __syncthreads();
    for (int d = 1; d < 1024; d <<= 1) {
        int val = (t >= d) ? part[t - d] : 0;
        __syncthreads();
        part[t] += val;
        __syncthreads();
    }
    int run = part[t] - s;            // exclusive prefix of this chunk
    for (int i = 0; i < CH; ++i) {
        int idx = base + i;
        if (idx < N_NODES_C) {
            row_ptr[idx] = run;
            cursor[idx]  = run;
            run += counts[idx];
        }
    }
    if (t == 1023) row_ptr[N_NODES_C] = part[1023];
}

__global__ void scatter_kernel(const int* __restrict__ ei, const int* __restrict__ ea,
                               int* __restrict__ cursor, int* __restrict__ packed)
{
    int e = blockIdx.x * blockDim.x + threadIdx.x;
    if (e >= N_EDGES_C) return;
    int src  = ei[e];
    int dst  = ei[N_EDGES_C + e];
    int code = ea[e * 3] * 25 + ea[e * 3 + 1] * 5 + ea[e * 3 + 2];
    int p = atomicAdd(&cursor[dst], 1);
    packed[p] = (src << 7) | code;
}

// ---------------------------------------------------------------------------
// Projections via split-bf16 MFMA: [20000x64] @ [64x256] (q|k|v|xs).
// Block = 4 waves; wave w owns matrix w, 64 rows x 64 cols, K=64.
// acc += Ahi*Bhi + Ahi*Blo + Alo*Bhi  (f32 accum; lo*lo dropped ~2^-18).
// Outputs: qb (bf16 [n][64]), kvb (bf16 [n][128] = k|v), xs (f32).
// ---------------------------------------------------------------------------
template<int L>
__global__ __launch_bounds__(256) void qkvs_mfma_kernel(
    const unsigned short* __restrict__ xhi, const unsigned short* __restrict__ xlo,
    const unsigned short* __restrict__ bt_hi, const unsigned short* __restrict__ bt_lo,
    const float* __restrict__ bq, const float* __restrict__ bk,
    const float* __restrict__ bv, const float* __restrict__ bs,
    unsigned short* __restrict__ qb, unsigned short* __restrict__ kvb,
    float* __restrict__ xs)
{
    const int w    = threadIdx.x >> 6;   // matrix 0..3
    const int lane = threadIdx.x & 63;
    const int lr   = lane & 15;
    const int lg   = lane >> 4;
    const int m0   = blockIdx.x * 64;

    f32x4 acc[4][4];
    #pragma unroll
    for (int m = 0; m < 4; ++m)
        #pragma unroll
        for (int n = 0; n < 4; ++n)
            acc[m][n] = (f32x4){0.f, 0.f, 0.f, 0.f};

    const unsigned short* bth = bt_hi + (size_t)(w * 64) * 64;
    const unsigned short* btl = bt_lo + (size_t)(w * 64) * 64;

    #pragma unroll
    for (int pass = 0; pass < 3; ++pass) {
        const unsigned short* Ap = (pass == 2) ? xlo : xhi;
        const unsigned short* Bp = (pass == 1) ? btl : bth;
        #pragma unroll
        for (int kk = 0; kk < 2; ++kk) {
            const int kb = kk * 32 + lg * 8;
            bf16x8 a[4], b[4];
            #pragma unroll
            for (int m = 0; m < 4; ++m)
                a[m] = *(const bf16x8*)(Ap + (size_t)(m0 + m * 16 + lr) * 64 + kb);
            #pragma unroll
            for (int n = 0; n < 4; ++n)
                b[n] = *(const bf16x8*)(Bp + (size_t)(n * 16 + lr) * 64 + kb);
            #pragma unroll
            for (int m = 0; m < 4; ++m)
                #pragma unroll
                for (int n = 0; n < 4; ++n)
                    acc[m][n] = __builtin_amdgcn_mfma_f32_16x16x32_bf16(a[m], b[n], acc[m][n], 0, 0, 0);
        }
    }

    const float* bias = (w == 0) ? bq : (w == 1) ? bk : (w == 2) ? bv : bs;
    float bv4[4];
    #pragma unroll
    for (int n = 0; n < 4; ++n) bv4[n] = bias[n * 16 + lr];

    #pragma unroll
    for (int m = 0; m < 4; ++m) {
        #pragma unroll
        for (int rr = 0; rr < 4; ++rr) {
            const int row = m0 + m * 16 + lg * 4 + rr;
            if (row < N_NODES_C) {
                #pragma unroll
                for (int n = 0; n < 4; ++n) {
                    const float val = acc[m][n][rr] + bv4[n];
                    const int ch = n * 16 + lr;
                    if      (w == 0) qb [(size_t)row * 64  + ch]      = f2bf(val);
                    else if (w == 1) kvb[(size_t)row * 128 + ch]      = f2bf(val);
                    else if (w == 2) kvb[(size_t)row * 128 + 64 + ch] = f2bf(val);
                    else             xs [(size_t)row * 64  + ch]      = val;
                }
            }
        }
    }
}

// ---------------------------------------------------------------------------
// Attention: one wave per node; 8 edge slots x 8 lanes. Lane owns channels
// 8r..8r+7 (nested in head r>>1); per-edge loads are one uint4 (8 bf16) each
// for k, v, e -> 384B/edge total (vs 768B f32). Head dot = shfl_xor(1);
// cross-slot merge = butterfly 8/16/32. Depth-2 pipeline (3 buffers).
// No max-shift (softmax shift-invariant; logits O(1), clamped at 80).
// ---------------------------------------------------------------------------
template<int L>
__global__ __launch_bounds__(256) void attn_kernel(
    const unsigned short* __restrict__ qb, const unsigned short* __restrict__ kvb,
    const float* __restrict__ xs, const unsigned short* __restrict__ etb_l,
    const int* __restrict__ row_ptr, const int* __restrict__ packed,
    float* __restrict__ x, unsigned short* __restrict__ xhi,
    unsigned short* __restrict__ xlo)
{
    const int lane = threadIdx.x & 63;
    const int s    = lane >> 3;          // edge slot 0..7
    const int r    = lane & 7;           // channel group
    const int c0   = r * 8;              // channels c0..c0+7 (head c0>>4)
    const int n    = blockIdx.x * 4 + (threadIdx.x >> 6);

    float qf[8];
    {
        uint4 qu = *(const uint4*)(qb + (size_t)n * 64 + c0);
        bf2x(qu.x, qf[0], qf[1]); bf2x(qu.y, qf[2], qf[3]);
        bf2x(qu.z, qf[4], qf[5]); bf2x(qu.w, qf[6], qf[7]);
    }
    const int start = row_ptr[n], end = row_ptr[n + 1];

    float den = 0.f;
    float acc[8] = {0.f, 0.f, 0.f, 0.f, 0.f, 0.f, 0.f, 0.f};

    for (int base = start; base < end; base += 64) {
        const int cnt = min(64, end - base);
        int pk_l = (base + lane < end) ? packed[base + lane] : 0;
        const int nit = (cnt + 7) >> 3;

        uint4 kA, vA, eA, kB, vB, eB, kC, vC, eC;

        auto LD = [&](int t, uint4& kf, uint4& vf, uint4& ef) {
            int idx = min(t * 8 + s, 63);
            int pk = __shfl(pk_l, idx, 64);
            const unsigned short* kp = kvb + (size_t)(pk >> 7) * 128;
            kf = *(const uint4*)(kp + c0);
            vf = *(const uint4*)(kp + 64 + c0);
            ef = *(const uint4*)(etb_l + (pk & 127) * 64 + c0);
        };
        auto PROC = [&](int t, const uint4& ku, const uint4& vu, const uint4& eu) {
            const unsigned kw[4] = {ku.x, ku.y, ku.z, ku.w};
            const unsigned vw[4] = {vu.x, vu.y, vu.z, vu.w};
            const unsigned ew[4] = {eu.x, eu.y, eu.z, eu.w};
            float p = 0.f;
            float ve[8];
            #pragma unroll
            for (int i = 0; i < 4; ++i) {
                float ka, kb2, ea, eb, va, vb;
                bf2x(kw[i], ka, kb2);
                bf2x(ew[i], ea, eb);
                bf2x(vw[i], va, vb);
                p = fmaf(qf[2 * i],     ka  + ea, p);
                p = fmaf(qf[2 * i + 1], kb2 + eb, p);
                ve[2 * i]     = va + ea;
                ve[2 * i + 1] = vb + eb;
            }
            p += __shfl_xor(p, 1, 64);               // 16-ch head reduce
            const float ex = (t * 8 + s < cnt) ? __expf(fminf(p * 0.25f, 80.f)) : 0.f;
            den += ex;
            #pragma unroll
            for (int i = 0; i < 8; ++i)
                acc[i] = fmaf(ex, ve[i], acc[i]);
        };

        LD(0, kA, vA, eA);
        LD(1, kB, vB, eB);
        int t = 0;
        for (; t + 3 <= nit; t += 3) {
            LD(t + 2, kC, vC, eC); PROC(t,     kA, vA, eA);
            LD(t + 3, kA, vA, eA); PROC(t + 1, kB, vB, eB);
            LD(t + 4, kB, vB, eB); PROC(t + 2, kC, vC, eC);
        }
        if (t     < nit) PROC(t,     kA, vA, eA);
        if (t + 1 < nit) PROC(t + 1, kB, vB, eB);
    }

    // merge the 8 slots' partials (butterfly over lane bits 3..5)
    #pragma unroll
    for (int off = 8; off <= 32; off <<= 1) {
        den += __shfl_xor(den, off, 64);
        #pragma unroll
        for (int i = 0; i < 8; ++i)
            acc[i] += __shfl_xor(acc[i], off, 64);
    }

    if (s == 0) {
        const float inv = 1.f / (den + 1e-16f);
        const float4 xsa = *(const float4*)(xs + (size_t)n * 64 + c0);
        const float4 xsb = *(const float4*)(xs + (size_t)n * 64 + c0 + 4);
        float o[8];
        o[0] = fmaxf(acc[0] * inv + xsa.x, 0.f);
        o[1] = fmaxf(acc[1] * inv + xsa.y, 0.f);
        o[2] = fmaxf(acc[2] * inv + xsa.z, 0.f);
        o[3] = fmaxf(acc[3] * inv + xsa.w, 0.f);
        o[4] = fmaxf(acc[4] * inv + xsb.x, 0.f);
        o[5] = fmaxf(acc[5] * inv + xsb.y, 0.f);
        o[6] = fmaxf(acc[6] * inv + xsb.z, 0.f);
        o[7] = fmaxf(acc[7] * inv + xsb.w, 0.f);

        float4 oa = {o[0], o[1], o[2], o[3]};
        float4 ob = {o[4], o[5], o[6], o[7]};
        *(float4*)(x + (size_t)n * 64 + c0)     = oa;
        *(float4*)(x + (size_t)n * 64 + c0 + 4) = ob;

        ushort4 ha, hb, la, lb;
        split_bf(o[0], ha.x, la.x); split_bf(o[1], ha.y, la.y);
        split_bf(o[2], ha.z, la.z); split_bf(o[3], ha.w, la.w);
        split_bf(o[4], hb.x, lb.x); split_bf(o[5], hb.y, lb.y);
        split_bf(o[6], hb.z, lb.z); split_bf(o[7], hb.w, lb.w);
        *(ushort4*)(xhi + (size_t)n * 64 + c0)     = ha;
        *(ushort4*)(xhi + (size_t)n * 64 + c0 + 4) = hb;
        *(ushort4*)(xlo + (size_t)n * 64 + c0)     = la;
        *(ushort4*)(xlo + (size_t)n * 64 + c0 + 4) = lb;
    }
}

// ---------------------------------------------------------------------------
// Graph boundaries: gstart[g] = lower_bound(batch, g), g in [0,512].
// ---------------------------------------------------------------------------
__global__ void gbounds_kernel(const int* __restrict__ batch, int* __restrict__ gstart)
{
    int g = blockIdx.x * blockDim.x + threadIdx.x;
    if (g > GRAPHS_C) return;
    int lo = 0, hi = N_NODES_C;
    while (lo < hi) {
        int mid = (lo + hi) >> 1;
        if (batch[mid] < g) lo = mid + 1; else hi = mid;
    }
    gstart[g] = lo;
}

// ---------------------------------------------------------------------------
// Fused mean-pool + classifier head: one 128-thread block per graph.
// ---------------------------------------------------------------------------
__global__ __launch_bounds__(128) void pool_head_kernel(
    const float* __restrict__ x, const int* __restrict__ gstart,
    const float* __restrict__ fc_W, const float* __restrict__ fc_b,
    float* __restrict__ out)
{
    __shared__ float tmp[128];
    __shared__ float p[HID_C];
    const int g = blockIdx.x;
    const int s0 = gstart[g], s1 = gstart[g + 1];
    const int ch = threadIdx.x & 63;
    const int half = threadIdx.x >> 6;

    float acc = 0.f;
    for (int n = s0 + half; n < s1; n += 2)
        acc += x[(size_t)n * 64 + ch];
    tmp[threadIdx.x] = acc;
    __syncthreads();
    if (half == 0)
        p[ch] = (tmp[ch] + tmp[64 + ch]) / fmaxf((float)(s1 - s0), 1.f);
    __syncthreads();

    const int o = threadIdx.x;            // 0..127
    float rr = fc_b[o];
    #pragma unroll 8
    for (int i = 0; i < HID_C; ++i)
        rr = fmaf(p[i], fc_W[i * OUT_C + o], rr);
    out[(size_t)g * OUT_C + o] = rr;
}

// ---------------------------------------------------------------------------
extern "C" void kernel_launch(void* const* d_in, const int* in_sizes, int n_in,
                              void* d_out, int out_size, void* d_ws, size_t ws_size,
                              hipStream_t stream)
{
    const int*   x_atom     = (const int*)  d_in[0];
    const int*   edge_index = (const int*)  d_in[1];
    const int*   edge_attr  = (const int*)  d_in[2];
    const int*   batch      = (const int*)  d_in[3];
    const float* lap_pe     = (const float*)d_in[4];
    const float* rwse       = (const float*)d_in[5];
    const float* atom_emb   = (const float*)d_in[6];
    const float* bond_emb   = (const float*)d_in[7];
    const float* sign_W1    = (const float*)d_in[8];
    const float* sign_b1    = (const float*)d_in[9];
    const float* sign_W2    = (const float*)d_in[10];
    const float* sign_b2    = (const float*)d_in[11];
    const float* rwse_W1    = (const float*)d_in[12];
    const float* rwse_b1    = (const float*)d_in[13];
    const float* rwse_W2    = (const float*)d_in[14];
    const float* rwse_b2    = (const float*)d_in[15];
    const float* Wq = (const float*)d_in[16];
    const float* bq = (const float*)d_in[17];
    const float* Wk = (const float*)d_in[18];
    const float* bk = (const float*)d_in[19];
    const float* Wv = (const float*)d_in[20];
    const float* bv = (const float*)d_in[21];
    const float* We = (const float*)d_in[22];
    const float* be = (const float*)d_in[23];
    const float* Ws = (const float*)d_in[24];
    const float* bs = (const float*)d_in[25];
    const float* fc_W = (const float*)d_in[26];
    const float* fc_b = (const float*)d_in[27];
    float* out = (float*)d_out;

    char* ws = (char*)d_ws;
    size_t off = 0;
    auto alloc = [&](size_t bytes) {
        size_t o = off;
        off += (bytes + 255) & ~(size_t)255;
        return o;
    };
    float* x    = (float*)(ws + alloc((size_t)N_NODES_C * HID_C * 4));
    float* xs   = (float*)(ws + alloc((size_t)N_NODES_C * HID_C * 4));
    unsigned short* qb  = (unsigned short*)(ws + alloc((size_t)N_NODES_C * HID_C * 2));
    unsigned short* kvb = (unsigned short*)(ws + alloc((size_t)N_NODES_C * HID_C * 2 * 2));
    unsigned short* xhi = (unsigned short*)(ws + alloc((size_t)N_NODES_PAD * HID_C * 2));
    unsigned short* xlo = (unsigned short*)(ws + alloc((size_t)N_NODES_PAD * HID_C * 2));
    unsigned short* bt_hi = (unsigned short*)(ws + alloc((size_t)LAYERS_C * 256 * 64 * 2));
    unsigned short* bt_lo = (unsigned short*)(ws + alloc((size_t)LAYERS_C * 256 * 64 * 2));
    unsigned short* etb = (unsigned short*)(ws + alloc((size_t)LAYERS_C * NCODES_C * HID_C * 2));
    int* counts = (int*)  (ws + alloc((size_t)N_NODES_C * 4));
    int* rowp   = (int*)  (ws + alloc((size_t)(N_NODES_C + 1) * 4));
    int* cursor = (int*)  (ws + alloc((size_t)N_NODES_C * 4));
    int* packed = (int*)  (ws + alloc((size_t)N_EDGES_C * 4));
    int* gstart = (int*)  (ws + alloc((size_t)(GRAPHS_C + 1) * 4));

    hipMemsetAsync(counts, 0, (size_t)N_NODES_C * 4, stream);

    node_encode_kernel<<<N_NODES_C / NE_NPB, 256, 0, stream>>>(
        x_atom, lap_pe, rwse, atom_emb,
        sign_W1, sign_b1, sign_W2, sign_b2,
        rwse_W1, rwse_b1, rwse_W2, rwse_b2, x, xhi, xlo);

    bond_etab_kernel<<<NCODES_C, 64, 0, stream>>>(bond_emb, We, be, etb);
    prep_w_kernel<<<(LAYERS_C * 4 * 64 * 64) / 256, 256, 0, stream>>>(Wq, Wk, Wv, Ws, bt_hi, bt_lo);

    hist_kernel<<<(N_EDGES_C + 255) / 256, 256, 0, stream>>>(edge_index + N_EDGES_C, counts);
    scan_kernel<<<1, 1024, 0, stream>>>(counts, rowp, cursor);
    scatter_kernel<<<(N_EDGES_C + 255) / 256, 256, 0, stream>>>(edge_index, edge_attr, cursor, packed);
    gbounds_kernel<<<1, 1024, 0, stream>>>(batch, gstart);

    const int qkvs_grid = (N_NODES_C + 63) / 64;
    const int attn_grid = N_NODES_C / 4;
    for (int l = 0; l < LAYERS_C; ++l) {
        const unsigned short* bh = bt_hi + (size_t)l * 256 * 64;
        const unsigned short* bl = bt_lo + (size_t)l * 256 * 64;
        const unsigned short* el = etb + (size_t)l * NCODES_C * HID_C;
        switch (l) {
        case 0:
            qkvs_mfma_kernel<0><<<qkvs_grid, 256, 0, stream>>>(xhi, xlo, bh, bl,
                bq + l * 64, bk + l * 64, bv + l * 64, bs + l * 64, qb, kvb, xs);
            attn_kernel<0><<<attn_grid, 256, 0, stream>>>(qb, kvb, xs, el, rowp, packed, x, xhi, xlo);
            break;
        case 1:
            qkvs_mfma_kernel<1><<<qkvs_grid, 256, 0, stream>>>(xhi, xlo, bh, bl,
                bq + l * 64, bk + l * 64, bv + l * 64, bs + l * 64, qb, kvb, xs);
            attn_kernel<1><<<attn_grid, 256, 0, stream>>>(qb, kvb, xs, el, rowp, packed, x, xhi, xlo);
            break;
        default:
            qkvs_mfma_kernel<2><<<qkvs_grid, 256, 0, stream>>>(xhi, xlo, bh, bl,
                bq + l * 64, bk + l * 64, bv + l * 64, bs + l * 64, qb, kvb, xs);
            attn_kernel<2><<<attn_grid, 256, 0, stream>>>(qb, kvb, xs, el, rowp, packed, x, xhi, xlo);
            break;
        }
    }

    pool_head_kernel<<<GRAPHS_C, 128, 0, stream>>>(x, gstart, fc_W, fc_b, out);
}

// Round 8
// 391.214 us; speedup vs baseline: 1.8444x; 1.0489x over previous
//
#include <hip/hip_runtime.h>
#include <hip/hip_bf16.h>

#define N_NODES_C 20000
#define N_NODES_PAD 20032
#define N_EDGES_C 640000
#define HID_C 64
#define GRAPHS_C 512
#define OUT_C 128
#define PE_DIM_C 10
#define ATOM_FEATS_C 9
#define ATOM_VOCAB_C 119
#define BOND_VOCAB_C 5
#define LAYERS_C 3
#define NCODES_C 125   // 5*5*5 distinct bond-type combinations

typedef __attribute__((ext_vector_type(8))) short bf16x8;
typedef __attribute__((ext_vector_type(4))) float f32x4;

static __device__ __forceinline__ void split_bf(float f, unsigned short& hi, unsigned short& lo)
{
    __hip_bfloat16 h = __float2bfloat16(f);
    float fh = __bfloat162float(h);
    __hip_bfloat16 l = __float2bfloat16(f - fh);
    hi = *reinterpret_cast<unsigned short*>(&h);
    lo = *reinterpret_cast<unsigned short*>(&l);
}

static __device__ __forceinline__ unsigned short f2bf(float f)
{
    __hip_bfloat16 h = __float2bfloat16(f);
    return *reinterpret_cast<unsigned short*>(&h);
}

// unpack a u32 holding two bf16 (lo half = even channel) to two floats
static __device__ __forceinline__ void bf2x(unsigned u, float& a, float& b)
{
    a = __uint_as_float(u << 16);
    b = __uint_as_float(u & 0xffff0000u);
}

// ---------------------------------------------------------------------------
// Node encoder: atom-emb sum + SignNet(±lap_pe) + RWSE MLP.
// Emits ONLY the split-bf16 copy (xhi/xlo); f32 x is dead until the last
// attention layer writes it for pooling.
// ---------------------------------------------------------------------------
#define NE_NPB 32
__global__ __launch_bounds__(256) void node_encode_kernel(
    const int* __restrict__ x_atom, const float* __restrict__ lap_pe,
    const float* __restrict__ rwse, const float* __restrict__ atom_emb,
    const float* __restrict__ sW1, const float* __restrict__ sb1,
    const float* __restrict__ sW2, const float* __restrict__ sb2,
    const float* __restrict__ rW1, const float* __restrict__ rb1,
    const float* __restrict__ rW2, const float* __restrict__ rb2,
    unsigned short* __restrict__ xhi, unsigned short* __restrict__ xlo)
{
    __shared__ float hs[NE_NPB][HID_C];
    __shared__ float hr[NE_NPB][HID_C];
    const int w = threadIdx.x >> 6;
    const int j = threadIdx.x & 63;
    const int nbase = blockIdx.x * NE_NPB + w * 8;

    float sw2[64], rw2[64];
    #pragma unroll
    for (int i = 0; i < 64; ++i) {
        sw2[i] = sW2[i * 64 + j];
        rw2[i] = rW2[i * 64 + j];
    }
    float sw1[PE_DIM_C], rw1[PE_DIM_C];
    #pragma unroll
    for (int i = 0; i < PE_DIM_C; ++i) {
        sw1[i] = sW1[i * 64 + j];
        rw1[i] = rW1[i * 64 + j];
    }
    const float sb1j = sb1[j], rb1j = rb1[j];
    const float cb = 2.f * sb2[j] + rb2[j];

    float o[8];
    #pragma unroll
    for (int nn = 0; nn < 8; ++nn) {
        const int n = nbase + nn;
        float acc = 0.f;
        #pragma unroll
        for (int f = 0; f < ATOM_FEATS_C; ++f)
            acc += atom_emb[(f * ATOM_VOCAB_C + x_atom[n * ATOM_FEATS_C + f]) * 64 + j];
        float h1 = sb1j, h2 = sb1j, hv = rb1j;
        #pragma unroll
        for (int i = 0; i < PE_DIM_C; ++i) {
            float pv = lap_pe[n * PE_DIM_C + i];
            h1 += pv * sw1[i];
            h2 -= pv * sw1[i];
            hv += rwse[n * PE_DIM_C + i] * rw1[i];
        }
        hs[w * 8 + nn][j] = fmaxf(h1, 0.f) + fmaxf(h2, 0.f);
        hr[w * 8 + nn][j] = fmaxf(hv, 0.f);
        o[nn] = acc + cb;
    }
    __syncthreads();
    #pragma unroll
    for (int nn = 0; nn < 8; ++nn) {
        const float* hsp = hs[w * 8 + nn];
        const float* hrp = hr[w * 8 + nn];
        float a = o[nn];
        #pragma unroll
        for (int i = 0; i < 64; ++i)
            a += hsp[i] * sw2[i] + hrp[i] * rw2[i];
        const size_t idx = (size_t)(nbase + nn) * 64 + j;
        unsigned short hi, lo;
        split_bf(a, hi, lo);
        xhi[idx] = hi;
        xlo[idx] = lo;
    }
}

// ---------------------------------------------------------------------------
// Fused prologue: prep_w (blocks 0..191), bond_etab (192..316),
// gbounds (317), counts-zero (318..). One dispatch instead of four.
// ---------------------------------------------------------------------------
#define PRO_ZBLK ((N_NODES_C + 255) / 256)
__global__ __launch_bounds__(256) void prologue_kernel(
    const float* __restrict__ bond_emb, const float* __restrict__ We,
    const float* __restrict__ be,
    const float* __restrict__ Wq, const float* __restrict__ Wk,
    const float* __restrict__ Wv, const float* __restrict__ Ws,
    const int* __restrict__ batch,
    unsigned short* __restrict__ etb,
    unsigned short* __restrict__ bt_hi, unsigned short* __restrict__ bt_lo,
    int* __restrict__ gstart, int* __restrict__ counts)
{
    const int b = blockIdx.x;
    if (b < 192) {
        // split Wq/Wk/Wv/Ws into bf16 hi/lo, transposed to [n][k]
        const int idx = b * 256 + threadIdx.x;          // 3*4*64*64 = 49152
        const int j = idx & 63;
        const int k = (idx >> 6) & 63;
        const int mat = (idx >> 12) & 3;
        const int l = idx >> 14;
        const float* W;
        if      (mat == 0) W = Wq;
        else if (mat == 1) W = Wk;
        else if (mat == 2) W = Wv;
        else               W = Ws;
        const float wv = W[(size_t)l * 4096 + k * 64 + j];
        unsigned short hi, lo;
        split_bf(wv, hi, lo);
        const size_t o = ((size_t)l * 256 + mat * 64 + j) * 64 + k;
        bt_hi[o] = hi;
        bt_lo[o] = lo;
    } else if (b < 192 + NCODES_C) {
        // bond table for one code
        __shared__ float t[HID_C];
        const int c = b - 192;
        const int j = threadIdx.x;
        if (j < 64) {
            const int f0 = c / 25, f1 = (c / 5) % 5, f2 = c % 5;
            t[j] = bond_emb[(0 * BOND_VOCAB_C + f0) * HID_C + j]
                 + bond_emb[(1 * BOND_VOCAB_C + f1) * HID_C + j]
                 + bond_emb[(2 * BOND_VOCAB_C + f2) * HID_C + j];
        }
        __syncthreads();
        if (j < 64) {
            for (int l = 0; l < LAYERS_C; ++l) {
                float o = be[l * HID_C + j];
                #pragma unroll 8
                for (int i = 0; i < HID_C; ++i)
                    o += t[i] * We[(l * HID_C + i) * HID_C + j];
                etb[(l * NCODES_C + c) * HID_C + j] = f2bf(o);
            }
        }
    } else if (b == 192 + NCODES_C) {
        // graph boundaries: gstart[g] = lower_bound(batch, g)
        for (int g = threadIdx.x; g <= GRAPHS_C; g += 256) {
            int lo = 0, hi = N_NODES_C;
            while (lo < hi) {
                int mid = (lo + hi) >> 1;
                if (batch[mid] < g) lo = mid + 1; else hi = mid;
            }
            gstart[g] = lo;
        }
    } else {
        const int i = (b - 193 - NCODES_C) * 256 + threadIdx.x;
        if (i < N_NODES_C) counts[i] = 0;
    }
}

// ---------------------------------------------------------------------------
// CSR build: histogram by dst, exclusive scan, scatter packed (src<<7|code).
// ---------------------------------------------------------------------------
__global__ void hist_kernel(const int* __restrict__ dst, int* __restrict__ counts)
{
    int e = blockIdx.x * blockDim.x + threadIdx.x;
    if (e < N_EDGES_C) atomicAdd(&counts[dst[e]], 1);
}

__global__ void scan_kernel(const int* __restrict__ counts,
                            int* __restrict__ row_ptr, int* __restrict__ cursor)
{
    __shared__ int part[1024];
    const int t = threadIdx.x;
    const int CH = 20;                // 1024*20 = 20480 >= 20000
    const int base = t * CH;
    int s = 0;
    for (int i = 0; i < CH; ++i) {
        int idx = base + i;
        if (idx < N_NODES_C) s += counts[idx];
    }
    part[t] = s;
    __syncthreads();
    for (int d = 1; d < 1024; d <<= 1) {
        int val = (t >= d) ? part[t - d] : 0;
        __syncthreads();
        part[t] += val;
        __syncthreads();
    }
    int run = part[t] - s;            // exclusive prefix of this chunk
    for (int i = 0; i < CH; ++i) {
        int idx = base + i;
        if (idx < N_NODES_C) {
            row_ptr[idx] = run;
            cursor[idx]  = run;
            run += counts[idx];
        }
    }
    if (t == 1023) row_ptr[N_NODES_C] = part[1023];
}

__global__ void scatter_kernel(const int* __restrict__ ei, const int* __restrict__ ea,
                               int* __restrict__ cursor, int* __restrict__ packed)
{
    int e = blockIdx.x * blockDim.x + threadIdx.x;
    if (e >= N_EDGES_C) return;
    int src  = ei[e];
    int dst  = ei[N_EDGES_C + e];
    int code = ea[e * 3] * 25 + ea[e * 3 + 1] * 5 + ea[e * 3 + 2];
    int p = atomicAdd(&cursor[dst], 1);
    packed[p] = (src << 7) | code;
}

// ---------------------------------------------------------------------------
// Projections via split-bf16 MFMA: [20000x64] @ [64x256] (q|k|v|xs).
// Block = 4 waves; wave w owns matrix w, 64 rows x 64 cols, K=64.
// acc += Ahi*Bhi + Ahi*Blo + Alo*Bhi  (f32 accum; lo*lo dropped ~2^-18).
// Outputs: qb (bf16 [n][64]), kvb (bf16 [n][128] = k|v), xs (f32).
// ---------------------------------------------------------------------------
__global__ __launch_bounds__(256) void qkvs_mfma_kernel(
    const unsigned short* __restrict__ xhi, const unsigned short* __restrict__ xlo,
    const unsigned short* __restrict__ bt_hi, const unsigned short* __restrict__ bt_lo,
    const float* __restrict__ bq, const float* __restrict__ bk,
    const float* __restrict__ bv, const float* __restrict__ bs,
    unsigned short* __restrict__ qb, unsigned short* __restrict__ kvb,
    float* __restrict__ xs)
{
    const int w    = threadIdx.x >> 6;   // matrix 0..3
    const int lane = threadIdx.x & 63;
    const int lr   = lane & 15;
    const int lg   = lane >> 4;
    const int m0   = blockIdx.x * 64;

    f32x4 acc[4][4];
    #pragma unroll
    for (int m = 0; m < 4; ++m)
        #pragma unroll
        for (int n = 0; n < 4; ++n)
            acc[m][n] = (f32x4){0.f, 0.f, 0.f, 0.f};

    const unsigned short* bth = bt_hi + (size_t)(w * 64) * 64;
    const unsigned short* btl = bt_lo + (size_t)(w * 64) * 64;

    #pragma unroll
    for (int pass = 0; pass < 3; ++pass) {
        const unsigned short* Ap = (pass == 2) ? xlo : xhi;
        const unsigned short* Bp = (pass == 1) ? btl : bth;
        #pragma unroll
        for (int kk = 0; kk < 2; ++kk) {
            const int kb = kk * 32 + lg * 8;
            bf16x8 a[4], b[4];
            #pragma unroll
            for (int m = 0; m < 4; ++m)
                a[m] = *(const bf16x8*)(Ap + (size_t)(m0 + m * 16 + lr) * 64 + kb);
            #pragma unroll
            for (int n = 0; n < 4; ++n)
                b[n] = *(const bf16x8*)(Bp + (size_t)(n * 16 + lr) * 64 + kb);
            #pragma unroll
            for (int m = 0; m < 4; ++m)
                #pragma unroll
                for (int n = 0; n < 4; ++n)
                    acc[m][n] = __builtin_amdgcn_mfma_f32_16x16x32_bf16(a[m], b[n], acc[m][n], 0, 0, 0);
        }
    }

    const float* bias = (w == 0) ? bq : (w == 1) ? bk : (w == 2) ? bv : bs;
    float bv4[4];
    #pragma unroll
    for (int n = 0; n < 4; ++n) bv4[n] = bias[n * 16 + lr];

    #pragma unroll
    for (int m = 0; m < 4; ++m) {
        #pragma unroll
        for (int rr = 0; rr < 4; ++rr) {
            const int row = m0 + m * 16 + lg * 4 + rr;
            if (row < N_NODES_C) {
                #pragma unroll
                for (int n = 0; n < 4; ++n) {
                    const float val = acc[m][n][rr] + bv4[n];
                    const int ch = n * 16 + lr;
                    if      (w == 0) qb [(size_t)row * 64  + ch]      = f2bf(val);
                    else if (w == 1) kvb[(size_t)row * 128 + ch]      = f2bf(val);
                    else if (w == 2) kvb[(size_t)row * 128 + 64 + ch] = f2bf(val);
                    else             xs [(size_t)row * 64  + ch]      = val;
                }
            }
        }
    }
}

// ---------------------------------------------------------------------------
// Attention: one wave per node; 8 edge slots x 8 lanes; lane owns channels
// 8r..8r+7. Edge index per slot is STATIC (start + t*8 + s) so the packed
// word is loaded directly per lane (no shuffle / bpermute on the critical
// path). Depth-2 software pipeline over the full neighbor list.
// No max-shift (softmax shift-invariant; logits O(1), clamped at 80).
// WRITE_X: emit f32 x for pooling (last layer only).
// ---------------------------------------------------------------------------
template<int WRITE_X>
__global__ __launch_bounds__(256) void attn_kernel(
    const unsigned short* __restrict__ qb, const unsigned short* __restrict__ kvb,
    const float* __restrict__ xs, const unsigned short* __restrict__ etb_l,
    const int* __restrict__ row_ptr, const int* __restrict__ packed,
    float* __restrict__ x, unsigned short* __restrict__ xhi,
    unsigned short* __restrict__ xlo)
{
    const int lane = threadIdx.x & 63;
    const int s    = lane >> 3;          // edge slot 0..7
    const int r    = lane & 7;           // channel group
    const int c0   = r * 8;              // channels c0..c0+7 (head c0>>4)
    const int n    = blockIdx.x * 4 + (threadIdx.x >> 6);

    float qf[8];
    {
        uint4 qu = *(const uint4*)(qb + (size_t)n * 64 + c0);
        bf2x(qu.x, qf[0], qf[1]); bf2x(qu.y, qf[2], qf[3]);
        bf2x(qu.z, qf[4], qf[5]); bf2x(qu.w, qf[6], qf[7]);
    }
    const int start = row_ptr[n], end = row_ptr[n + 1];
    const int deg = end - start;

    float den = 0.f;
    float acc[8] = {0.f, 0.f, 0.f, 0.f, 0.f, 0.f, 0.f, 0.f};

    if (deg > 0) {
        const int nit = (deg + 7) >> 3;
        uint4 kA, vA, eA, kB, vB, eB, kC, vC, eC;

        auto LD = [&](int t, uint4& kf, uint4& vf, uint4& ef) {
            const int ei = min(start + t * 8 + s, end - 1);
            const int pk = packed[ei];                      // direct, no shfl
            const unsigned short* kp = kvb + (size_t)(pk >> 7) * 128;
            kf = *(const uint4*)(kp + c0);
            vf = *(const uint4*)(kp + 64 + c0);
            ef = *(const uint4*)(etb_l + (pk & 127) * 64 + c0);
        };
        auto PROC = [&](int t, const uint4& ku, const uint4& vu, const uint4& eu) {
            const unsigned kw[4] = {ku.x, ku.y, ku.z, ku.w};
            const unsigned vw[4] = {vu.x, vu.y, vu.z, vu.w};
            const unsigned ew[4] = {eu.x, eu.y, eu.z, eu.w};
            float p = 0.f;
            float ve[8];
            #pragma unroll
            for (int i = 0; i < 4; ++i) {
                float ka, kb2, ea, eb, va, vb;
                bf2x(kw[i], ka, kb2);
                bf2x(ew[i], ea, eb);
                bf2x(vw[i], va, vb);
                p = fmaf(qf[2 * i],     ka  + ea, p);
                p = fmaf(qf[2 * i + 1], kb2 + eb, p);
                ve[2 * i]     = va + ea;
                ve[2 * i + 1] = vb + eb;
            }
            p += __shfl_xor(p, 1, 64);               // 16-ch head reduce
            const float ex = (t * 8 + s < deg) ? __expf(fminf(p * 0.25f, 80.f)) : 0.f;
            den += ex;
            #pragma unroll
            for (int i = 0; i < 8; ++i)
                acc[i] = fmaf(ex, ve[i], acc[i]);
        };

        LD(0, kA, vA, eA);
        LD(1, kB, vB, eB);
        int t = 0;
        for (; t + 3 <= nit; t += 3) {
            LD(t + 2, kC, vC, eC); PROC(t,     kA, vA, eA);
            LD(t + 3, kA, vA, eA); PROC(t + 1, kB, vB, eB);
            LD(t + 4, kB, vB, eB); PROC(t + 2, kC, vC, eC);
        }
        if (t     < nit) PROC(t,     kA, vA, eA);
        if (t + 1 < nit) PROC(t + 1, kB, vB, eB);
    }

    // merge the 8 slots' partials (butterfly over lane bits 3..5)
    #pragma unroll
    for (int off = 8; off <= 32; off <<= 1) {
        den += __shfl_xor(den, off, 64);
        #pragma unroll
        for (int i = 0; i < 8; ++i)
            acc[i] += __shfl_xor(acc[i], off, 64);
    }

    if (s == 0) {
        const float inv = 1.f / (den + 1e-16f);
        const float4 xsa = *(const float4*)(xs + (size_t)n * 64 + c0);
        const float4 xsb = *(const float4*)(xs + (size_t)n * 64 + c0 + 4);
        float o[8];
        o[0] = fmaxf(acc[0] * inv + xsa.x, 0.f);
        o[1] = fmaxf(acc[1] * inv + xsa.y, 0.f);
        o[2] = fmaxf(acc[2] * inv + xsa.z, 0.f);
        o[3] = fmaxf(acc[3] * inv + xsa.w, 0.f);
        o[4] = fmaxf(acc[4] * inv + xsb.x, 0.f);
        o[5] = fmaxf(acc[5] * inv + xsb.y, 0.f);
        o[6] = fmaxf(acc[6] * inv + xsb.z, 0.f);
        o[7] = fmaxf(acc[7] * inv + xsb.w, 0.f);

        if (WRITE_X) {
            float4 oa = {o[0], o[1], o[2], o[3]};
            float4 ob = {o[4], o[5], o[6], o[7]};
            *(float4*)(x + (size_t)n * 64 + c0)     = oa;
            *(float4*)(x + (size_t)n * 64 + c0 + 4) = ob;
        }

        ushort4 ha, hb, la, lb;
        split_bf(o[0], ha.x, la.x); split_bf(o[1], ha.y, la.y);
        split_bf(o[2], ha.z, la.z); split_bf(o[3], ha.w, la.w);
        split_bf(o[4], hb.x, lb.x); split_bf(o[5], hb.y, lb.y);
        split_bf(o[6], hb.z, lb.z); split_bf(o[7], hb.w, lb.w);
        *(ushort4*)(xhi + (size_t)n * 64 + c0)     = ha;
        *(ushort4*)(xhi + (size_t)n * 64 + c0 + 4) = hb;
        *(ushort4*)(xlo + (size_t)n * 64 + c0)     = la;
        *(ushort4*)(xlo + (size_t)n * 64 + c0 + 4) = lb;
    }
}

// ---------------------------------------------------------------------------
// Fused mean-pool + classifier head: one 128-thread block per graph.
// ---------------------------------------------------------------------------
__global__ __launch_bounds__(128) void pool_head_kernel(
    const float* __restrict__ x, const int* __restrict__ gstart,
    const float* __restrict__ fc_W, const float* __restrict__ fc_b,
    float* __restrict__ out)
{
    __shared__ float tmp[128];
    __shared__ float p[HID_C];
    const int g = blockIdx.x;
    const int s0 = gstart[g], s1 = gstart[g + 1];
    const int ch = threadIdx.x & 63;
    const int half = threadIdx.x >> 6;

    float acc = 0.f;
    for (int n = s0 + half; n < s1; n += 2)
        acc += x[(size_t)n * 64 + ch];
    tmp[threadIdx.x] = acc;
    __syncthreads();
    if (half == 0)
        p[ch] = (tmp[ch] + tmp[64 + ch]) / fmaxf((float)(s1 - s0), 1.f);
    __syncthreads();

    const int o = threadIdx.x;            // 0..127
    float rr = fc_b[o];
    #pragma unroll 8
    for (int i = 0; i < HID_C; ++i)
        rr = fmaf(p[i], fc_W[i * OUT_C + o], rr);
    out[(size_t)g * OUT_C + o] = rr;
}

// ---------------------------------------------------------------------------
extern "C" void kernel_launch(void* const* d_in, const int* in_sizes, int n_in,
                              void* d_out, int out_size, void* d_ws, size_t ws_size,
                              hipStream_t stream)
{
    const int*   x_atom     = (const int*)  d_in[0];
    const int*   edge_index = (const int*)  d_in[1];
    const int*   edge_attr  = (const int*)  d_in[2];
    const int*   batch      = (const int*)  d_in[3];
    const float* lap_pe     = (const float*)d_in[4];
    const float* rwse       = (const float*)d_in[5];
    const float* atom_emb   = (const float*)d_in[6];
    const float* bond_emb   = (const float*)d_in[7];
    const float* sign_W1    = (const float*)d_in[8];
    const float* sign_b1    = (const float*)d_in[9];
    const float* sign_W2    = (const float*)d_in[10];
    const float* sign_b2    = (const float*)d_in[11];
    const float* rwse_W1    = (const float*)d_in[12];
    const float* rwse_b1    = (const float*)d_in[13];
    const float* rwse_W2    = (const float*)d_in[14];
    const float* rwse_b2    = (const float*)d_in[15];
    const float* Wq = (const float*)d_in[16];
    const float* bq = (const float*)d_in[17];
    const float* Wk = (const float*)d_in[18];
    const float* bk = (const float*)d_in[19];
    const float* Wv = (const float*)d_in[20];
    const float* bv = (const float*)d_in[21];
    const float* We = (const float*)d_in[22];
    const float* be = (const float*)d_in[23];
    const float* Ws = (const float*)d_in[24];
    const float* bs = (const float*)d_in[25];
    const float* fc_W = (const float*)d_in[26];
    const float* fc_b = (const float*)d_in[27];
    float* out = (float*)d_out;

    char* ws = (char*)d_ws;
    size_t off = 0;
    auto alloc = [&](size_t bytes) {
        size_t o = off;
        off += (bytes + 255) & ~(size_t)255;
        return o;
    };
    float* x    = (float*)(ws + alloc((size_t)N_NODES_C * HID_C * 4));
    float* xs   = (float*)(ws + alloc((size_t)N_NODES_C * HID_C * 4));
    unsigned short* qb  = (unsigned short*)(ws + alloc((size_t)N_NODES_C * HID_C * 2));
    unsigned short* kvb = (unsigned short*)(ws + alloc((size_t)N_NODES_C * HID_C * 2 * 2));
    unsigned short* xhi = (unsigned short*)(ws + alloc((size_t)N_NODES_PAD * HID_C * 2));
    unsigned short* xlo = (unsigned short*)(ws + alloc((size_t)N_NODES_PAD * HID_C * 2));
    unsigned short* bt_hi = (unsigned short*)(ws + alloc((size_t)LAYERS_C * 256 * 64 * 2));
    unsigned short* bt_lo = (unsigned short*)(ws + alloc((size_t)LAYERS_C * 256 * 64 * 2));
    unsigned short* etb = (unsigned short*)(ws + alloc((size_t)LAYERS_C * NCODES_C * HID_C * 2));
    int* counts = (int*)  (ws + alloc((size_t)N_NODES_C * 4));
    int* rowp   = (int*)  (ws + alloc((size_t)(N_NODES_C + 1) * 4));
    int* cursor = (int*)  (ws + alloc((size_t)N_NODES_C * 4));
    int* packed = (int*)  (ws + alloc((size_t)N_EDGES_C * 4));
    int* gstart = (int*)  (ws + alloc((size_t)(GRAPHS_C + 1) * 4));

    node_encode_kernel<<<N_NODES_C / NE_NPB, 256, 0, stream>>>(
        x_atom, lap_pe, rwse, atom_emb,
        sign_W1, sign_b1, sign_W2, sign_b2,
        rwse_W1, rwse_b1, rwse_W2, rwse_b2, xhi, xlo);

    prologue_kernel<<<193 + NCODES_C + PRO_ZBLK, 256, 0, stream>>>(
        bond_emb, We, be, Wq, Wk, Wv, Ws, batch,
        etb, bt_hi, bt_lo, gstart, counts);

    hist_kernel<<<(N_EDGES_C + 255) / 256, 256, 0, stream>>>(edge_index + N_EDGES_C, counts);
    scan_kernel<<<1, 1024, 0, stream>>>(counts, rowp, cursor);
    scatter_kernel<<<(N_EDGES_C + 255) / 256, 256, 0, stream>>>(edge_index, edge_attr, cursor, packed);

    const int qkvs_grid = (N_NODES_C + 63) / 64;
    const int attn_grid = N_NODES_C / 4;
    for (int l = 0; l < LAYERS_C; ++l) {
        const unsigned short* bh = bt_hi + (size_t)l * 256 * 64;
        const unsigned short* bl = bt_lo + (size_t)l * 256 * 64;
        const unsigned short* el = etb + (size_t)l * NCODES_C * HID_C;
        qkvs_mfma_kernel<<<qkvs_grid, 256, 0, stream>>>(xhi, xlo, bh, bl,
            bq + l * 64, bk + l * 64, bv + l * 64, bs + l * 64, qb, kvb, xs);
        if (l < LAYERS_C - 1)
            attn_kernel<0><<<attn_grid, 256, 0, stream>>>(qb, kvb, xs, el, rowp, packed, x, xhi, xlo);
        else
            attn_kernel<1><<<attn_grid, 256, 0, stream>>>(qb, kvb, xs, el, rowp, packed, x, xhi, xlo);
    }

    pool_head_kernel<<<GRAPHS_C, 128, 0, stream>>>(x, gstart, fc_W, fc_b, out);
}

// Round 9
// 313.696 us; speedup vs baseline: 2.3002x; 1.2471x over previous
//
#include <hip/hip_runtime.h>
#include <hip/hip_bf16.h>

#define N_NODES_C 20000
#define N_NODES_PAD 20032
#define N_EDGES_C 640000
#define HID_C 64
#define GRAPHS_C 512
#define OUT_C 128
#define PE_DIM_C 10
#define ATOM_FEATS_C 9
#define ATOM_VOCAB_C 119
#define BOND_VOCAB_C 5
#define LAYERS_C 3
#define NCODES_C 125   // 5*5*5 distinct bond-type combinations
#define MAXDEG_C 96    // fixed bucket stride; P(deg>96) ~ 1e-18 for Poisson(32)

typedef __attribute__((ext_vector_type(8))) short bf16x8;
typedef __attribute__((ext_vector_type(4))) float f32x4;

static __device__ __forceinline__ void split_bf(float f, unsigned short& hi, unsigned short& lo)
{
    __hip_bfloat16 h = __float2bfloat16(f);
    float fh = __bfloat162float(h);
    __hip_bfloat16 l = __float2bfloat16(f - fh);
    hi = *reinterpret_cast<unsigned short*>(&h);
    lo = *reinterpret_cast<unsigned short*>(&l);
}

static __device__ __forceinline__ unsigned short f2bf(float f)
{
    __hip_bfloat16 h = __float2bfloat16(f);
    return *reinterpret_cast<unsigned short*>(&h);
}

// unpack a u32 holding two bf16 (lo half = even channel) to two floats
static __device__ __forceinline__ void bf2x(unsigned u, float& a, float& b)
{
    a = __uint_as_float(u << 16);
    b = __uint_as_float(u & 0xffff0000u);
}

// ---------------------------------------------------------------------------
// Mega-prologue, one dispatch. Block ranges:
//   [0,625)    node encoder (32 nodes/block) -> xhi/xlo
//   [625,817)  prep_w: split Wq/Wk/Wv/Ws bf16 hi/lo transposed [n][k]
//   [817,942)  bond tables etb (bf16)
//   942        graph boundaries gstart
//   [943,1022) zero cnt
// ---------------------------------------------------------------------------
#define NE_NPB 32
#define NE_BLK 625
#define PW_BLK 192
#define BOND_BLK 125
#define Z_BLK 79
#define PRO_BLK (NE_BLK + PW_BLK + BOND_BLK + 1 + Z_BLK)

__global__ __launch_bounds__(256) void mega_prologue_kernel(
    const int* __restrict__ x_atom, const float* __restrict__ lap_pe,
    const float* __restrict__ rwse, const float* __restrict__ atom_emb,
    const float* __restrict__ sW1, const float* __restrict__ sb1,
    const float* __restrict__ sW2, const float* __restrict__ sb2,
    const float* __restrict__ rW1, const float* __restrict__ rb1,
    const float* __restrict__ rW2, const float* __restrict__ rb2,
    const float* __restrict__ bond_emb, const float* __restrict__ We,
    const float* __restrict__ be,
    const float* __restrict__ Wq, const float* __restrict__ Wk,
    const float* __restrict__ Wv, const float* __restrict__ Ws,
    const int* __restrict__ batch,
    unsigned short* __restrict__ xhi, unsigned short* __restrict__ xlo,
    unsigned short* __restrict__ bt_hi, unsigned short* __restrict__ bt_lo,
    unsigned short* __restrict__ etb,
    int* __restrict__ gstart, int* __restrict__ cnt)
{
    __shared__ float hs[NE_NPB][HID_C];
    __shared__ float hr[NE_NPB][HID_C];
    __shared__ float tb[HID_C];
    const int b = blockIdx.x;

    if (b < NE_BLK) {
        const int w = threadIdx.x >> 6;
        const int j = threadIdx.x & 63;
        const int nbase = b * NE_NPB + w * 8;

        float sw2[64], rw2[64];
        #pragma unroll
        for (int i = 0; i < 64; ++i) {
            sw2[i] = sW2[i * 64 + j];
            rw2[i] = rW2[i * 64 + j];
        }
        float sw1[PE_DIM_C], rw1[PE_DIM_C];
        #pragma unroll
        for (int i = 0; i < PE_DIM_C; ++i) {
            sw1[i] = sW1[i * 64 + j];
            rw1[i] = rW1[i * 64 + j];
        }
        const float sb1j = sb1[j], rb1j = rb1[j];
        const float cb = 2.f * sb2[j] + rb2[j];

        float o[8];
        #pragma unroll
        for (int nn = 0; nn < 8; ++nn) {
            const int n = nbase + nn;
            float acc = 0.f;
            #pragma unroll
            for (int f = 0; f < ATOM_FEATS_C; ++f)
                acc += atom_emb[(f * ATOM_VOCAB_C + x_atom[n * ATOM_FEATS_C + f]) * 64 + j];
            float h1 = sb1j, h2 = sb1j, hv = rb1j;
            #pragma unroll
            for (int i = 0; i < PE_DIM_C; ++i) {
                float pv = lap_pe[n * PE_DIM_C + i];
                h1 += pv * sw1[i];
                h2 -= pv * sw1[i];
                hv += rwse[n * PE_DIM_C + i] * rw1[i];
            }
            hs[w * 8 + nn][j] = fmaxf(h1, 0.f) + fmaxf(h2, 0.f);
            hr[w * 8 + nn][j] = fmaxf(hv, 0.f);
            o[nn] = acc + cb;
        }
        __syncthreads();
        #pragma unroll
        for (int nn = 0; nn < 8; ++nn) {
            const float* hsp = hs[w * 8 + nn];
            const float* hrp = hr[w * 8 + nn];
            float a = o[nn];
            #pragma unroll
            for (int i = 0; i < 64; ++i)
                a += hsp[i] * sw2[i] + hrp[i] * rw2[i];
            const size_t idx = (size_t)(nbase + nn) * 64 + j;
            unsigned short hi, lo;
            split_bf(a, hi, lo);
            xhi[idx] = hi;
            xlo[idx] = lo;
        }
    } else if (b < NE_BLK + PW_BLK) {
        const int idx = (b - NE_BLK) * 256 + threadIdx.x;  // 3*4*64*64 = 49152
        const int j = idx & 63;
        const int k = (idx >> 6) & 63;
        const int mat = (idx >> 12) & 3;
        const int l = idx >> 14;
        const float* W;
        if      (mat == 0) W = Wq;
        else if (mat == 1) W = Wk;
        else if (mat == 2) W = Wv;
        else               W = Ws;
        const float wv = W[(size_t)l * 4096 + k * 64 + j];
        unsigned short hi, lo;
        split_bf(wv, hi, lo);
        const size_t o = ((size_t)l * 256 + mat * 64 + j) * 64 + k;
        bt_hi[o] = hi;
        bt_lo[o] = lo;
    } else if (b < NE_BLK + PW_BLK + BOND_BLK) {
        const int c = b - NE_BLK - PW_BLK;
        const int j = threadIdx.x;
        if (j < 64) {
            const int f0 = c / 25, f1 = (c / 5) % 5, f2 = c % 5;
            tb[j] = bond_emb[(0 * BOND_VOCAB_C + f0) * HID_C + j]
                  + bond_emb[(1 * BOND_VOCAB_C + f1) * HID_C + j]
                  + bond_emb[(2 * BOND_VOCAB_C + f2) * HID_C + j];
        }
        __syncthreads();
        if (j < 64) {
            for (int l = 0; l < LAYERS_C; ++l) {
                float o = be[l * HID_C + j];
                #pragma unroll 8
                for (int i = 0; i < HID_C; ++i)
                    o += tb[i] * We[(l * HID_C + i) * HID_C + j];
                etb[(l * NCODES_C + c) * HID_C + j] = f2bf(o);
            }
        }
    } else if (b == NE_BLK + PW_BLK + BOND_BLK) {
        for (int g = threadIdx.x; g <= GRAPHS_C; g += 256) {
            int lo = 0, hi = N_NODES_C;
            while (lo < hi) {
                int mid = (lo + hi) >> 1;
                if (batch[mid] < g) lo = mid + 1; else hi = mid;
            }
            gstart[g] = lo;
        }
    } else {
        const int i = (b - NE_BLK - PW_BLK - BOND_BLK - 1) * 256 + threadIdx.x;
        if (i < N_NODES_C) cnt[i] = 0;
    }
}

// ---------------------------------------------------------------------------
// Projections via split-bf16 MFMA (device body, shared by two kernels).
// acc += Ahi*Bhi + Ahi*Blo + Alo*Bhi  (f32 accum; lo*lo dropped ~2^-18).
// ---------------------------------------------------------------------------
static __device__ __forceinline__ void qkvs_tile_body(
    int tile, int tid,
    const unsigned short* __restrict__ xhi, const unsigned short* __restrict__ xlo,
    const unsigned short* __restrict__ bt_hi, const unsigned short* __restrict__ bt_lo,
    const float* __restrict__ bq, const float* __restrict__ bk,
    const float* __restrict__ bv, const float* __restrict__ bs,
    unsigned short* __restrict__ qb, unsigned short* __restrict__ kvb,
    float* __restrict__ xs)
{
    const int w    = tid >> 6;   // matrix 0..3
    const int lane = tid & 63;
    const int lr   = lane & 15;
    const int lg   = lane >> 4;
    const int m0   = tile * 64;

    f32x4 acc[4][4];
    #pragma unroll
    for (int m = 0; m < 4; ++m)
        #pragma unroll
        for (int n = 0; n < 4; ++n)
            acc[m][n] = (f32x4){0.f, 0.f, 0.f, 0.f};

    const unsigned short* bth = bt_hi + (size_t)(w * 64) * 64;
    const unsigned short* btl = bt_lo + (size_t)(w * 64) * 64;

    #pragma unroll
    for (int pass = 0; pass < 3; ++pass) {
        const unsigned short* Ap = (pass == 2) ? xlo : xhi;
        const unsigned short* Bp = (pass == 1) ? btl : bth;
        #pragma unroll
        for (int kk = 0; kk < 2; ++kk) {
            const int kb = kk * 32 + lg * 8;
            bf16x8 a[4], b[4];
            #pragma unroll
            for (int m = 0; m < 4; ++m)
                a[m] = *(const bf16x8*)(Ap + (size_t)(m0 + m * 16 + lr) * 64 + kb);
            #pragma unroll
            for (int n = 0; n < 4; ++n)
                b[n] = *(const bf16x8*)(Bp + (size_t)(n * 16 + lr) * 64 + kb);
            #pragma unroll
            for (int m = 0; m < 4; ++m)
                #pragma unroll
                for (int n = 0; n < 4; ++n)
                    acc[m][n] = __builtin_amdgcn_mfma_f32_16x16x32_bf16(a[m], b[n], acc[m][n], 0, 0, 0);
        }
    }

    const float* bias = (w == 0) ? bq : (w == 1) ? bk : (w == 2) ? bv : bs;
    float bv4[4];
    #pragma unroll
    for (int n = 0; n < 4; ++n) bv4[n] = bias[n * 16 + lr];

    #pragma unroll
    for (int m = 0; m < 4; ++m) {
        #pragma unroll
        for (int rr = 0; rr < 4; ++rr) {
            const int row = m0 + m * 16 + lg * 4 + rr;
            if (row < N_NODES_C) {
                #pragma unroll
                for (int n = 0; n < 4; ++n) {
                    const float val = acc[m][n][rr] + bv4[n];
                    const int ch = n * 16 + lr;
                    if      (w == 0) qb [(size_t)row * 64  + ch]      = f2bf(val);
                    else if (w == 1) kvb[(size_t)row * 128 + ch]      = f2bf(val);
                    else if (w == 2) kvb[(size_t)row * 128 + 64 + ch] = f2bf(val);
                    else             xs [(size_t)row * 64  + ch]      = val;
                }
            }
        }
    }
}

__global__ __launch_bounds__(256) void qkvs_mfma_kernel(
    const unsigned short* __restrict__ xhi, const unsigned short* __restrict__ xlo,
    const unsigned short* __restrict__ bt_hi, const unsigned short* __restrict__ bt_lo,
    const float* __restrict__ bq, const float* __restrict__ bk,
    const float* __restrict__ bv, const float* __restrict__ bs,
    unsigned short* __restrict__ qb, unsigned short* __restrict__ kvb,
    float* __restrict__ xs)
{
    qkvs_tile_body(blockIdx.x, threadIdx.x, xhi, xlo, bt_hi, bt_lo,
                   bq, bk, bv, bs, qb, kvb, xs);
}

// ---------------------------------------------------------------------------
// Fused single-pass CSR bucketing (blocks [0,2500)) + layer-0 projections
// (blocks [2500,2813)). Both depend only on the prologue.
// packed[dst*96 + p] = (src<<7)|code, p from atomicAdd(&cnt[dst],1).
// ---------------------------------------------------------------------------
#define SCAT_BLK ((N_EDGES_C + 255) / 256)
__global__ __launch_bounds__(256) void scatter_qkvs_kernel(
    const int* __restrict__ ei, const int* __restrict__ ea,
    int* __restrict__ cnt, int* __restrict__ packed,
    const unsigned short* __restrict__ xhi, const unsigned short* __restrict__ xlo,
    const unsigned short* __restrict__ bt_hi, const unsigned short* __restrict__ bt_lo,
    const float* __restrict__ bq, const float* __restrict__ bk,
    const float* __restrict__ bv, const float* __restrict__ bs,
    unsigned short* __restrict__ qb, unsigned short* __restrict__ kvb,
    float* __restrict__ xs)
{
    if (blockIdx.x < SCAT_BLK) {
        const int e = blockIdx.x * 256 + threadIdx.x;
        if (e < N_EDGES_C) {
            const int src  = ei[e];
            const int dst  = ei[N_EDGES_C + e];
            const int code = ea[e * 3] * 25 + ea[e * 3 + 1] * 5 + ea[e * 3 + 2];
            const int p = atomicAdd(&cnt[dst], 1);
            if (p < MAXDEG_C) packed[dst * MAXDEG_C + p] = (src << 7) | code;
        }
    } else {
        qkvs_tile_body(blockIdx.x - SCAT_BLK, threadIdx.x, xhi, xlo, bt_hi, bt_lo,
                       bq, bk, bv, bs, qb, kvb, xs);
    }
}

// ---------------------------------------------------------------------------
// Attention: one wave per node; 8 edge slots x 8 lanes; lane owns channels
// 8r..8r+7. Bucket base is n*96; degree from cnt[n]. Direct per-lane packed
// loads (no shuffle). Depth-2 software pipeline.
// No max-shift (softmax shift-invariant; logits O(1), clamped at 80).
// WRITE_X: emit f32 x for pooling (last layer only).
// ---------------------------------------------------------------------------
template<int WRITE_X>
__global__ __launch_bounds__(256) void attn_kernel(
    const unsigned short* __restrict__ qb, const unsigned short* __restrict__ kvb,
    const float* __restrict__ xs, const unsigned short* __restrict__ etb_l,
    const int* __restrict__ cnt, const int* __restrict__ packed,
    float* __restrict__ x, unsigned short* __restrict__ xhi,
    unsigned short* __restrict__ xlo)
{
    const int lane = threadIdx.x & 63;
    const int s    = lane >> 3;          // edge slot 0..7
    const int r    = lane & 7;           // channel group
    const int c0   = r * 8;              // channels c0..c0+7
    const int n    = blockIdx.x * 4 + (threadIdx.x >> 6);

    float qf[8];
    {
        uint4 qu = *(const uint4*)(qb + (size_t)n * 64 + c0);
        bf2x(qu.x, qf[0], qf[1]); bf2x(qu.y, qf[2], qf[3]);
        bf2x(qu.z, qf[4], qf[5]); bf2x(qu.w, qf[6], qf[7]);
    }
    const int deg  = min(cnt[n], MAXDEG_C);
    const int base = n * MAXDEG_C;

    float den = 0.f;
    float acc[8] = {0.f, 0.f, 0.f, 0.f, 0.f, 0.f, 0.f, 0.f};

    if (deg > 0) {
        const int nit = (deg + 7) >> 3;
        uint4 kA, vA, eA, kB, vB, eB, kC, vC, eC;

        auto LD = [&](int t, uint4& kf, uint4& vf, uint4& ef) {
            const int idx = min(t * 8 + s, deg - 1);
            const int pk = packed[base + idx];              // direct, no shfl
            const unsigned short* kp = kvb + (size_t)(pk >> 7) * 128;
            kf = *(const uint4*)(kp + c0);
            vf = *(const uint4*)(kp + 64 + c0);
            ef = *(const uint4*)(etb_l + (pk & 127) * 64 + c0);
        };
        auto PROC = [&](int t, const uint4& ku, const uint4& vu, const uint4& eu) {
            const unsigned kw[4] = {ku.x, ku.y, ku.z, ku.w};
            const unsigned vw[4] = {vu.x, vu.y, vu.z, vu.w};
            const unsigned ew[4] = {eu.x, eu.y, eu.z, eu.w};
            float p = 0.f;
            float ve[8];
            #pragma unroll
            for (int i = 0; i < 4; ++i) {
                float ka, kb2, ea, eb, va, vb;
                bf2x(kw[i], ka, kb2);
                bf2x(ew[i], ea, eb);
                bf2x(vw[i], va, vb);
                p = fmaf(qf[2 * i],     ka  + ea, p);
                p = fmaf(qf[2 * i + 1], kb2 + eb, p);
                ve[2 * i]     = va + ea;
                ve[2 * i + 1] = vb + eb;
            }
            p += __shfl_xor(p, 1, 64);               // 16-ch head reduce
            const float ex = (t * 8 + s < deg) ? __expf(fminf(p * 0.25f, 80.f)) : 0.f;
            den += ex;
            #pragma unroll
            for (int i = 0; i < 8; ++i)
                acc[i] = fmaf(ex, ve[i], acc[i]);
        };

        LD(0, kA, vA, eA);
        LD(1, kB, vB, eB);
        int t = 0;
        for (; t + 3 <= nit; t += 3) {
            LD(t + 2, kC, vC, eC); PROC(t,     kA, vA, eA);
            LD(t + 3, kA, vA, eA); PROC(t + 1, kB, vB, eB);
            LD(t + 4, kB, vB, eB); PROC(t + 2, kC, vC, eC);
        }
        if (t     < nit) PROC(t,     kA, vA, eA);
        if (t + 1 < nit) PROC(t + 1, kB, vB, eB);
    }

    // merge the 8 slots' partials (butterfly over lane bits 3..5)
    #pragma unroll
    for (int off = 8; off <= 32; off <<= 1) {
        den += __shfl_xor(den, off, 64);
        #pragma unroll
        for (int i = 0; i < 8; ++i)
            acc[i] += __shfl_xor(acc[i], off, 64);
    }

    if (s == 0) {
        const float inv = 1.f / (den + 1e-16f);
        const float4 xsa = *(const float4*)(xs + (size_t)n * 64 + c0);
        const float4 xsb = *(const float4*)(xs + (size_t)n * 64 + c0 + 4);
        float o[8];
        o[0] = fmaxf(acc[0] * inv + xsa.x, 0.f);
        o[1] = fmaxf(acc[1] * inv + xsa.y, 0.f);
        o[2] = fmaxf(acc[2] * inv + xsa.z, 0.f);
        o[3] = fmaxf(acc[3] * inv + xsa.w, 0.f);
        o[4] = fmaxf(acc[4] * inv + xsb.x, 0.f);
        o[5] = fmaxf(acc[5] * inv + xsb.y, 0.f);
        o[6] = fmaxf(acc[6] * inv + xsb.z, 0.f);
        o[7] = fmaxf(acc[7] * inv + xsb.w, 0.f);

        if (WRITE_X) {
            float4 oa = {o[0], o[1], o[2], o[3]};
            float4 ob = {o[4], o[5], o[6], o[7]};
            *(float4*)(x + (size_t)n * 64 + c0)     = oa;
            *(float4*)(x + (size_t)n * 64 + c0 + 4) = ob;
        }

        ushort4 ha, hb, la, lb;
        split_bf(o[0], ha.x, la.x); split_bf(o[1], ha.y, la.y);
        split_bf(o[2], ha.z, la.z); split_bf(o[3], ha.w, la.w);
        split_bf(o[4], hb.x, lb.x); split_bf(o[5], hb.y, lb.y);
        split_bf(o[6], hb.z, lb.z); split_bf(o[7], hb.w, lb.w);
        *(ushort4*)(xhi + (size_t)n * 64 + c0)     = ha;
        *(ushort4*)(xhi + (size_t)n * 64 + c0 + 4) = hb;
        *(ushort4*)(xlo + (size_t)n * 64 + c0)     = la;
        *(ushort4*)(xlo + (size_t)n * 64 + c0 + 4) = lb;
    }
}

// ---------------------------------------------------------------------------
// Fused mean-pool + classifier head: one 128-thread block per graph.
// ---------------------------------------------------------------------------
__global__ __launch_bounds__(128) void pool_head_kernel(
    const float* __restrict__ x, const int* __restrict__ gstart,
    const float* __restrict__ fc_W, const float* __restrict__ fc_b,
    float* __restrict__ out)
{
    __shared__ float tmp[128];
    __shared__ float p[HID_C];
    const int g = blockIdx.x;
    const int s0 = gstart[g], s1 = gstart[g + 1];
    const int ch = threadIdx.x & 63;
    const int half = threadIdx.x >> 6;

    float acc = 0.f;
    for (int n = s0 + half; n < s1; n += 2)
        acc += x[(size_t)n * 64 + ch];
    tmp[threadIdx.x] = acc;
    __syncthreads();
    if (half == 0)
        p[ch] = (tmp[ch] + tmp[64 + ch]) / fmaxf((float)(s1 - s0), 1.f);
    __syncthreads();

    const int o = threadIdx.x;            // 0..127
    float rr = fc_b[o];
    #pragma unroll 8
    for (int i = 0; i < HID_C; ++i)
        rr = fmaf(p[i], fc_W[i * OUT_C + o], rr);
    out[(size_t)g * OUT_C + o] = rr;
}

// ---------------------------------------------------------------------------
extern "C" void kernel_launch(void* const* d_in, const int* in_sizes, int n_in,
                              void* d_out, int out_size, void* d_ws, size_t ws_size,
                              hipStream_t stream)
{
    const int*   x_atom     = (const int*)  d_in[0];
    const int*   edge_index = (const int*)  d_in[1];
    const int*   edge_attr  = (const int*)  d_in[2];
    const int*   batch      = (const int*)  d_in[3];
    const float* lap_pe     = (const float*)d_in[4];
    const float* rwse       = (const float*)d_in[5];
    const float* atom_emb   = (const float*)d_in[6];
    const float* bond_emb   = (const float*)d_in[7];
    const float* sign_W1    = (const float*)d_in[8];
    const float* sign_b1    = (const float*)d_in[9];
    const float* sign_W2    = (const float*)d_in[10];
    const float* sign_b2    = (const float*)d_in[11];
    const float* rwse_W1    = (const float*)d_in[12];
    const float* rwse_b1    = (const float*)d_in[13];
    const float* rwse_W2    = (const float*)d_in[14];
    const float* rwse_b2    = (const float*)d_in[15];
    const float* Wq = (const float*)d_in[16];
    const float* bq = (const float*)d_in[17];
    const float* Wk = (const float*)d_in[18];
    const float* bk = (const float*)d_in[19];
    const float* Wv = (const float*)d_in[20];
    const float* bv = (const float*)d_in[21];
    const float* We = (const float*)d_in[22];
    const float* be = (const float*)d_in[23];
    const float* Ws = (const float*)d_in[24];
    const float* bs = (const float*)d_in[25];
    const float* fc_W = (const float*)d_in[26];
    const float* fc_b = (const float*)d_in[27];
    float* out = (float*)d_out;

    char* ws = (char*)d_ws;
    size_t off = 0;
    auto alloc = [&](size_t bytes) {
        size_t o = off;
        off += (bytes + 255) & ~(size_t)255;
        return o;
    };
    float* x    = (float*)(ws + alloc((size_t)N_NODES_C * HID_C * 4));
    float* xs   = (float*)(ws + alloc((size_t)N_NODES_C * HID_C * 4));
    unsigned short* qb  = (unsigned short*)(ws + alloc((size_t)N_NODES_C * HID_C * 2));
    unsigned short* kvb = (unsigned short*)(ws + alloc((size_t)N_NODES_C * HID_C * 2 * 2));
    unsigned short* xhi = (unsigned short*)(ws + alloc((size_t)N_NODES_PAD * HID_C * 2));
    unsigned short* xlo = (unsigned short*)(ws + alloc((size_t)N_NODES_PAD * HID_C * 2));
    unsigned short* bt_hi = (unsigned short*)(ws + alloc((size_t)LAYERS_C * 256 * 64 * 2));
    unsigned short* bt_lo = (unsigned short*)(ws + alloc((size_t)LAYERS_C * 256 * 64 * 2));
    unsigned short* etb = (unsigned short*)(ws + alloc((size_t)LAYERS_C * NCODES_C * HID_C * 2));
    int* cnt    = (int*)  (ws + alloc((size_t)N_NODES_C * 4));
    int* packed = (int*)  (ws + alloc((size_t)N_NODES_C * MAXDEG_C * 4));
    int* gstart = (int*)  (ws + alloc((size_t)(GRAPHS_C + 1) * 4));

    mega_prologue_kernel<<<PRO_BLK, 256, 0, stream>>>(
        x_atom, lap_pe, rwse, atom_emb,
        sign_W1, sign_b1, sign_W2, sign_b2,
        rwse_W1, rwse_b1, rwse_W2, rwse_b2,
        bond_emb, We, be, Wq, Wk, Wv, Ws, batch,
        xhi, xlo, bt_hi, bt_lo, etb, gstart, cnt);

    const int qkvs_grid = (N_NODES_C + 63) / 64;     // 313
    const int attn_grid = N_NODES_C / 4;             // 5000

    // layer 0 projections fused with the single-pass CSR bucketing
    scatter_qkvs_kernel<<<SCAT_BLK + qkvs_grid, 256, 0, stream>>>(
        edge_index, edge_attr, cnt, packed,
        xhi, xlo, bt_hi, bt_lo,
        bq, bk, bv, bs, qb, kvb, xs);

    for (int l = 0; l < LAYERS_C; ++l) {
        const unsigned short* el = etb + (size_t)l * NCODES_C * HID_C;
        if (l > 0) {
            qkvs_mfma_kernel<<<qkvs_grid, 256, 0, stream>>>(
                xhi, xlo,
                bt_hi + (size_t)l * 256 * 64, bt_lo + (size_t)l * 256 * 64,
                bq + l * 64, bk + l * 64, bv + l * 64, bs + l * 64, qb, kvb, xs);
        }
        if (l < LAYERS_C - 1)
            attn_kernel<0><<<attn_grid, 256, 0, stream>>>(qb, kvb, xs, el, cnt, packed, x, xhi, xlo);
        else
            attn_kernel<1><<<attn_grid, 256, 0, stream>>>(qb, kvb, xs, el, cnt, packed, x, xhi, xlo);
    }

    pool_head_kernel<<<GRAPHS_C, 128, 0, stream>>>(x, gstart, fc_W, fc_b, out);
}

// Round 11
// 309.972 us; speedup vs baseline: 2.3278x; 1.0120x over previous
//
#include <hip/hip_runtime.h>
#include <hip/hip_bf16.h>

#define N_NODES_C 20000
#define N_NODES_PAD 20032
#define N_EDGES_C 640000
#define HID_C 64
#define GRAPHS_C 512
#define OUT_C 128
#define PE_DIM_C 10
#define ATOM_FEATS_C 9
#define ATOM_VOCAB_C 119
#define BOND_VOCAB_C 5
#define LAYERS_C 3
#define NCODES_C 125   // 5*5*5 distinct bond-type combinations
#define MAXDEG_C 96    // fixed bucket stride; P(deg>96) ~ 1e-18 for Poisson(32)

typedef __attribute__((ext_vector_type(8))) short bf16x8;
typedef __attribute__((ext_vector_type(4))) float f32x4;
typedef _Float16 f16x2 __attribute__((ext_vector_type(2)));

static __device__ __forceinline__ void split_bf(float f, unsigned short& hi, unsigned short& lo)
{
    __hip_bfloat16 h = __float2bfloat16(f);
    float fh = __bfloat162float(h);
    __hip_bfloat16 l = __float2bfloat16(f - fh);
    hi = *reinterpret_cast<unsigned short*>(&h);
    lo = *reinterpret_cast<unsigned short*>(&l);
}

static __device__ __forceinline__ unsigned short f2h(float f)
{
    union { _Float16 h; unsigned short s; } u;
    u.h = (_Float16)f;
    return u.s;
}

union U4 { uint4 u; f16x2 h[4]; };

// ---------------------------------------------------------------------------
// Mega-prologue, one dispatch. Block ranges:
//   [0,625)    node encoder (32 nodes/block) -> xhi/xlo (split-bf16)
//   [625,817)  prep_w: split Wq/Wk/Wv/Ws bf16 hi/lo transposed [n][k]
//   [817,942)  bond tables eth (fp16)
//   942        graph boundaries gstart
//   [943,1022) zero cnt
// ---------------------------------------------------------------------------
#define NE_NPB 32
#define NE_BLK 625
#define PW_BLK 192
#define BOND_BLK 125
#define Z_BLK 79
#define PRO_BLK (NE_BLK + PW_BLK + BOND_BLK + 1 + Z_BLK)

__global__ __launch_bounds__(256) void mega_prologue_kernel(
    const int* __restrict__ x_atom, const float* __restrict__ lap_pe,
    const float* __restrict__ rwse, const float* __restrict__ atom_emb,
    const float* __restrict__ sW1, const float* __restrict__ sb1,
    const float* __restrict__ sW2, const float* __restrict__ sb2,
    const float* __restrict__ rW1, const float* __restrict__ rb1,
    const float* __restrict__ rW2, const float* __restrict__ rb2,
    const float* __restrict__ bond_emb, const float* __restrict__ We,
    const float* __restrict__ be,
    const float* __restrict__ Wq, const float* __restrict__ Wk,
    const float* __restrict__ Wv, const float* __restrict__ Ws,
    const int* __restrict__ batch,
    unsigned short* __restrict__ xhi, unsigned short* __restrict__ xlo,
    unsigned short* __restrict__ bt_hi, unsigned short* __restrict__ bt_lo,
    unsigned short* __restrict__ eth,
    int* __restrict__ gstart, int* __restrict__ cnt)
{
    __shared__ float hs[NE_NPB][HID_C];
    __shared__ float hr[NE_NPB][HID_C];
    __shared__ float tb[HID_C];
    const int b = blockIdx.x;

    if (b < NE_BLK) {
        const int w = threadIdx.x >> 6;
        const int j = threadIdx.x & 63;
        const int nbase = b * NE_NPB + w * 8;

        float sw2[64], rw2[64];
        #pragma unroll
        for (int i = 0; i < 64; ++i) {
            sw2[i] = sW2[i * 64 + j];
            rw2[i] = rW2[i * 64 + j];
        }
        float sw1[PE_DIM_C], rw1[PE_DIM_C];
        #pragma unroll
        for (int i = 0; i < PE_DIM_C; ++i) {
            sw1[i] = sW1[i * 64 + j];
            rw1[i] = rW1[i * 64 + j];
        }
        const float sb1j = sb1[j], rb1j = rb1[j];
        const float cb = 2.f * sb2[j] + rb2[j];

        float o[8];
        #pragma unroll
        for (int nn = 0; nn < 8; ++nn) {
            const int n = nbase + nn;
            float acc = 0.f;
            #pragma unroll
            for (int f = 0; f < ATOM_FEATS_C; ++f)
                acc += atom_emb[(f * ATOM_VOCAB_C + x_atom[n * ATOM_FEATS_C + f]) * 64 + j];
            float h1 = sb1j, h2 = sb1j, hv = rb1j;
            #pragma unroll
            for (int i = 0; i < PE_DIM_C; ++i) {
                float pv = lap_pe[n * PE_DIM_C + i];
                h1 += pv * sw1[i];
                h2 -= pv * sw1[i];
                hv += rwse[n * PE_DIM_C + i] * rw1[i];
            }
            hs[w * 8 + nn][j] = fmaxf(h1, 0.f) + fmaxf(h2, 0.f);
            hr[w * 8 + nn][j] = fmaxf(hv, 0.f);
            o[nn] = acc + cb;
        }
        __syncthreads();
        #pragma unroll
        for (int nn = 0; nn < 8; ++nn) {
            const float* hsp = hs[w * 8 + nn];
            const float* hrp = hr[w * 8 + nn];
            float a = o[nn];
            #pragma unroll
            for (int i = 0; i < 64; ++i)
                a += hsp[i] * sw2[i] + hrp[i] * rw2[i];
            const size_t idx = (size_t)(nbase + nn) * 64 + j;
            unsigned short hi, lo;
            split_bf(a, hi, lo);
            xhi[idx] = hi;
            xlo[idx] = lo;
        }
    } else if (b < NE_BLK + PW_BLK) {
        const int idx = (b - NE_BLK) * 256 + threadIdx.x;  // 3*4*64*64 = 49152
        const int j = idx & 63;
        const int k = (idx >> 6) & 63;
        const int mat = (idx >> 12) & 3;
        const int l = idx >> 14;
        const float* W;
        if      (mat == 0) W = Wq;
        else if (mat == 1) W = Wk;
        else if (mat == 2) W = Wv;
        else               W = Ws;
        const float wv = W[(size_t)l * 4096 + k * 64 + j];
        unsigned short hi, lo;
        split_bf(wv, hi, lo);
        const size_t o = ((size_t)l * 256 + mat * 64 + j) * 64 + k;
        bt_hi[o] = hi;
        bt_lo[o] = lo;
    } else if (b < NE_BLK + PW_BLK + BOND_BLK) {
        const int c = b - NE_BLK - PW_BLK;
        const int j = threadIdx.x;
        if (j < 64) {
            const int f0 = c / 25, f1 = (c / 5) % 5, f2 = c % 5;
            tb[j] = bond_emb[(0 * BOND_VOCAB_C + f0) * HID_C + j]
                  + bond_emb[(1 * BOND_VOCAB_C + f1) * HID_C + j]
                  + bond_emb[(2 * BOND_VOCAB_C + f2) * HID_C + j];
        }
        __syncthreads();
        if (j < 64) {
            for (int l = 0; l < LAYERS_C; ++l) {
                float o = be[l * HID_C + j];
                #pragma unroll 8
                for (int i = 0; i < HID_C; ++i)
                    o += tb[i] * We[(l * HID_C + i) * HID_C + j];
                eth[(l * NCODES_C + c) * HID_C + j] = f2h(o);
            }
        }
    } else if (b == NE_BLK + PW_BLK + BOND_BLK) {
        for (int g = threadIdx.x; g <= GRAPHS_C; g += 256) {
            int lo = 0, hi = N_NODES_C;
            while (lo < hi) {
                int mid = (lo + hi) >> 1;
                if (batch[mid] < g) lo = mid + 1; else hi = mid;
            }
            gstart[g] = lo;
        }
    } else {
        const int i = (b - NE_BLK - PW_BLK - BOND_BLK - 1) * 256 + threadIdx.x;
        if (i < N_NODES_C) cnt[i] = 0;
    }
}

// ---------------------------------------------------------------------------
// Projections via split-bf16 MFMA (device body, shared by two kernels).
// acc += Ahi*Bhi + Ahi*Blo + Alo*Bhi  (f32 accum; lo*lo dropped ~2^-18).
// Outputs: qh (fp16 [n][64]), kvh (fp16 [n][128] = k|v), xs (f32).
// ---------------------------------------------------------------------------
static __device__ __forceinline__ void qkvs_tile_body(
    int tile, int tid,
    const unsigned short* __restrict__ xhi, const unsigned short* __restrict__ xlo,
    const unsigned short* __restrict__ bt_hi, const unsigned short* __restrict__ bt_lo,
    const float* __restrict__ bq, const float* __restrict__ bk,
    const float* __restrict__ bv, const float* __restrict__ bs,
    unsigned short* __restrict__ qh, unsigned short* __restrict__ kvh,
    float* __restrict__ xs)
{
    const int w    = tid >> 6;   // matrix 0..3
    const int lane = tid & 63;
    const int lr   = lane & 15;
    const int lg   = lane >> 4;
    const int m0   = tile * 64;

    f32x4 acc[4][4];
    #pragma unroll
    for (int m = 0; m < 4; ++m)
        #pragma unroll
        for (int n = 0; n < 4; ++n)
            acc[m][n] = (f32x4){0.f, 0.f, 0.f, 0.f};

    const unsigned short* bth = bt_hi + (size_t)(w * 64) * 64;
    const unsigned short* btl = bt_lo + (size_t)(w * 64) * 64;

    #pragma unroll
    for (int pass = 0; pass < 3; ++pass) {
        const unsigned short* Ap = (pass == 2) ? xlo : xhi;
        const unsigned short* Bp = (pass == 1) ? btl : bth;
        #pragma unroll
        for (int kk = 0; kk < 2; ++kk) {
            const int kb = kk * 32 + lg * 8;
            bf16x8 a[4], b[4];
            #pragma unroll
            for (int m = 0; m < 4; ++m)
                a[m] = *(const bf16x8*)(Ap + (size_t)(m0 + m * 16 + lr) * 64 + kb);
            #pragma unroll
            for (int n = 0; n < 4; ++n)
                b[n] = *(const bf16x8*)(Bp + (size_t)(n * 16 + lr) * 64 + kb);
            #pragma unroll
            for (int m = 0; m < 4; ++m)
                #pragma unroll
                for (int n = 0; n < 4; ++n)
                    acc[m][n] = __builtin_amdgcn_mfma_f32_16x16x32_bf16(a[m], b[n], acc[m][n], 0, 0, 0);
        }
    }

    const float* bias = (w == 0) ? bq : (w == 1) ? bk : (w == 2) ? bv : bs;
    float bv4[4];
    #pragma unroll
    for (int n = 0; n < 4; ++n) bv4[n] = bias[n * 16 + lr];

    #pragma unroll
    for (int m = 0; m < 4; ++m) {
        #pragma unroll
        for (int rr = 0; rr < 4; ++rr) {
            const int row = m0 + m * 16 + lg * 4 + rr;
            if (row < N_NODES_C) {
                #pragma unroll
                for (int n = 0; n < 4; ++n) {
                    const float val = acc[m][n][rr] + bv4[n];
                    const int ch = n * 16 + lr;
                    if      (w == 0) qh [(size_t)row * 64  + ch]      = f2h(val);
                    else if (w == 1) kvh[(size_t)row * 128 + ch]      = f2h(val);
                    else if (w == 2) kvh[(size_t)row * 128 + 64 + ch] = f2h(val);
                    else             xs [(size_t)row * 64  + ch]      = val;
                }
            }
        }
    }
}

__global__ __launch_bounds__(256) void qkvs_mfma_kernel(
    const unsigned short* __restrict__ xhi, const unsigned short* __restrict__ xlo,
    const unsigned short* __restrict__ bt_hi, const unsigned short* __restrict__ bt_lo,
    const float* __restrict__ bq, const float* __restrict__ bk,
    const float* __restrict__ bv, const float* __restrict__ bs,
    unsigned short* __restrict__ qh, unsigned short* __restrict__ kvh,
    float* __restrict__ xs)
{
    qkvs_tile_body(blockIdx.x, threadIdx.x, xhi, xlo, bt_hi, bt_lo,
                   bq, bk, bv, bs, qh, kvh, xs);
}

// ---------------------------------------------------------------------------
// Fused single-pass CSR bucketing (blocks [0,2500)) + layer-0 projections
// (blocks [2500,2813)). packed[dst*96+p] via NON-TEMPORAL store: bypasses
// L2 write-allocate (round-9 profile: 51 MB WRITE_SIZE for a 7.7 MB array
// = RMW line thrash).
// ---------------------------------------------------------------------------
#define SCAT_BLK ((N_EDGES_C + 255) / 256)
__global__ __launch_bounds__(256) void scatter_qkvs_kernel(
    const int* __restrict__ ei, const int* __restrict__ ea,
    int* __restrict__ cnt, int* __restrict__ packed,
    const unsigned short* __restrict__ xhi, const unsigned short* __restrict__ xlo,
    const unsigned short* __restrict__ bt_hi, const unsigned short* __restrict__ bt_lo,
    const float* __restrict__ bq, const float* __restrict__ bk,
    const float* __restrict__ bv, const float* __restrict__ bs,
    unsigned short* __restrict__ qh, unsigned short* __restrict__ kvh,
    float* __restrict__ xs)
{
    if (blockIdx.x < SCAT_BLK) {
        const int e = blockIdx.x * 256 + threadIdx.x;
        if (e < N_EDGES_C) {
            const int src  = ei[e];
            const int dst  = ei[N_EDGES_C + e];
            const int code = ea[e * 3] * 25 + ea[e * 3 + 1] * 5 + ea[e * 3 + 2];
            const int p = atomicAdd(&cnt[dst], 1);
            if (p < MAXDEG_C)
                __builtin_nontemporal_store((src << 7) | code, &packed[dst * MAXDEG_C + p]);
        }
    } else {
        qkvs_tile_body(blockIdx.x - SCAT_BLK, threadIdx.x, xhi, xlo, bt_hi, bt_lo,
                       bq, bk, bv, bs, qh, kvh, xs);
    }
}

// ---------------------------------------------------------------------------
// Attention (fp16 operands): one wave per node; 8 edge slots x 8 lanes; lane
// owns channels 8r..8r+7 as 4x f16x2. k+e / v+e via v_pk_add_f16; qk dot via
// v_dot2_f32_f16 (fdot2, f32 accum). Direct per-lane packed loads, depth-2
// pipeline. No max-shift (softmax shift-invariant; logits O(1), clamp 80).
// WRITE_X: emit f32 x for pooling (last layer only).
// ---------------------------------------------------------------------------
template<int WRITE_X>
__global__ __launch_bounds__(256) void attn_kernel(
    const unsigned short* __restrict__ qh, const unsigned short* __restrict__ kvh,
    const float* __restrict__ xs, const unsigned short* __restrict__ eth_l,
    const int* __restrict__ cnt, const int* __restrict__ packed,
    float* __restrict__ x, unsigned short* __restrict__ xhi,
    unsigned short* __restrict__ xlo)
{
    const int lane = threadIdx.x & 63;
    const int s    = lane >> 3;          // edge slot 0..7
    const int r    = lane & 7;           // channel group
    const int c0   = r * 8;              // channels c0..c0+7
    const int n    = blockIdx.x * 4 + (threadIdx.x >> 6);

    f16x2 q2[4];
    {
        U4 qu; qu.u = *(const uint4*)(qh + (size_t)n * 64 + c0);
        q2[0] = qu.h[0]; q2[1] = qu.h[1]; q2[2] = qu.h[2]; q2[3] = qu.h[3];
    }
    const int deg  = min(cnt[n], MAXDEG_C);
    const int base = n * MAXDEG_C;

    float den = 0.f;
    float acc[8] = {0.f, 0.f, 0.f, 0.f, 0.f, 0.f, 0.f, 0.f};

    if (deg > 0) {
        const int nit = (deg + 7) >> 3;
        uint4 kA, vA, eA, kB, vB, eB, kC, vC, eC;

        auto LD = [&](int t, uint4& kf, uint4& vf, uint4& ef) {
            const int idx = min(t * 8 + s, deg - 1);
            const int pk = packed[base + idx];              // direct, no shfl
            const unsigned short* kp = kvh + (size_t)(pk >> 7) * 128;
            kf = *(const uint4*)(kp + c0);
            vf = *(const uint4*)(kp + 64 + c0);
            ef = *(const uint4*)(eth_l + (pk & 127) * 64 + c0);
        };
        auto PROC = [&](int t, const uint4& ku, const uint4& vu, const uint4& eu) {
            U4 kk, vv, ee;
            kk.u = ku; vv.u = vu; ee.u = eu;
            float p = 0.f;
            f16x2 ve[4];
            #pragma unroll
            for (int i = 0; i < 4; ++i) {
                f16x2 ke = kk.h[i] + ee.h[i];               // v_pk_add_f16
                p = __builtin_amdgcn_fdot2(q2[i], ke, p, false);
                ve[i] = vv.h[i] + ee.h[i];                  // v_pk_add_f16
            }
            p += __shfl_xor(p, 1, 64);                      // 16-ch head reduce
            const float ex = (t * 8 + s < deg) ? __expf(fminf(p * 0.25f, 80.f)) : 0.f;
            den += ex;
            #pragma unroll
            for (int i = 0; i < 4; ++i) {
                acc[2 * i]     = fmaf(ex, (float)ve[i][0], acc[2 * i]);
                acc[2 * i + 1] = fmaf(ex, (float)ve[i][1], acc[2 * i + 1]);
            }
        };

        LD(0, kA, vA, eA);
        LD(1, kB, vB, eB);
        int t = 0;
        for (; t + 3 <= nit; t += 3) {
            LD(t + 2, kC, vC, eC); PROC(t,     kA, vA, eA);
            LD(t + 3, kA, vA, eA); PROC(t + 1, kB, vB, eB);
            LD(t + 4, kB, vB, eB); PROC(t + 2, kC, vC, eC);
        }
        if (t     < nit) PROC(t,     kA, vA, eA);
        if (t + 1 < nit) PROC(t + 1, kB, vB, eB);
    }

    // merge the 8 slots' partials (butterfly over lane bits 3..5)
    #pragma unroll
    for (int off = 8; off <= 32; off <<= 1) {
        den += __shfl_xor(den, off, 64);
        #pragma unroll
        for (int i = 0; i < 8; ++i)
            acc[i] += __shfl_xor(acc[i], off, 64);
    }

    if (s == 0) {
        const float inv = 1.f / (den + 1e-16f);
        const float4 xsa = *(const float4*)(xs + (size_t)n * 64 + c0);
        const float4 xsb = *(const float4*)(xs + (size_t)n * 64 + c0 + 4);
        float o[8];
        o[0] = fmaxf(acc[0] * inv + xsa.x, 0.f);
        o[1] = fmaxf(acc[1] * inv + xsa.y, 0.f);
        o[2] = fmaxf(acc[2] * inv + xsa.z, 0.f);
        o[3] = fmaxf(acc[3] * inv + xsa.w, 0.f);
        o[4] = fmaxf(acc[4] * inv + xsb.x, 0.f);
        o[5] = fmaxf(acc[5] * inv + xsb.y, 0.f);
        o[6] = fmaxf(acc[6] * inv + xsb.z, 0.f);
        o[7] = fmaxf(acc[7] * inv + xsb.w, 0.f);

        if (WRITE_X) {
            float4 oa = {o[0], o[1], o[2], o[3]};
            float4 ob = {o[4], o[5], o[6], o[7]};
            *(float4*)(x + (size_t)n * 64 + c0)     = oa;
            *(float4*)(x + (size_t)n * 64 + c0 + 4) = ob;
        }

        ushort4 ha, hb, la, lb;
        split_bf(o[0], ha.x, la.x); split_bf(o[1], ha.y, la.y);
        split_bf(o[2], ha.z, la.z); split_bf(o[3], ha.w, la.w);
        split_bf(o[4], hb.x, lb.x); split_bf(o[5], hb.y, lb.y);
        split_bf(o[6], hb.z, lb.z); split_bf(o[7], hb.w, lb.w);
        *(ushort4*)(xhi + (size_t)n * 64 + c0)     = ha;
        *(ushort4*)(xhi + (size_t)n * 64 + c0 + 4) = hb;
        *(ushort4*)(xlo + (size_t)n * 64 + c0)     = la;
        *(ushort4*)(xlo + (size_t)n * 64 + c0 + 4) = lb;
    }
}

// ---------------------------------------------------------------------------
// Fused mean-pool + classifier head: one 128-thread block per graph.
// ---------------------------------------------------------------------------
__global__ __launch_bounds__(128) void pool_head_kernel(
    const float* __restrict__ x, const int* __restrict__ gstart,
    const float* __restrict__ fc_W, const float* __restrict__ fc_b,
    float* __restrict__ out)
{
    __shared__ float tmp[128];
    __shared__ float p[HID_C];
    const int g = blockIdx.x;
    const int s0 = gstart[g], s1 = gstart[g + 1];
    const int ch = threadIdx.x & 63;
    const int half = threadIdx.x >> 6;

    float acc = 0.f;
    for (int n = s0 + half; n < s1; n += 2)
        acc += x[(size_t)n * 64 + ch];
    tmp[threadIdx.x] = acc;
    __syncthreads();
    if (half == 0)
        p[ch] = (tmp[ch] + tmp[64 + ch]) / fmaxf((float)(s1 - s0), 1.f);
    __syncthreads();

    const int o = threadIdx.x;            // 0..127
    float rr = fc_b[o];
    #pragma unroll 8
    for (int i = 0; i < HID_C; ++i)
        rr = fmaf(p[i], fc_W[i * OUT_C + o], rr);
    out[(size_t)g * OUT_C + o] = rr;
}

// ---------------------------------------------------------------------------
extern "C" void kernel_launch(void* const* d_in, const int* in_sizes, int n_in,
                              void* d_out, int out_size, void* d_ws, size_t ws_size,
                              hipStream_t stream)
{
    const int*   x_atom     = (const int*)  d_in[0];
    const int*   edge_index = (const int*)  d_in[1];
    const int*   edge_attr  = (const int*)  d_in[2];
    const int*   batch      = (const int*)  d_in[3];
    const float* lap_pe     = (const float*)d_in[4];
    const float* rwse       = (const float*)d_in[5];
    const float* atom_emb   = (const float*)d_in[6];
    const float* bond_emb   = (const float*)d_in[7];
    const float* sign_W1    = (const float*)d_in[8];
    const float* sign_b1    = (const float*)d_in[9];
    const float* sign_W2    = (const float*)d_in[10];
    const float* sign_b2    = (const float*)d_in[11];
    const float* rwse_W1    = (const float*)d_in[12];
    const float* rwse_b1    = (const float*)d_in[13];
    const float* rwse_W2    = (const float*)d_in[14];
    const float* rwse_b2    = (const float*)d_in[15];
    const float* Wq = (const float*)d_in[16];
    const float* bq = (const float*)d_in[17];
    const float* Wk = (const float*)d_in[18];
    const float* bk = (const float*)d_in[19];
    const float* Wv = (const float*)d_in[20];
    const float* bv = (const float*)d_in[21];
    const float* We = (const float*)d_in[22];
    const float* be = (const float*)d_in[23];
    const float* Ws = (const float*)d_in[24];
    const float* bs = (const float*)d_in[25];
    const float* fc_W = (const float*)d_in[26];
    const float* fc_b = (const float*)d_in[27];
    float* out = (float*)d_out;

    char* ws = (char*)d_ws;
    size_t off = 0;
    auto alloc = [&](size_t bytes) {
        size_t o = off;
        off += (bytes + 255) & ~(size_t)255;
        return o;
    };
    float* x    = (float*)(ws + alloc((size_t)N_NODES_C * HID_C * 4));
    float* xs   = (float*)(ws + alloc((size_t)N_NODES_C * HID_C * 4));
    unsigned short* qh  = (unsigned short*)(ws + alloc((size_t)N_NODES_C * HID_C * 2));
    unsigned short* kvh = (unsigned short*)(ws + alloc((size_t)N_NODES_C * HID_C * 2 * 2));
    unsigned short* xhi = (unsigned short*)(ws + alloc((size_t)N_NODES_PAD * HID_C * 2));
    unsigned short* xlo = (unsigned short*)(ws + alloc((size_t)N_NODES_PAD * HID_C * 2));
    unsigned short* bt_hi = (unsigned short*)(ws + alloc((size_t)LAYERS_C * 256 * 64 * 2));
    unsigned short* bt_lo = (unsigned short*)(ws + alloc((size_t)LAYERS_C * 256 * 64 * 2));
    unsigned short* eth = (unsigned short*)(ws + alloc((size_t)LAYERS_C * NCODES_C * HID_C * 2));
    int* cnt    = (int*)  (ws + alloc((size_t)N_NODES_C * 4));
    int* packed = (int*)  (ws + alloc((size_t)N_NODES_C * MAXDEG_C * 4));
    int* gstart = (int*)  (ws + alloc((size_t)(GRAPHS_C + 1) * 4));

    mega_prologue_kernel<<<PRO_BLK, 256, 0, stream>>>(
        x_atom, lap_pe, rwse, atom_emb,
        sign_W1, sign_b1, sign_W2, sign_b2,
        rwse_W1, rwse_b1, rwse_W2, rwse_b2,
        bond_emb, We, be, Wq, Wk, Wv, Ws, batch,
        xhi, xlo, bt_hi, bt_lo, eth, gstart, cnt);

    const int qkvs_grid = (N_NODES_C + 63) / 64;     // 313
    const int attn_grid = N_NODES_C / 4;             // 5000

    // layer 0 projections fused with the single-pass CSR bucketing
    scatter_qkvs_kernel<<<SCAT_BLK + qkvs_grid, 256, 0, stream>>>(
        edge_index, edge_attr, cnt, packed,
        xhi, xlo, bt_hi, bt_lo,
        bq, bk, bv, bs, qh, kvh, xs);

    for (int l = 0; l < LAYERS_C; ++l) {
        const unsigned short* el = eth + (size_t)l * NCODES_C * HID_C;
        if (l > 0) {
            qkvs_mfma_kernel<<<qkvs_grid, 256, 0, stream>>>(
                xhi, xlo,
                bt_hi + (size_t)l * 256 * 64, bt_lo + (size_t)l * 256 * 64,
                bq + l * 64, bk + l * 64, bv + l * 64, bs + l * 64, qh, kvh, xs);
        }
        if (l < LAYERS_C - 1)
            attn_kernel<0><<<attn_grid, 256, 0, stream>>>(qh, kvh, xs, el, cnt, packed, x, xhi, xlo);
        else
            attn_kernel<1><<<attn_grid, 256, 0, stream>>>(qh, kvh, xs, el, cnt, packed, x, xhi, xlo);
    }

    pool_head_kernel<<<GRAPHS_C, 128, 0, stream>>>(x, gstart, fc_W, fc_b, out);
}

// Round 12
// 302.293 us; speedup vs baseline: 2.3870x; 1.0254x over previous
//
#include <hip/hip_runtime.h>
#include <hip/hip_bf16.h>

#define N_NODES_C 20000
#define N_NODES_PAD 20032
#define N_EDGES_C 640000
#define HID_C 64
#define GRAPHS_C 512
#define OUT_C 128
#define PE_DIM_C 10
#define ATOM_FEATS_C 9
#define ATOM_VOCAB_C 119
#define BOND_VOCAB_C 5
#define LAYERS_C 3
#define NCODES_C 125   // 5*5*5 distinct bond-type combinations
#define MAXDEG_C 96    // fixed bucket stride; P(deg>96) ~ 1e-18 for Poisson(32)
#define CNT_STRIDE 16  // one counter per 64B line: kills cross-XCD false sharing

typedef __attribute__((ext_vector_type(8))) short bf16x8;
typedef __attribute__((ext_vector_type(4))) float f32x4;
typedef _Float16 f16x2 __attribute__((ext_vector_type(2)));

static __device__ __forceinline__ void split_bf(float f, unsigned short& hi, unsigned short& lo)
{
    __hip_bfloat16 h = __float2bfloat16(f);
    float fh = __bfloat162float(h);
    __hip_bfloat16 l = __float2bfloat16(f - fh);
    hi = *reinterpret_cast<unsigned short*>(&h);
    lo = *reinterpret_cast<unsigned short*>(&l);
}

static __device__ __forceinline__ unsigned short f2h(float f)
{
    union { _Float16 h; unsigned short s; } u;
    u.h = (_Float16)f;
    return u.s;
}

union U4 { uint4 u; f16x2 h[4]; };

// ---------------------------------------------------------------------------
// Mega-prologue, one dispatch. Block ranges:
//   [0,625)      node encoder (32 nodes/block) -> xhi/xlo (split-bf16)
//   [625,817)    prep_w: split Wq/Wk/Wv/Ws bf16 hi/lo transposed [n][k]
//   [817,942)    bond tables eth (fp16)
//   942          graph boundaries gstart
//   [943,2193)   zero cnt (padded, N*16 ints)
// ---------------------------------------------------------------------------
#define NE_NPB 32
#define NE_BLK 625
#define PW_BLK 192
#define BOND_BLK 125
#define Z_BLK ((N_NODES_C * CNT_STRIDE + 255) / 256)
#define PRO_BLK (NE_BLK + PW_BLK + BOND_BLK + 1 + Z_BLK)

__global__ __launch_bounds__(256) void mega_prologue_kernel(
    const int* __restrict__ x_atom, const float* __restrict__ lap_pe,
    const float* __restrict__ rwse, const float* __restrict__ atom_emb,
    const float* __restrict__ sW1, const float* __restrict__ sb1,
    const float* __restrict__ sW2, const float* __restrict__ sb2,
    const float* __restrict__ rW1, const float* __restrict__ rb1,
    const float* __restrict__ rW2, const float* __restrict__ rb2,
    const float* __restrict__ bond_emb, const float* __restrict__ We,
    const float* __restrict__ be,
    const float* __restrict__ Wq, const float* __restrict__ Wk,
    const float* __restrict__ Wv, const float* __restrict__ Ws,
    const int* __restrict__ batch,
    unsigned short* __restrict__ xhi, unsigned short* __restrict__ xlo,
    unsigned short* __restrict__ bt_hi, unsigned short* __restrict__ bt_lo,
    unsigned short* __restrict__ eth,
    int* __restrict__ gstart, int* __restrict__ cnt)
{
    __shared__ float hs[NE_NPB][HID_C];
    __shared__ float hr[NE_NPB][HID_C];
    __shared__ float tb[HID_C];
    const int b = blockIdx.x;

    if (b < NE_BLK) {
        const int w = threadIdx.x >> 6;
        const int j = threadIdx.x & 63;
        const int nbase = b * NE_NPB + w * 8;

        float sw2[64], rw2[64];
        #pragma unroll
        for (int i = 0; i < 64; ++i) {
            sw2[i] = sW2[i * 64 + j];
            rw2[i] = rW2[i * 64 + j];
        }
        float sw1[PE_DIM_C], rw1[PE_DIM_C];
        #pragma unroll
        for (int i = 0; i < PE_DIM_C; ++i) {
            sw1[i] = sW1[i * 64 + j];
            rw1[i] = rW1[i * 64 + j];
        }
        const float sb1j = sb1[j], rb1j = rb1[j];
        const float cb = 2.f * sb2[j] + rb2[j];

        float o[8];
        #pragma unroll
        for (int nn = 0; nn < 8; ++nn) {
            const int n = nbase + nn;
            float acc = 0.f;
            #pragma unroll
            for (int f = 0; f < ATOM_FEATS_C; ++f)
                acc += atom_emb[(f * ATOM_VOCAB_C + x_atom[n * ATOM_FEATS_C + f]) * 64 + j];
            float h1 = sb1j, h2 = sb1j, hv = rb1j;
            #pragma unroll
            for (int i = 0; i < PE_DIM_C; ++i) {
                float pv = lap_pe[n * PE_DIM_C + i];
                h1 += pv * sw1[i];
                h2 -= pv * sw1[i];
                hv += rwse[n * PE_DIM_C + i] * rw1[i];
            }
            hs[w * 8 + nn][j] = fmaxf(h1, 0.f) + fmaxf(h2, 0.f);
            hr[w * 8 + nn][j] = fmaxf(hv, 0.f);
            o[nn] = acc + cb;
        }
        __syncthreads();
        #pragma unroll
        for (int nn = 0; nn < 8; ++nn) {
            const float* hsp = hs[w * 8 + nn];
            const float* hrp = hr[w * 8 + nn];
            float a = o[nn];
            #pragma unroll
            for (int i = 0; i < 64; ++i)
                a += hsp[i] * sw2[i] + hrp[i] * rw2[i];
            const size_t idx = (size_t)(nbase + nn) * 64 + j;
            unsigned short hi, lo;
            split_bf(a, hi, lo);
            xhi[idx] = hi;
            xlo[idx] = lo;
        }
    } else if (b < NE_BLK + PW_BLK) {
        const int idx = (b - NE_BLK) * 256 + threadIdx.x;  // 3*4*64*64 = 49152
        const int j = idx & 63;
        const int k = (idx >> 6) & 63;
        const int mat = (idx >> 12) & 3;
        const int l = idx >> 14;
        const float* W;
        if      (mat == 0) W = Wq;
        else if (mat == 1) W = Wk;
        else if (mat == 2) W = Wv;
        else               W = Ws;
        const float wv = W[(size_t)l * 4096 + k * 64 + j];
        unsigned short hi, lo;
        split_bf(wv, hi, lo);
        const size_t o = ((size_t)l * 256 + mat * 64 + j) * 64 + k;
        bt_hi[o] = hi;
        bt_lo[o] = lo;
    } else if (b < NE_BLK + PW_BLK + BOND_BLK) {
        const int c = b - NE_BLK - PW_BLK;
        const int j = threadIdx.x;
        if (j < 64) {
            const int f0 = c / 25, f1 = (c / 5) % 5, f2 = c % 5;
            tb[j] = bond_emb[(0 * BOND_VOCAB_C + f0) * HID_C + j]
                  + bond_emb[(1 * BOND_VOCAB_C + f1) * HID_C + j]
                  + bond_emb[(2 * BOND_VOCAB_C + f2) * HID_C + j];
        }
        __syncthreads();
        if (j < 64) {
            for (int l = 0; l < LAYERS_C; ++l) {
                float o = be[l * HID_C + j];
                #pragma unroll 8
                for (int i = 0; i < HID_C; ++i)
                    o += tb[i] * We[(l * HID_C + i) * HID_C + j];
                eth[(l * NCODES_C + c) * HID_C + j] = f2h(o);
            }
        }
    } else if (b == NE_BLK + PW_BLK + BOND_BLK) {
        for (int g = threadIdx.x; g <= GRAPHS_C; g += 256) {
            int lo = 0, hi = N_NODES_C;
            while (lo < hi) {
                int mid = (lo + hi) >> 1;
                if (batch[mid] < g) lo = mid + 1; else hi = mid;
            }
            gstart[g] = lo;
        }
    } else {
        const int i = (b - NE_BLK - PW_BLK - BOND_BLK - 1) * 256 + threadIdx.x;
        if (i < N_NODES_C * CNT_STRIDE) cnt[i] = 0;
    }
}

// ---------------------------------------------------------------------------
// Projections via split-bf16 MFMA (device body, shared by two kernels).
// acc += Ahi*Bhi + Ahi*Blo + Alo*Bhi  (f32 accum; lo*lo dropped ~2^-18).
// Outputs: qh (fp16 [n][64]), kvh (fp16 [n][128] = k|v), xs (f32).
// ---------------------------------------------------------------------------
static __device__ __forceinline__ void qkvs_tile_body(
    int tile, int tid,
    const unsigned short* __restrict__ xhi, const unsigned short* __restrict__ xlo,
    const unsigned short* __restrict__ bt_hi, const unsigned short* __restrict__ bt_lo,
    const float* __restrict__ bq, const float* __restrict__ bk,
    const float* __restrict__ bv, const float* __restrict__ bs,
    unsigned short* __restrict__ qh, unsigned short* __restrict__ kvh,
    float* __restrict__ xs)
{
    const int w    = tid >> 6;   // matrix 0..3
    const int lane = tid & 63;
    const int lr   = lane & 15;
    const int lg   = lane >> 4;
    const int m0   = tile * 64;

    f32x4 acc[4][4];
    #pragma unroll
    for (int m = 0; m < 4; ++m)
        #pragma unroll
        for (int n = 0; n < 4; ++n)
            acc[m][n] = (f32x4){0.f, 0.f, 0.f, 0.f};

    const unsigned short* bth = bt_hi + (size_t)(w * 64) * 64;
    const unsigned short* btl = bt_lo + (size_t)(w * 64) * 64;

    #pragma unroll
    for (int pass = 0; pass < 3; ++pass) {
        const unsigned short* Ap = (pass == 2) ? xlo : xhi;
        const unsigned short* Bp = (pass == 1) ? btl : bth;
        #pragma unroll
        for (int kk = 0; kk < 2; ++kk) {
            const int kb = kk * 32 + lg * 8;
            bf16x8 a[4], b[4];
            #pragma unroll
            for (int m = 0; m < 4; ++m)
                a[m] = *(const bf16x8*)(Ap + (size_t)(m0 + m * 16 + lr) * 64 + kb);
            #pragma unroll
            for (int n = 0; n < 4; ++n)
                b[n] = *(const bf16x8*)(Bp + (size_t)(n * 16 + lr) * 64 + kb);
            #pragma unroll
            for (int m = 0; m < 4; ++m)
                #pragma unroll
                for (int n = 0; n < 4; ++n)
                    acc[m][n] = __builtin_amdgcn_mfma_f32_16x16x32_bf16(a[m], b[n], acc[m][n], 0, 0, 0);
        }
    }

    const float* bias = (w == 0) ? bq : (w == 1) ? bk : (w == 2) ? bv : bs;
    float bv4[4];
    #pragma unroll
    for (int n = 0; n < 4; ++n) bv4[n] = bias[n * 16 + lr];

    #pragma unroll
    for (int m = 0; m < 4; ++m) {
        #pragma unroll
        for (int rr = 0; rr < 4; ++rr) {
            const int row = m0 + m * 16 + lg * 4 + rr;
            if (row < N_NODES_C) {
                #pragma unroll
                for (int n = 0; n < 4; ++n) {
                    const float val = acc[m][n][rr] + bv4[n];
                    const int ch = n * 16 + lr;
                    if      (w == 0) qh [(size_t)row * 64  + ch]      = f2h(val);
                    else if (w == 1) kvh[(size_t)row * 128 + ch]      = f2h(val);
                    else if (w == 2) kvh[(size_t)row * 128 + 64 + ch] = f2h(val);
                    else             xs [(size_t)row * 64  + ch]      = val;
                }
            }
        }
    }
}

__global__ __launch_bounds__(256) void qkvs_mfma_kernel(
    const unsigned short* __restrict__ xhi, const unsigned short* __restrict__ xlo,
    const unsigned short* __restrict__ bt_hi, const unsigned short* __restrict__ bt_lo,
    const float* __restrict__ bq, const float* __restrict__ bk,
    const float* __restrict__ bv, const float* __restrict__ bs,
    unsigned short* __restrict__ qh, unsigned short* __restrict__ kvh,
    float* __restrict__ xs)
{
    qkvs_tile_body(blockIdx.x, threadIdx.x, xhi, xlo, bt_hi, bt_lo,
                   bq, bk, bv, bs, qh, kvh, xs);
}

// ---------------------------------------------------------------------------
// Fused single-pass CSR bucketing (blocks [0,2500)) + layer-0 projections
// (blocks [2500,2813)). Counters padded to one per 64B line (CNT_STRIDE):
// round-11 showed the hot-line cross-XCD atomic chain (512 ops/line) was the
// serializer. Plain stores (NT store regressed: WRITE_SIZE 51->59 MB).
// ---------------------------------------------------------------------------
#define SCAT_BLK ((N_EDGES_C + 255) / 256)
__global__ __launch_bounds__(256) void scatter_qkvs_kernel(
    const int* __restrict__ ei, const int* __restrict__ ea,
    int* __restrict__ cnt, int* __restrict__ packed,
    const unsigned short* __restrict__ xhi, const unsigned short* __restrict__ xlo,
    const unsigned short* __restrict__ bt_hi, const unsigned short* __restrict__ bt_lo,
    const float* __restrict__ bq, const float* __restrict__ bk,
    const float* __restrict__ bv, const float* __restrict__ bs,
    unsigned short* __restrict__ qh, unsigned short* __restrict__ kvh,
    float* __restrict__ xs)
{
    if (blockIdx.x < SCAT_BLK) {
        const int e = blockIdx.x * 256 + threadIdx.x;
        if (e < N_EDGES_C) {
            const int src  = ei[e];
            const int dst  = ei[N_EDGES_C + e];
            const int code = ea[e * 3] * 25 + ea[e * 3 + 1] * 5 + ea[e * 3 + 2];
            const int p = atomicAdd(&cnt[dst * CNT_STRIDE], 1);
            if (p < MAXDEG_C)
                packed[dst * MAXDEG_C + p] = (src << 7) | code;
        }
    } else {
        qkvs_tile_body(blockIdx.x - SCAT_BLK, threadIdx.x, xhi, xlo, bt_hi, bt_lo,
                       bq, bk, bv, bs, qh, kvh, xs);
    }
}

// ---------------------------------------------------------------------------
// Attention (fp16 operands): one wave per node; 8 edge slots x 8 lanes; lane
// owns channels 8r..8r+7 as 4x f16x2. k+e / v+e via v_pk_add_f16; qk dot via
// v_dot2_f32_f16 (fdot2, f32 accum). Direct per-lane packed loads, depth-2
// pipeline. No max-shift (softmax shift-invariant; logits O(1), clamp 80).
// WRITE_X: emit f32 x for pooling (last layer only).
// ---------------------------------------------------------------------------
template<int WRITE_X>
__global__ __launch_bounds__(256) void attn_kernel(
    const unsigned short* __restrict__ qh, const unsigned short* __restrict__ kvh,
    const float* __restrict__ xs, const unsigned short* __restrict__ eth_l,
    const int* __restrict__ cnt, const int* __restrict__ packed,
    float* __restrict__ x, unsigned short* __restrict__ xhi,
    unsigned short* __restrict__ xlo)
{
    const int lane = threadIdx.x & 63;
    const int s    = lane >> 3;          // edge slot 0..7
    const int r    = lane & 7;           // channel group
    const int c0   = r * 8;              // channels c0..c0+7
    const int n    = blockIdx.x * 4 + (threadIdx.x >> 6);

    f16x2 q2[4];
    {
        U4 qu; qu.u = *(const uint4*)(qh + (size_t)n * 64 + c0);
        q2[0] = qu.h[0]; q2[1] = qu.h[1]; q2[2] = qu.h[2]; q2[3] = qu.h[3];
    }
    const int deg  = min(cnt[n * CNT_STRIDE], MAXDEG_C);
    const int base = n * MAXDEG_C;

    float den = 0.f;
    float acc[8] = {0.f, 0.f, 0.f, 0.f, 0.f, 0.f, 0.f, 0.f};

    if (deg > 0) {
        const int nit = (deg + 7) >> 3;
        uint4 kA, vA, eA, kB, vB, eB, kC, vC, eC;

        auto LD = [&](int t, uint4& kf, uint4& vf, uint4& ef) {
            const int idx = min(t * 8 + s, deg - 1);
            const int pk = packed[base + idx];              // direct, no shfl
            const unsigned short* kp = kvh + (size_t)(pk >> 7) * 128;
            kf = *(const uint4*)(kp + c0);
            vf = *(const uint4*)(kp + 64 + c0);
            ef = *(const uint4*)(eth_l + (pk & 127) * 64 + c0);
        };
        auto PROC = [&](int t, const uint4& ku, const uint4& vu, const uint4& eu) {
            U4 kk, vv, ee;
            kk.u = ku; vv.u = vu; ee.u = eu;
            float p = 0.f;
            f16x2 ve[4];
            #pragma unroll
            for (int i = 0; i < 4; ++i) {
                f16x2 ke = kk.h[i] + ee.h[i];               // v_pk_add_f16
                p = __builtin_amdgcn_fdot2(q2[i], ke, p, false);
                ve[i] = vv.h[i] + ee.h[i];                  // v_pk_add_f16
            }
            p += __shfl_xor(p, 1, 64);                      // 16-ch head reduce
            const float ex = (t * 8 + s < deg) ? __expf(fminf(p * 0.25f, 80.f)) : 0.f;
            den += ex;
            #pragma unroll
            for (int i = 0; i < 4; ++i) {
                acc[2 * i]     = fmaf(ex, (float)ve[i][0], acc[2 * i]);
                acc[2 * i + 1] = fmaf(ex, (float)ve[i][1], acc[2 * i + 1]);
            }
        };

        LD(0, kA, vA, eA);
        LD(1, kB, vB, eB);
        int t = 0;
        for (; t + 3 <= nit; t += 3) {
            LD(t + 2, kC, vC, eC); PROC(t,     kA, vA, eA);
            LD(t + 3, kA, vA, eA); PROC(t + 1, kB, vB, eB);
            LD(t + 4, kB, vB, eB); PROC(t + 2, kC, vC, eC);
        }
        if (t     < nit) PROC(t,     kA, vA, eA);
        if (t + 1 < nit) PROC(t + 1, kB, vB, eB);
    }

    // merge the 8 slots' partials (butterfly over lane bits 3..5)
    #pragma unroll
    for (int off = 8; off <= 32; off <<= 1) {
        den += __shfl_xor(den, off, 64);
        #pragma unroll
        for (int i = 0; i < 8; ++i)
            acc[i] += __shfl_xor(acc[i], off, 64);
    }

    if (s == 0) {
        const float inv = 1.f / (den + 1e-16f);
        const float4 xsa = *(const float4*)(xs + (size_t)n * 64 + c0);
        const float4 xsb = *(const float4*)(xs + (size_t)n * 64 + c0 + 4);
        float o[8];
        o[0] = fmaxf(acc[0] * inv + xsa.x, 0.f);
        o[1] = fmaxf(acc[1] * inv + xsa.y, 0.f);
        o[2] = fmaxf(acc[2] * inv + xsa.z, 0.f);
        o[3] = fmaxf(acc[3] * inv + xsa.w, 0.f);
        o[4] = fmaxf(acc[4] * inv + xsb.x, 0.f);
        o[5] = fmaxf(acc[5] * inv + xsb.y, 0.f);
        o[6] = fmaxf(acc[6] * inv + xsb.z, 0.f);
        o[7] = fmaxf(acc[7] * inv + xsb.w, 0.f);

        if (WRITE_X) {
            float4 oa = {o[0], o[1], o[2], o[3]};
            float4 ob = {o[4], o[5], o[6], o[7]};
            *(float4*)(x + (size_t)n * 64 + c0)     = oa;
            *(float4*)(x + (size_t)n * 64 + c0 + 4) = ob;
        }

        ushort4 ha, hb, la, lb;
        split_bf(o[0], ha.x, la.x); split_bf(o[1], ha.y, la.y);
        split_bf(o[2], ha.z, la.z); split_bf(o[3], ha.w, la.w);
        split_bf(o[4], hb.x, lb.x); split_bf(o[5], hb.y, lb.y);
        split_bf(o[6], hb.z, lb.z); split_bf(o[7], hb.w, lb.w);
        *(ushort4*)(xhi + (size_t)n * 64 + c0)     = ha;
        *(ushort4*)(xhi + (size_t)n * 64 + c0 + 4) = hb;
        *(ushort4*)(xlo + (size_t)n * 64 + c0)     = la;
        *(ushort4*)(xlo + (size_t)n * 64 + c0 + 4) = lb;
    }
}

// ---------------------------------------------------------------------------
// Fused mean-pool + classifier head: one 128-thread block per graph.
// ---------------------------------------------------------------------------
__global__ __launch_bounds__(128) void pool_head_kernel(
    const float* __restrict__ x, const int* __restrict__ gstart,
    const float* __restrict__ fc_W, const float* __restrict__ fc_b,
    float* __restrict__ out)
{
    __shared__ float tmp[128];
    __shared__ float p[HID_C];
    const int g = blockIdx.x;
    const int s0 = gstart[g], s1 = gstart[g + 1];
    const int ch = threadIdx.x & 63;
    const int half = threadIdx.x >> 6;

    float acc = 0.f;
    for (int n = s0 + half; n < s1; n += 2)
        acc += x[(size_t)n * 64 + ch];
    tmp[threadIdx.x] = acc;
    __syncthreads();
    if (half == 0)
        p[ch] = (tmp[ch] + tmp[64 + ch]) / fmaxf((float)(s1 - s0), 1.f);
    __syncthreads();

    const int o = threadIdx.x;            // 0..127
    float rr = fc_b[o];
    #pragma unroll 8
    for (int i = 0; i < HID_C; ++i)
        rr = fmaf(p[i], fc_W[i * OUT_C + o], rr);
    out[(size_t)g * OUT_C + o] = rr;
}

// ---------------------------------------------------------------------------
extern "C" void kernel_launch(void* const* d_in, const int* in_sizes, int n_in,
                              void* d_out, int out_size, void* d_ws, size_t ws_size,
                              hipStream_t stream)
{
    const int*   x_atom     = (const int*)  d_in[0];
    const int*   edge_index = (const int*)  d_in[1];
    const int*   edge_attr  = (const int*)  d_in[2];
    const int*   batch      = (const int*)  d_in[3];
    const float* lap_pe     = (const float*)d_in[4];
    const float* rwse       = (const float*)d_in[5];
    const float* atom_emb   = (const float*)d_in[6];
    const float* bond_emb   = (const float*)d_in[7];
    const float* sign_W1    = (const float*)d_in[8];
    const float* sign_b1    = (const float*)d_in[9];
    const float* sign_W2    = (const float*)d_in[10];
    const float* sign_b2    = (const float*)d_in[11];
    const float* rwse_W1    = (const float*)d_in[12];
    const float* rwse_b1    = (const float*)d_in[13];
    const float* rwse_W2    = (const float*)d_in[14];
    const float* rwse_b2    = (const float*)d_in[15];
    const float* Wq = (const float*)d_in[16];
    const float* bq = (const float*)d_in[17];
    const float* Wk = (const float*)d_in[18];
    const float* bk = (const float*)d_in[19];
    const float* Wv = (const float*)d_in[20];
    const float* bv = (const float*)d_in[21];
    const float* We = (const float*)d_in[22];
    const float* be = (const float*)d_in[23];
    const float* Ws = (const float*)d_in[24];
    const float* bs = (const float*)d_in[25];
    const float* fc_W = (const float*)d_in[26];
    const float* fc_b = (const float*)d_in[27];
    float* out = (float*)d_out;

    char* ws = (char*)d_ws;
    size_t off = 0;
    auto alloc = [&](size_t bytes) {
        size_t o = off;
        off += (bytes + 255) & ~(size_t)255;
        return o;
    };
    float* x    = (float*)(ws + alloc((size_t)N_NODES_C * HID_C * 4));
    float* xs   = (float*)(ws + alloc((size_t)N_NODES_C * HID_C * 4));
    unsigned short* qh  = (unsigned short*)(ws + alloc((size_t)N_NODES_C * HID_C * 2));
    unsigned short* kvh = (unsigned short*)(ws + alloc((size_t)N_NODES_C * HID_C * 2 * 2));
    unsigned short* xhi = (unsigned short*)(ws + alloc((size_t)N_NODES_PAD * HID_C * 2));
    unsigned short* xlo = (unsigned short*)(ws + alloc((size_t)N_NODES_PAD * HID_C * 2));
    unsigned short* bt_hi = (unsigned short*)(ws + alloc((size_t)LAYERS_C * 256 * 64 * 2));
    unsigned short* bt_lo = (unsigned short*)(ws + alloc((size_t)LAYERS_C * 256 * 64 * 2));
    unsigned short* eth = (unsigned short*)(ws + alloc((size_t)LAYERS_C * NCODES_C * HID_C * 2));
    int* cnt    = (int*)  (ws + alloc((size_t)N_NODES_C * CNT_STRIDE * 4));
    int* packed = (int*)  (ws + alloc((size_t)N_NODES_C * MAXDEG_C * 4));
    int* gstart = (int*)  (ws + alloc((size_t)(GRAPHS_C + 1) * 4));

    mega_prologue_kernel<<<PRO_BLK, 256, 0, stream>>>(
        x_atom, lap_pe, rwse, atom_emb,
        sign_W1, sign_b1, sign_W2, sign_b2,
        rwse_W1, rwse_b1, rwse_W2, rwse_b2,
        bond_emb, We, be, Wq, Wk, Wv, Ws, batch,
        xhi, xlo, bt_hi, bt_lo, eth, gstart, cnt);

    const int qkvs_grid = (N_NODES_C + 63) / 64;     // 313
    const int attn_grid = N_NODES_C / 4;             // 5000

    // layer 0 projections fused with the single-pass CSR bucketing
    scatter_qkvs_kernel<<<SCAT_BLK + qkvs_grid, 256, 0, stream>>>(
        edge_index, edge_attr, cnt, packed,
        xhi, xlo, bt_hi, bt_lo,
        bq, bk, bv, bs, qh, kvh, xs);

    for (int l = 0; l < LAYERS_C; ++l) {
        const unsigned short* el = eth + (size_t)l * NCODES_C * HID_C;
        if (l > 0) {
            qkvs_mfma_kernel<<<qkvs_grid, 256, 0, stream>>>(
                xhi, xlo,
                bt_hi + (size_t)l * 256 * 64, bt_lo + (size_t)l * 256 * 64,
                bq + l * 64, bk + l * 64, bv + l * 64, bs + l * 64, qh, kvh, xs);
        }
        if (l < LAYERS_C - 1)
            attn_kernel<0><<<attn_grid, 256, 0, stream>>>(qh, kvh, xs, el, cnt, packed, x, xhi, xlo);
        else
            attn_kernel<1><<<attn_grid, 256, 0, stream>>>(qh, kvh, xs, el, cnt, packed, x, xhi, xlo);
    }

    pool_head_kernel<<<GRAPHS_C, 128, 0, stream>>>(x, gstart, fc_W, fc_b, out);
}